// Round 6
// baseline (269.925 us; speedup 1.0000x reference)
//
#include <hip/hip_runtime.h>
#include <hip/hip_bf16.h>
#include <cstddef>

#define BATCH 4
#define CH 256
#define HH 96
#define WW 96
#define HWN (HH*WW)               // 9216
#define NTOT (BATCH*CH*HWN)       // 9437184
#define XT_H 98
#define XT_W 98
#define XT_PLANE (XT_H*XT_W*CH)   // per-batch elements in xt (bf16)

typedef __attribute__((ext_vector_type(16))) float f32x16;
typedef __attribute__((ext_vector_type(8))) __bf16 bfrag;
typedef __attribute__((ext_vector_type(8))) unsigned short u16x8;

static __device__ __forceinline__ unsigned short f2bf(float f) {
  unsigned int u = __float_as_uint(f);
  unsigned int r = (u + 0x7fffu + ((u >> 16) & 1u)) >> 16;
  return (unsigned short)r;
}

// ---------------------------------------------------------------------------
// Kernel 1: all the small MLPs (unchanged — proven).
// ---------------------------------------------------------------------------
__global__ __launch_bounds__(256) void params_kernel(
    const float* __restrict__ para, const float* __restrict__ style,
    const float* __restrict__ cw,  const float* __restrict__ cb,
    const float* __restrict__ sw,  const float* __restrict__ sb,
    const float* __restrict__ rw,  const float* __restrict__ rb,
    const float* __restrict__ tw,  const float* __restrict__ tb,
    const float* __restrict__ a1w, const float* __restrict__ a1b,
    const float* __restrict__ g1w, const float* __restrict__ g1b,
    const float* __restrict__ b1w, const float* __restrict__ b1b,
    const float* __restrict__ a2w, const float* __restrict__ a2b,
    const float* __restrict__ g2w, const float* __restrict__ g2b,
    const float* __restrict__ b2w, const float* __restrict__ b2b,
    float* __restrict__ warp, float* __restrict__ gb1, float* __restrict__ gb2)
{
  __shared__ float s_para[256], s_sty[256], s_pc[256], s_a1[128], s_a2[128];
  int b = blockIdx.x;
  int t = threadIdx.x;
  s_para[t] = para[b*256 + t];
  s_sty[t]  = style[b*256 + t];
  __syncthreads();

  float acc = cb[t];
  for (int i = 0; i < 256; i++) acc = fmaf(s_para[i], cw[i*256 + t], acc);
  s_pc[t] = fmaxf(acc, 0.f);

  if (t < 128) {
    float a = a1b[t];
    for (int i = 0; i < 256; i++) a = fmaf(s_sty[i], a1w[i*128 + t], a);
    s_a1[t] = fmaxf(a, 0.f);
  } else {
    int u = t - 128;
    float a = a2b[u];
    for (int i = 0; i < 256; i++) a = fmaf(s_sty[i], a2w[i*128 + u], a);
    s_a2[u] = fmaxf(a, 0.f);
  }
  __syncthreads();

  int c = t;
  float ds = sb[c], dr = rb[c], dtx = tb[2*c], dty = tb[2*c + 1];
  for (int i = 0; i < 256; i++) {
    float p = s_pc[i];
    ds  = fmaf(p, sw[i*256 + c], ds);
    dr  = fmaf(p, rw[i*256 + c], dr);
    dtx = fmaf(p, tw[i*512 + 2*c], dtx);
    dty = fmaf(p, tw[i*512 + 2*c + 1], dty);
  }
  float scale = 2.f / (1.f + expf(-ds));
  float ang = tanhf(dr) * 3.14159f;
  float sn, cs;
  sincosf(ang, &sn, &cs);
  int bc = b*256 + c;
  warp[bc*4 + 0] = cs * scale;
  warp[bc*4 + 1] = sn * scale;
  warp[bc*4 + 2] = tanhf(dtx);
  warp[bc*4 + 3] = tanhf(dty);

  float g1 = g1b[c], be1 = b1b[c], g2 = g2b[c], be2 = b2b[c];
  for (int i = 0; i < 128; i++) {
    float a = s_a1[i];
    g1  = fmaf(a, g1w[i*256 + c], g1);
    be1 = fmaf(a, b1w[i*256 + c], be1);
  }
  for (int i = 0; i < 128; i++) {
    float a = s_a2[i];
    g2  = fmaf(a, g2w[i*256 + c], g2);
    be2 = fmaf(a, b2w[i*256 + c], be2);
  }
  gb1[bc*2] = g1; gb1[bc*2 + 1] = be1;
  gb2[bc*2] = g2; gb2[bc*2 + 1] = be2;
}

// ---------------------------------------------------------------------------
// Kernel 2: weight preconversion into per-lane MFMA fragment order (proven).
// wf[coblk4][ks16][tap9][m2][lane64][8]
// ---------------------------------------------------------------------------
__global__ __launch_bounds__(256) void prep_weights_kernel(
    const float* __restrict__ w1, const float* __restrict__ w2,
    unsigned short* __restrict__ wf1, unsigned short* __restrict__ wf2)
{
  int co = blockIdx.x & 255;
  const float* src = (blockIdx.x < 256) ? w1 : w2;
  unsigned short* dst = (blockIdx.x < 256) ? wf1 : wf2;
  int ci = threadIdx.x;
  int coblk = co >> 6, m = (co >> 5) & 1;
  int l = (co & 31) | (((ci >> 3) & 1) << 5);
  int ks = ci >> 4, j = ci & 7;
  const float* p = src + ((size_t)co * 256 + ci) * 9;
  #pragma unroll
  for (int tap = 0; tap < 9; tap++) {
    size_t idx = (((size_t)((coblk * 16 + ks) * 9 + tap) * 2 + m) * 64 + l) * 8 + j;
    dst[idx] = f2bf(p[tap]);
  }
}

// ---------------------------------------------------------------------------
// Kernel 3: AdaAT trilinear warp, quarter-plane blocks (unchanged from R5).
// ---------------------------------------------------------------------------
__global__ __launch_bounds__(256) void adaat_kernel(
    const float* __restrict__ fm, const float* __restrict__ warp,
    float* __restrict__ tout, float* __restrict__ part)
{
  int bid = blockIdx.x;
  int bc = bid >> 2, q = bid & 3;
  int b = bc >> 8, c = bc & 255;
  float csc = warp[bc*4 + 0], ssc = warp[bc*4 + 1];
  float tx = warp[bc*4 + 2], ty = warp[bc*4 + 3];

  const float axw = csc * (2.f / 95.f) * 48.f;
  const float axh = -ssc * (2.f / 95.f) * 48.f;
  const float ax0 = 48.f * (tx - csc + ssc) + 47.5f;
  const float ayw = ssc * (2.f / 95.f) * 48.f;
  const float ayh = csc * (2.f / 95.f) * 48.f;
  const float ay0 = 48.f * (ty - ssc - csc) + 47.5f;

  float gzc = 2.f * c / 255.f - 1.f;
  float iz = ((gzc + 1.f) * 256.f - 1.f) * 0.5f;
  float z0f = floorf(iz);
  float wz = iz - z0f;
  int z0 = (int)z0f;
  const float* p0 = (z0 >= 0 && z0 < 256) ? fm + (size_t)(b*256 + z0) * HWN : nullptr;
  const float* p1 = (z0 + 1 < 256) ? fm + (size_t)(b*256 + z0 + 1) * HWN : nullptr;
  float wpl0 = 1.f - wz, wpl1 = wz;

  int t = threadIdx.x;
  int h = q * 24 + t / 96;
  int w = t % 96;
  float* dst = tout + (size_t)bc * HWN + q * 2304 + t;

  float sum = 0.f, sumsq = 0.f;
  #pragma unroll
  for (int k = 0; k < 9; k++) {
    float fw = (float)w, fh = (float)h;
    float ix = fmaf(axw, fw, fmaf(axh, fh, ax0));
    float iy = fmaf(ayw, fw, fmaf(ayh, fh, ay0));
    float x0f = floorf(ix), y0f = floorf(iy);
    float wx = ix - x0f, wy = iy - y0f;
    int x0 = (int)x0f, y0 = (int)y0f;
    bool vx0 = (unsigned)x0 < 96u, vx1 = (unsigned)(x0 + 1) < 96u;
    bool vy0 = (unsigned)y0 < 96u, vy1 = (unsigned)(y0 + 1) < 96u;
    float w00 = (1.f - wy) * (1.f - wx), w01 = (1.f - wy) * wx;
    float w10 = wy * (1.f - wx),         w11 = wy * wx;
    int o00 = y0 * 96 + x0;
    float v = 0.f;
    if (p0) {
      float a00 = (vy0 && vx0) ? p0[o00]      : 0.f;
      float a01 = (vy0 && vx1) ? p0[o00 + 1]  : 0.f;
      float a10 = (vy1 && vx0) ? p0[o00 + 96] : 0.f;
      float a11 = (vy1 && vx1) ? p0[o00 + 97] : 0.f;
      v += wpl0 * (w00*a00 + w01*a01 + w10*a10 + w11*a11);
    }
    if (p1) {
      float a00 = (vy0 && vx0) ? p1[o00]      : 0.f;
      float a01 = (vy0 && vx1) ? p1[o00 + 1]  : 0.f;
      float a10 = (vy1 && vx0) ? p1[o00 + 96] : 0.f;
      float a11 = (vy1 && vx1) ? p1[o00 + 97] : 0.f;
      v += wpl1 * (w00*a00 + w01*a01 + w10*a10 + w11*a11);
    }
    dst[k * 256] = v;
    sum += v;
    sumsq += v * v;
    int wn = w + 64;
    int carry = (wn >= 96) ? 1 : 0;
    w = wn - (carry ? 96 : 0);
    h += 2 + carry;
  }

  for (int off = 32; off > 0; off >>= 1) {
    sum   += __shfl_down(sum, off, 64);
    sumsq += __shfl_down(sumsq, off, 64);
  }
  __shared__ float rs[4], rq[4];
  int lane = t & 63, wvi = t >> 6;
  if (lane == 0) { rs[wvi] = sum; rq[wvi] = sumsq; }
  __syncthreads();
  if (t == 0) {
    part[bid * 2]     = rs[0] + rs[1] + rs[2] + rs[3];
    part[bid * 2 + 1] = rq[0] + rq[1] + rq[2] + rq[3];
  }
}

// ---------------------------------------------------------------------------
// Kernel 3b: combine quarter partials -> nrm1 scale/bias (unchanged).
// ---------------------------------------------------------------------------
__global__ __launch_bounds__(256) void finalize_nrm_kernel(
    const float* __restrict__ part, const float* __restrict__ gb,
    float* __restrict__ nrm)
{
  int bc = blockIdx.x * 256 + threadIdx.x;
  float S = 0.f, Q = 0.f;
  #pragma unroll
  for (int q = 0; q < 4; q++) {
    S += part[(bc * 4 + q) * 2];
    Q += part[(bc * 4 + q) * 2 + 1];
  }
  float m = S * (1.f / 9216.f);
  float var = Q * (1.f / 9216.f) - m * m;
  float rstd = rsqrtf(var + 1e-5f);
  float sc = (1.f + gb[bc*2]) * rstd;
  nrm[bc*2] = sc;
  nrm[bc*2 + 1] = gb[bc*2 + 1] - m * sc;
}

// ---------------------------------------------------------------------------
// Kernel 4: per-plane stats of conv1 output (for AdaIN-2) — unchanged.
// ---------------------------------------------------------------------------
__global__ __launch_bounds__(256) void stats_kernel(
    const float* __restrict__ x, const float* __restrict__ gb,
    float* __restrict__ nrm)
{
  int bc = blockIdx.x;
  const float4* p = (const float4*)(x + (size_t)bc * HWN);
  float sum = 0.f, sumsq = 0.f;
  for (int i = threadIdx.x; i < HWN / 4; i += 256) {
    float4 v = p[i];
    sum   += v.x + v.y + v.z + v.w;
    sumsq += v.x*v.x + v.y*v.y + v.z*v.z + v.w*v.w;
  }
  for (int off = 32; off > 0; off >>= 1) {
    sum   += __shfl_down(sum, off, 64);
    sumsq += __shfl_down(sumsq, off, 64);
  }
  __shared__ float rs[4], rq[4];
  int lane = threadIdx.x & 63, wv = threadIdx.x >> 6;
  if (lane == 0) { rs[wv] = sum; rq[wv] = sumsq; }
  __syncthreads();
  if (threadIdx.x == 0) {
    float S = rs[0] + rs[1] + rs[2] + rs[3];
    float Q = rq[0] + rq[1] + rq[2] + rq[3];
    float m = S * (1.f / 9216.f);
    float var = Q * (1.f / 9216.f) - m * m;
    float rstd = rsqrtf(var + 1e-5f);
    float sc = (1.f + gb[bc*2]) * rstd;
    nrm[bc*2] = sc;
    nrm[bc*2 + 1] = gb[bc*2 + 1] - m * sc;
  }
}

// ---------------------------------------------------------------------------
// Kernel 5: transpose + fused AdaIN(scale/bias) + lrelu + bf16 cvt (unchanged).
// ---------------------------------------------------------------------------
__global__ __launch_bounds__(256) void transpose_norm_kernel(
    const float* __restrict__ x, const float* __restrict__ nrm,
    unsigned short* __restrict__ xt)
{
  int hi = blockIdx.x;
  int b  = blockIdx.y;
  unsigned short* dst = xt + (size_t)b * XT_PLANE + (size_t)hi * (XT_W * CH);
  int t = threadIdx.x;
  int h = hi - 1;
  u16x8 zero = {0,0,0,0,0,0,0,0};
  if (h < 0 || h >= 96) {
    for (int c = t; c < XT_W * CH / 8; c += 256) ((u16x8*)dst)[c] = zero;
    return;
  }
  __shared__ unsigned short s[96 * 256];  // [w][ci]
  int ci = t;
  float sc = nrm[(b*256 + ci)*2], bi = nrm[(b*256 + ci)*2 + 1];
  const float* src = x + ((size_t)(b*256 + ci)) * HWN + h * 96;
  for (int wg = 0; wg < 24; wg++) {
    float4 v = *(const float4*)(src + wg * 4);
    float y0 = fmaf(v.x, sc, bi); y0 = (y0 >= 0.f) ? y0 : 0.2f * y0;
    float y1 = fmaf(v.y, sc, bi); y1 = (y1 >= 0.f) ? y1 : 0.2f * y1;
    float y2 = fmaf(v.z, sc, bi); y2 = (y2 >= 0.f) ? y2 : 0.2f * y2;
    float y3 = fmaf(v.w, sc, bi); y3 = (y3 >= 0.f) ? y3 : 0.2f * y3;
    s[(wg*4 + 0) * 256 + ci] = f2bf(y0);
    s[(wg*4 + 1) * 256 + ci] = f2bf(y1);
    s[(wg*4 + 2) * 256 + ci] = f2bf(y2);
    s[(wg*4 + 3) * 256 + ci] = f2bf(y3);
  }
  __syncthreads();
  for (int c = t; c < 98 * 32; c += 256) {
    int w = c >> 5, p = c & 31;
    u16x8 v = zero;
    if (w >= 1 && w <= 96) v = *(const u16x8*)&s[(w - 1) * 256 + p * 8];
    ((u16x8*)dst)[c] = v;
  }
}

// ---------------------------------------------------------------------------
// Kernel 6 (R6): 3x3 conv 256->256, bf16 MFMA, BARRIER-FREE single-wave
// blocks. Tile: 1 row x 96 px x 64 co. Grid (96,4,4) = 1536 blocks = 6/CU.
// Weight frags register-rotated (reload tap t for ks+1 right after last use
// in ks => full K-step of latency cover). Stage dbuf in LDS, no syncthreads.
// ---------------------------------------------------------------------------
__global__ __launch_bounds__(64, 2) void conv_mfma_kernel(
    const unsigned short* __restrict__ xt,   // [4][98][98][256] bf16
    const unsigned short* __restrict__ wf,   // frag layout (see prep)
    const float* __restrict__ cb,
    float* __restrict__ out)                 // [4][256][96][96] f32
{
  // slab: 3 input rows (xt rows h..h+2), chunk c=(r*2+half)*98+w, 588 chunks
  __shared__ __align__(16) unsigned short s_in[2][588 * 8];

  int h = blockIdx.x, coblk = blockIdx.y, b = blockIdx.z;
  int co0 = coblk * 64;
  int lane = threadIdx.x;
  int l31 = lane & 31, lhi = lane >> 5;
  const unsigned short* xtb = xt + (size_t)b * XT_PLANE;

  int pre_g[10];
  #pragma unroll
  for (int i = 0; i < 10; i++) {
    int c = lane + i * 64;
    if (c < 588) {
      int r = c / 196;
      int rem = c - r * 196;
      int half = rem / 98;
      int w = rem - half * 98;
      pre_g[i] = ((h + r) * 98 + w) * 256 + half * 8;
    }
  }

  f32x16 acc[2][3];
  #pragma unroll
  for (int m = 0; m < 2; m++)
    #pragma unroll
    for (int n = 0; n < 3; n++)
      #pragma unroll
      for (int i = 0; i < 16; i++) acc[m][n][i] = 0.f;

  const unsigned short* wfb = wf + (size_t)(coblk * 16) * 9216 + lane * 8;

  u16x8 stg[10];
  // prologue: stage ks=0, write buf0; load wa for ks=0; issue stage ks=1
  #pragma unroll
  for (int i = 0; i < 9; i++) stg[i] = *(const u16x8*)(xtb + pre_g[i]);
  if (lane < 12) stg[9] = *(const u16x8*)(xtb + pre_g[9]);
  #pragma unroll
  for (int i = 0; i < 9; i++) *(u16x8*)(&s_in[0][(lane + i * 64) * 8]) = stg[i];
  if (lane < 12) *(u16x8*)(&s_in[0][(lane + 9 * 64) * 8]) = stg[9];

  bfrag wa[9][2];
  #pragma unroll
  for (int tap = 0; tap < 9; tap++) {
    wa[tap][0] = *(const bfrag*)(wfb + tap * 1024);
    wa[tap][1] = *(const bfrag*)(wfb + tap * 1024 + 512);
  }
  #pragma unroll
  for (int i = 0; i < 9; i++) stg[i] = *(const u16x8*)(xtb + pre_g[i] + 16);
  if (lane < 12) stg[9] = *(const u16x8*)(xtb + pre_g[9] + 16);

  int buf = 0;
  #pragma unroll 1
  for (int ks = 0; ks < 16; ks++) {
    const unsigned short* sb = s_in[buf];
    int ksn = (ks < 15) ? (ks + 1) : 15;
    const unsigned short* wkn = wfb + (size_t)ksn * 9216;
    #pragma unroll
    for (int ky = 0; ky < 3; ky++) {
      const unsigned short* srow = sb + (ky * 2 + lhi) * (98 * 8);
      #pragma unroll
      for (int kx = 0; kx < 3; kx++) {
        int tap = ky * 3 + kx;
        bfrag b0 = *(const bfrag*)(srow + (0 * 32 + kx + l31) * 8);
        bfrag b1 = *(const bfrag*)(srow + (1 * 32 + kx + l31) * 8);
        bfrag b2 = *(const bfrag*)(srow + (2 * 32 + kx + l31) * 8);
        __builtin_amdgcn_s_setprio(1);
        acc[0][0] = __builtin_amdgcn_mfma_f32_32x32x16_bf16(wa[tap][0], b0, acc[0][0], 0, 0, 0);
        acc[1][0] = __builtin_amdgcn_mfma_f32_32x32x16_bf16(wa[tap][1], b0, acc[1][0], 0, 0, 0);
        acc[0][1] = __builtin_amdgcn_mfma_f32_32x32x16_bf16(wa[tap][0], b1, acc[0][1], 0, 0, 0);
        acc[1][1] = __builtin_amdgcn_mfma_f32_32x32x16_bf16(wa[tap][1], b1, acc[1][1], 0, 0, 0);
        acc[0][2] = __builtin_amdgcn_mfma_f32_32x32x16_bf16(wa[tap][0], b2, acc[0][2], 0, 0, 0);
        acc[1][2] = __builtin_amdgcn_mfma_f32_32x32x16_bf16(wa[tap][1], b2, acc[1][2], 0, 0, 0);
        __builtin_amdgcn_s_setprio(0);
        // rotate: reload this tap's frags for the NEXT K-step (~430cy cover)
        wa[tap][0] = *(const bfrag*)(wkn + tap * 1024);
        wa[tap][1] = *(const bfrag*)(wkn + tap * 1024 + 512);
      }
    }
    // write staged ks+1 into the other buffer; then issue stage ks+2
    if (ks < 15) {
      unsigned short* sn = s_in[buf ^ 1];
      #pragma unroll
      for (int i = 0; i < 9; i++) *(u16x8*)(&sn[(lane + i * 64) * 8]) = stg[i];
      if (lane < 12) *(u16x8*)(&sn[(lane + 9 * 64) * 8]) = stg[9];
      if (ks < 14) {
        int off = (ks + 2) * 16;
        #pragma unroll
        for (int i = 0; i < 9; i++) stg[i] = *(const u16x8*)(xtb + pre_g[i] + off);
        if (lane < 12) stg[9] = *(const u16x8*)(xtb + pre_g[9] + off);
      }
    }
    buf ^= 1;
  }

  // epilogue: C col = lane&31 (px), row = (r&3)+8*(r>>2)+4*(lane>>5) (co)
  #pragma unroll
  for (int m = 0; m < 2; m++) {
    #pragma unroll
    for (int r = 0; r < 16; r++) {
      int row = (r & 3) + 8 * (r >> 2) + 4 * lhi;
      int co = co0 + m * 32 + row;
      float bv = cb[co];
      size_t base = ((size_t)(b * 256 + co) * 96 + h) * 96;
      #pragma unroll
      for (int n = 0; n < 3; n++) {
        out[base + n * 32 + l31] = acc[m][n][r] + bv;
      }
    }
  }
}

// ---------------------------------------------------------------------------
extern "C" void kernel_launch(void* const* d_in, const int* in_sizes, int n_in,
                              void* d_out, int out_size, void* d_ws, size_t ws_size,
                              hipStream_t stream)
{
  const float* fm    = (const float*)d_in[0];
  const float* para  = (const float*)d_in[1];
  const float* style = (const float*)d_in[2];
  const float* cw  = (const float*)d_in[3];
  const float* cb  = (const float*)d_in[4];
  const float* sw  = (const float*)d_in[5];
  const float* sb  = (const float*)d_in[6];
  const float* rw  = (const float*)d_in[7];
  const float* rb  = (const float*)d_in[8];
  const float* tw  = (const float*)d_in[9];
  const float* tb  = (const float*)d_in[10];
  const float* a1w = (const float*)d_in[11];
  const float* a1b = (const float*)d_in[12];
  const float* g1w = (const float*)d_in[13];
  const float* g1b = (const float*)d_in[14];
  const float* b1w = (const float*)d_in[15];
  const float* b1b = (const float*)d_in[16];
  const float* c1w = (const float*)d_in[17];
  const float* c1b = (const float*)d_in[18];
  const float* a2w = (const float*)d_in[19];
  const float* a2b = (const float*)d_in[20];
  const float* g2w = (const float*)d_in[21];
  const float* g2b = (const float*)d_in[22];
  const float* b2w = (const float*)d_in[23];
  const float* b2b = (const float*)d_in[24];
  const float* c2w = (const float*)d_in[25];
  const float* c2b = (const float*)d_in[26];

  float* outf = (float*)d_out;

  unsigned short* xtbuf = (unsigned short*)d_ws;                 // 4*98*98*256 bf16
  unsigned short* wf1   = xtbuf + (size_t)BATCH * XT_PLANE;      // 589824
  unsigned short* wf2   = wf1 + 9 * 256 * 256;
  float* fws  = (float*)(wf2 + 9 * 256 * 256);
  float* warp = fws;                   // 4096
  float* gb1  = warp + 4 * 1024;       // 2048
  float* gb2  = gb1 + 2 * 1024;        // 2048
  float* nrm1 = gb2 + 2 * 1024;        // 2048
  float* nrm2 = nrm1 + 2 * 1024;       // 2048
  float* part = nrm2 + 2 * 1024;       // 4096*2 floats

  params_kernel<<<4, 256, 0, stream>>>(para, style, cw, cb, sw, sb, rw, rb, tw, tb,
      a1w, a1b, g1w, g1b, b1w, b1b, a2w, a2b, g2w, g2b, b2w, b2b, warp, gb1, gb2);
  prep_weights_kernel<<<512, 256, 0, stream>>>(c1w, c2w, wf1, wf2);
  adaat_kernel<<<4096, 256, 0, stream>>>(fm, warp, outf, part);
  finalize_nrm_kernel<<<4, 256, 0, stream>>>(part, gb1, nrm1);
  transpose_norm_kernel<<<dim3(98, 4), 256, 0, stream>>>(outf, nrm1, xtbuf);
  conv_mfma_kernel<<<dim3(96, 4, 4), 64, 0, stream>>>(xtbuf, wf1, c1b, outf);
  stats_kernel<<<1024, 256, 0, stream>>>(outf, gb2, nrm2);
  transpose_norm_kernel<<<dim3(98, 4), 256, 0, stream>>>(outf, nrm2, xtbuf);
  conv_mfma_kernel<<<dim3(96, 4, 4), 64, 0, stream>>>(xtbuf, wf2, c2b, outf);
}

// Round 7
// 257.710 us; speedup vs baseline: 1.0474x; 1.0474x over previous
//
#include <hip/hip_runtime.h>
#include <hip/hip_bf16.h>
#include <cstddef>

#define BATCH 4
#define CH 256
#define HH 96
#define WW 96
#define HWN (HH*WW)               // 9216
#define NTOT (BATCH*CH*HWN)       // 9437184
#define XT_H 98
#define XT_W 98
#define XT_PLANE (XT_H*XT_W*CH)   // per-batch elements in xt (bf16)

typedef __attribute__((ext_vector_type(16))) float f32x16;
typedef __attribute__((ext_vector_type(8))) __bf16 bfrag;
typedef __attribute__((ext_vector_type(8))) unsigned short u16x8;

static __device__ __forceinline__ unsigned short f2bf(float f) {
  unsigned int u = __float_as_uint(f);
  unsigned int r = (u + 0x7fffu + ((u >> 16) & 1u)) >> 16;
  return (unsigned short)r;
}

// ---------------------------------------------------------------------------
// Kernel 1: all the small MLPs (unchanged — proven).
// ---------------------------------------------------------------------------
__global__ __launch_bounds__(256) void params_kernel(
    const float* __restrict__ para, const float* __restrict__ style,
    const float* __restrict__ cw,  const float* __restrict__ cb,
    const float* __restrict__ sw,  const float* __restrict__ sb,
    const float* __restrict__ rw,  const float* __restrict__ rb,
    const float* __restrict__ tw,  const float* __restrict__ tb,
    const float* __restrict__ a1w, const float* __restrict__ a1b,
    const float* __restrict__ g1w, const float* __restrict__ g1b,
    const float* __restrict__ b1w, const float* __restrict__ b1b,
    const float* __restrict__ a2w, const float* __restrict__ a2b,
    const float* __restrict__ g2w, const float* __restrict__ g2b,
    const float* __restrict__ b2w, const float* __restrict__ b2b,
    float* __restrict__ warp, float* __restrict__ gb1, float* __restrict__ gb2)
{
  __shared__ float s_para[256], s_sty[256], s_pc[256], s_a1[128], s_a2[128];
  int b = blockIdx.x;
  int t = threadIdx.x;
  s_para[t] = para[b*256 + t];
  s_sty[t]  = style[b*256 + t];
  __syncthreads();

  float acc = cb[t];
  for (int i = 0; i < 256; i++) acc = fmaf(s_para[i], cw[i*256 + t], acc);
  s_pc[t] = fmaxf(acc, 0.f);

  if (t < 128) {
    float a = a1b[t];
    for (int i = 0; i < 256; i++) a = fmaf(s_sty[i], a1w[i*128 + t], a);
    s_a1[t] = fmaxf(a, 0.f);
  } else {
    int u = t - 128;
    float a = a2b[u];
    for (int i = 0; i < 256; i++) a = fmaf(s_sty[i], a2w[i*128 + u], a);
    s_a2[u] = fmaxf(a, 0.f);
  }
  __syncthreads();

  int c = t;
  float ds = sb[c], dr = rb[c], dtx = tb[2*c], dty = tb[2*c + 1];
  for (int i = 0; i < 256; i++) {
    float p = s_pc[i];
    ds  = fmaf(p, sw[i*256 + c], ds);
    dr  = fmaf(p, rw[i*256 + c], dr);
    dtx = fmaf(p, tw[i*512 + 2*c], dtx);
    dty = fmaf(p, tw[i*512 + 2*c + 1], dty);
  }
  float scale = 2.f / (1.f + expf(-ds));
  float ang = tanhf(dr) * 3.14159f;
  float sn, cs;
  sincosf(ang, &sn, &cs);
  int bc = b*256 + c;
  warp[bc*4 + 0] = cs * scale;
  warp[bc*4 + 1] = sn * scale;
  warp[bc*4 + 2] = tanhf(dtx);
  warp[bc*4 + 3] = tanhf(dty);

  float g1 = g1b[c], be1 = b1b[c], g2 = g2b[c], be2 = b2b[c];
  for (int i = 0; i < 128; i++) {
    float a = s_a1[i];
    g1  = fmaf(a, g1w[i*256 + c], g1);
    be1 = fmaf(a, b1w[i*256 + c], be1);
  }
  for (int i = 0; i < 128; i++) {
    float a = s_a2[i];
    g2  = fmaf(a, g2w[i*256 + c], g2);
    be2 = fmaf(a, b2w[i*256 + c], be2);
  }
  gb1[bc*2] = g1; gb1[bc*2 + 1] = be1;
  gb2[bc*2] = g2; gb2[bc*2 + 1] = be2;
}

// ---------------------------------------------------------------------------
// Kernel 2: weight preconversion into per-lane MFMA fragment order (proven).
// wf[coblk4][ks16][tap9][m2][lane64][8]
// ---------------------------------------------------------------------------
__global__ __launch_bounds__(256) void prep_weights_kernel(
    const float* __restrict__ w1, const float* __restrict__ w2,
    unsigned short* __restrict__ wf1, unsigned short* __restrict__ wf2)
{
  int co = blockIdx.x & 255;
  const float* src = (blockIdx.x < 256) ? w1 : w2;
  unsigned short* dst = (blockIdx.x < 256) ? wf1 : wf2;
  int ci = threadIdx.x;
  int coblk = co >> 6, m = (co >> 5) & 1;
  int l = (co & 31) | (((ci >> 3) & 1) << 5);
  int ks = ci >> 4, j = ci & 7;
  const float* p = src + ((size_t)co * 256 + ci) * 9;
  #pragma unroll
  for (int tap = 0; tap < 9; tap++) {
    size_t idx = (((size_t)((coblk * 16 + ks) * 9 + tap) * 2 + m) * 64 + l) * 8 + j;
    dst[idx] = f2bf(p[tap]);
  }
}

// ---------------------------------------------------------------------------
// Kernel 3: AdaAT trilinear warp, quarter-plane blocks (unchanged from R5).
// ---------------------------------------------------------------------------
__global__ __launch_bounds__(256) void adaat_kernel(
    const float* __restrict__ fm, const float* __restrict__ warp,
    float* __restrict__ tout, float* __restrict__ part)
{
  int bid = blockIdx.x;
  int bc = bid >> 2, q = bid & 3;
  int b = bc >> 8, c = bc & 255;
  float csc = warp[bc*4 + 0], ssc = warp[bc*4 + 1];
  float tx = warp[bc*4 + 2], ty = warp[bc*4 + 3];

  const float axw = csc * (2.f / 95.f) * 48.f;
  const float axh = -ssc * (2.f / 95.f) * 48.f;
  const float ax0 = 48.f * (tx - csc + ssc) + 47.5f;
  const float ayw = ssc * (2.f / 95.f) * 48.f;
  const float ayh = csc * (2.f / 95.f) * 48.f;
  const float ay0 = 48.f * (ty - ssc - csc) + 47.5f;

  float gzc = 2.f * c / 255.f - 1.f;
  float iz = ((gzc + 1.f) * 256.f - 1.f) * 0.5f;
  float z0f = floorf(iz);
  float wz = iz - z0f;
  int z0 = (int)z0f;
  const float* p0 = (z0 >= 0 && z0 < 256) ? fm + (size_t)(b*256 + z0) * HWN : nullptr;
  const float* p1 = (z0 + 1 < 256) ? fm + (size_t)(b*256 + z0 + 1) * HWN : nullptr;
  float wpl0 = 1.f - wz, wpl1 = wz;

  int t = threadIdx.x;
  int h = q * 24 + t / 96;
  int w = t % 96;
  float* dst = tout + (size_t)bc * HWN + q * 2304 + t;

  float sum = 0.f, sumsq = 0.f;
  #pragma unroll
  for (int k = 0; k < 9; k++) {
    float fw = (float)w, fh = (float)h;
    float ix = fmaf(axw, fw, fmaf(axh, fh, ax0));
    float iy = fmaf(ayw, fw, fmaf(ayh, fh, ay0));
    float x0f = floorf(ix), y0f = floorf(iy);
    float wx = ix - x0f, wy = iy - y0f;
    int x0 = (int)x0f, y0 = (int)y0f;
    bool vx0 = (unsigned)x0 < 96u, vx1 = (unsigned)(x0 + 1) < 96u;
    bool vy0 = (unsigned)y0 < 96u, vy1 = (unsigned)(y0 + 1) < 96u;
    float w00 = (1.f - wy) * (1.f - wx), w01 = (1.f - wy) * wx;
    float w10 = wy * (1.f - wx),         w11 = wy * wx;
    int o00 = y0 * 96 + x0;
    float v = 0.f;
    if (p0) {
      float a00 = (vy0 && vx0) ? p0[o00]      : 0.f;
      float a01 = (vy0 && vx1) ? p0[o00 + 1]  : 0.f;
      float a10 = (vy1 && vx0) ? p0[o00 + 96] : 0.f;
      float a11 = (vy1 && vx1) ? p0[o00 + 97] : 0.f;
      v += wpl0 * (w00*a00 + w01*a01 + w10*a10 + w11*a11);
    }
    if (p1) {
      float a00 = (vy0 && vx0) ? p1[o00]      : 0.f;
      float a01 = (vy0 && vx1) ? p1[o00 + 1]  : 0.f;
      float a10 = (vy1 && vx0) ? p1[o00 + 96] : 0.f;
      float a11 = (vy1 && vx1) ? p1[o00 + 97] : 0.f;
      v += wpl1 * (w00*a00 + w01*a01 + w10*a10 + w11*a11);
    }
    dst[k * 256] = v;
    sum += v;
    sumsq += v * v;
    int wn = w + 64;
    int carry = (wn >= 96) ? 1 : 0;
    w = wn - (carry ? 96 : 0);
    h += 2 + carry;
  }

  for (int off = 32; off > 0; off >>= 1) {
    sum   += __shfl_down(sum, off, 64);
    sumsq += __shfl_down(sumsq, off, 64);
  }
  __shared__ float rs[4], rq[4];
  int lane = t & 63, wvi = t >> 6;
  if (lane == 0) { rs[wvi] = sum; rq[wvi] = sumsq; }
  __syncthreads();
  if (t == 0) {
    part[bid * 2]     = rs[0] + rs[1] + rs[2] + rs[3];
    part[bid * 2 + 1] = rq[0] + rq[1] + rq[2] + rq[3];
  }
}

// ---------------------------------------------------------------------------
// Kernel 3b: combine quarter partials -> nrm1 scale/bias (unchanged).
// ---------------------------------------------------------------------------
__global__ __launch_bounds__(256) void finalize_nrm_kernel(
    const float* __restrict__ part, const float* __restrict__ gb,
    float* __restrict__ nrm)
{
  int bc = blockIdx.x * 256 + threadIdx.x;
  float S = 0.f, Q = 0.f;
  #pragma unroll
  for (int q = 0; q < 4; q++) {
    S += part[(bc * 4 + q) * 2];
    Q += part[(bc * 4 + q) * 2 + 1];
  }
  float m = S * (1.f / 9216.f);
  float var = Q * (1.f / 9216.f) - m * m;
  float rstd = rsqrtf(var + 1e-5f);
  float sc = (1.f + gb[bc*2]) * rstd;
  nrm[bc*2] = sc;
  nrm[bc*2 + 1] = gb[bc*2 + 1] - m * sc;
}

// ---------------------------------------------------------------------------
// Kernel 4: per-plane stats of conv1 output (for AdaIN-2) — unchanged.
// ---------------------------------------------------------------------------
__global__ __launch_bounds__(256) void stats_kernel(
    const float* __restrict__ x, const float* __restrict__ gb,
    float* __restrict__ nrm)
{
  int bc = blockIdx.x;
  const float4* p = (const float4*)(x + (size_t)bc * HWN);
  float sum = 0.f, sumsq = 0.f;
  for (int i = threadIdx.x; i < HWN / 4; i += 256) {
    float4 v = p[i];
    sum   += v.x + v.y + v.z + v.w;
    sumsq += v.x*v.x + v.y*v.y + v.z*v.z + v.w*v.w;
  }
  for (int off = 32; off > 0; off >>= 1) {
    sum   += __shfl_down(sum, off, 64);
    sumsq += __shfl_down(sumsq, off, 64);
  }
  __shared__ float rs[4], rq[4];
  int lane = threadIdx.x & 63, wv = threadIdx.x >> 6;
  if (lane == 0) { rs[wv] = sum; rq[wv] = sumsq; }
  __syncthreads();
  if (threadIdx.x == 0) {
    float S = rs[0] + rs[1] + rs[2] + rs[3];
    float Q = rq[0] + rq[1] + rq[2] + rq[3];
    float m = S * (1.f / 9216.f);
    float var = Q * (1.f / 9216.f) - m * m;
    float rstd = rsqrtf(var + 1e-5f);
    float sc = (1.f + gb[bc*2]) * rstd;
    nrm[bc*2] = sc;
    nrm[bc*2 + 1] = gb[bc*2 + 1] - m * sc;
  }
}

// ---------------------------------------------------------------------------
// Kernel 5: transpose + fused AdaIN(scale/bias) + lrelu + bf16 cvt (unchanged).
// ---------------------------------------------------------------------------
__global__ __launch_bounds__(256) void transpose_norm_kernel(
    const float* __restrict__ x, const float* __restrict__ nrm,
    unsigned short* __restrict__ xt)
{
  int hi = blockIdx.x;
  int b  = blockIdx.y;
  unsigned short* dst = xt + (size_t)b * XT_PLANE + (size_t)hi * (XT_W * CH);
  int t = threadIdx.x;
  int h = hi - 1;
  u16x8 zero = {0,0,0,0,0,0,0,0};
  if (h < 0 || h >= 96) {
    for (int c = t; c < XT_W * CH / 8; c += 256) ((u16x8*)dst)[c] = zero;
    return;
  }
  __shared__ unsigned short s[96 * 256];  // [w][ci]
  int ci = t;
  float sc = nrm[(b*256 + ci)*2], bi = nrm[(b*256 + ci)*2 + 1];
  const float* src = x + ((size_t)(b*256 + ci)) * HWN + h * 96;
  for (int wg = 0; wg < 24; wg++) {
    float4 v = *(const float4*)(src + wg * 4);
    float y0 = fmaf(v.x, sc, bi); y0 = (y0 >= 0.f) ? y0 : 0.2f * y0;
    float y1 = fmaf(v.y, sc, bi); y1 = (y1 >= 0.f) ? y1 : 0.2f * y1;
    float y2 = fmaf(v.z, sc, bi); y2 = (y2 >= 0.f) ? y2 : 0.2f * y2;
    float y3 = fmaf(v.w, sc, bi); y3 = (y3 >= 0.f) ? y3 : 0.2f * y3;
    s[(wg*4 + 0) * 256 + ci] = f2bf(y0);
    s[(wg*4 + 1) * 256 + ci] = f2bf(y1);
    s[(wg*4 + 2) * 256 + ci] = f2bf(y2);
    s[(wg*4 + 3) * 256 + ci] = f2bf(y3);
  }
  __syncthreads();
  for (int c = t; c < 98 * 32; c += 256) {
    int w = c >> 5, p = c & 31;
    u16x8 v = zero;
    if (w >= 1 && w <= 96) v = *(const u16x8*)&s[(w - 1) * 256 + p * 8];
    ((u16x8*)dst)[c] = v;
  }
}

// ---------------------------------------------------------------------------
// Kernel 6 (R7): 3x3 conv 256->256, bf16 MFMA. 4-wave blocks, wave = 32co x
// 1 row x 96 px. Tile 64co x 2 rows. Grid (48,4,4)=768 = 3 blocks/CU =
// 12 waves/CU = 3 waves/SIMD (2x R4/R6). Per-ky batched ds_reads, weight
// register rotation, single barrier per K-step, LDS dbuf 25KB.
// ---------------------------------------------------------------------------
__global__ __launch_bounds__(256, 3) void conv_mfma_kernel(
    const unsigned short* __restrict__ xt,   // [4][98][98][256] bf16
    const unsigned short* __restrict__ wf,   // frag layout (see prep)
    const float* __restrict__ cb,
    float* __restrict__ out)                 // [4][256][96][96] f32
{
  // slab: 4 xt rows (h0..h0+3), chunk c=(r*2+half)*98+w, 784 chunks x 16B
  __shared__ __align__(16) unsigned short s_in[2][784 * 8];

  int hb = blockIdx.x, coblk = blockIdx.y, b = blockIdx.z;
  int co0 = coblk * 64, h0 = hb * 2;
  int t = threadIdx.x, lane = t & 63, wv = t >> 6;
  int rw = wv >> 1, mh = wv & 1;       // wave -> (row, co-half)
  int l31 = lane & 31, lhi = lane >> 5;
  const unsigned short* xtb = xt + (size_t)b * XT_PLANE;

  // stage descriptors: chunk c = t + i*256 (i<3 all threads, i=3 t<16)
  int pre_g[4];
  #pragma unroll
  for (int i = 0; i < 4; i++) {
    int c = t + i * 256;
    if (c < 784) {
      int r = c / 196;
      int rem = c - r * 196;
      int half = rem / 98;
      int w = rem - half * 98;
      pre_g[i] = ((h0 + r) * 98 + w) * 256 + half * 8;
    }
  }

  f32x16 acc[3];
  #pragma unroll
  for (int n = 0; n < 3; n++)
    #pragma unroll
    for (int i = 0; i < 16; i++) acc[n][i] = 0.f;

  // per-lane A-frag base for this wave's co-half
  const unsigned short* wfb = wf + (size_t)(coblk * 16) * 9216 + mh * 512 + lane * 8;

  // prologue: stage ks=0 -> buf0; load wa(ks=0); issue stage ks=1
  u16x8 stg[4];
  #pragma unroll
  for (int i = 0; i < 3; i++) stg[i] = *(const u16x8*)(xtb + pre_g[i]);
  if (t < 16) stg[3] = *(const u16x8*)(xtb + pre_g[3]);
  #pragma unroll
  for (int i = 0; i < 3; i++) *(u16x8*)(&s_in[0][(t + i * 256) * 8]) = stg[i];
  if (t < 16) *(u16x8*)(&s_in[0][(t + 3 * 256) * 8]) = stg[3];

  bfrag wa[9];
  #pragma unroll
  for (int tap = 0; tap < 9; tap++) wa[tap] = *(const bfrag*)(wfb + tap * 1024);

  #pragma unroll
  for (int i = 0; i < 3; i++) stg[i] = *(const u16x8*)(xtb + pre_g[i] + 16);
  if (t < 16) stg[3] = *(const u16x8*)(xtb + pre_g[3] + 16);
  __syncthreads();

  int buf = 0;
  #pragma unroll 1
  for (int ks = 0; ks < 16; ks++) {
    const unsigned short* sb = s_in[buf];
    int ksn = (ks < 15) ? (ks + 1) : 15;
    const unsigned short* wkn = wfb + (size_t)ksn * 9216;
    #pragma unroll
    for (int ky = 0; ky < 3; ky++) {
      const unsigned short* srow = sb + (((rw + ky) * 2 + lhi) * 98) * 8;
      // batched reads: all 9 B-frags for this ky
      bfrag bb[9];
      #pragma unroll
      for (int kx = 0; kx < 3; kx++)
        #pragma unroll
        for (int n = 0; n < 3; n++)
          bb[kx * 3 + n] = *(const bfrag*)(srow + (n * 32 + kx + l31) * 8);
      #pragma unroll
      for (int kx = 0; kx < 3; kx++) {
        int tap = ky * 3 + kx;
        acc[0] = __builtin_amdgcn_mfma_f32_32x32x16_bf16(wa[tap], bb[kx*3+0], acc[0], 0, 0, 0);
        acc[1] = __builtin_amdgcn_mfma_f32_32x32x16_bf16(wa[tap], bb[kx*3+1], acc[1], 0, 0, 0);
        acc[2] = __builtin_amdgcn_mfma_f32_32x32x16_bf16(wa[tap], bb[kx*3+2], acc[2], 0, 0, 0);
        // rotate: reload this tap's frag for the NEXT K-step (full-step cover)
        wa[tap] = *(const bfrag*)(wkn + tap * 1024);
      }
    }
    // write staged ks+1 into other buffer; issue stage ks+2; one barrier
    if (ks < 15) {
      unsigned short* sn = s_in[buf ^ 1];
      #pragma unroll
      for (int i = 0; i < 3; i++) *(u16x8*)(&sn[(t + i * 256) * 8]) = stg[i];
      if (t < 16) *(u16x8*)(&sn[(t + 3 * 256) * 8]) = stg[3];
      if (ks < 14) {
        int off = (ks + 2) * 16;
        #pragma unroll
        for (int i = 0; i < 3; i++) stg[i] = *(const u16x8*)(xtb + pre_g[i] + off);
        if (t < 16) stg[3] = *(const u16x8*)(xtb + pre_g[3] + off);
      }
    }
    __syncthreads();
    buf ^= 1;
  }

  // epilogue: C col = lane&31 (px), row = (r&3)+8*(r>>2)+4*(lane>>5) (co)
  int h = h0 + rw;
  #pragma unroll
  for (int r = 0; r < 16; r++) {
    int row = (r & 3) + 8 * (r >> 2) + 4 * lhi;
    int co = co0 + mh * 32 + row;
    float bv = cb[co];
    size_t base = ((size_t)(b * 256 + co) * 96 + h) * 96;
    #pragma unroll
    for (int n = 0; n < 3; n++) {
      out[base + n * 32 + l31] = acc[n][r] + bv;
    }
  }
}

// ---------------------------------------------------------------------------
extern "C" void kernel_launch(void* const* d_in, const int* in_sizes, int n_in,
                              void* d_out, int out_size, void* d_ws, size_t ws_size,
                              hipStream_t stream)
{
  const float* fm    = (const float*)d_in[0];
  const float* para  = (const float*)d_in[1];
  const float* style = (const float*)d_in[2];
  const float* cw  = (const float*)d_in[3];
  const float* cb  = (const float*)d_in[4];
  const float* sw  = (const float*)d_in[5];
  const float* sb  = (const float*)d_in[6];
  const float* rw  = (const float*)d_in[7];
  const float* rb  = (const float*)d_in[8];
  const float* tw  = (const float*)d_in[9];
  const float* tb  = (const float*)d_in[10];
  const float* a1w = (const float*)d_in[11];
  const float* a1b = (const float*)d_in[12];
  const float* g1w = (const float*)d_in[13];
  const float* g1b = (const float*)d_in[14];
  const float* b1w = (const float*)d_in[15];
  const float* b1b = (const float*)d_in[16];
  const float* c1w = (const float*)d_in[17];
  const float* c1b = (const float*)d_in[18];
  const float* a2w = (const float*)d_in[19];
  const float* a2b = (const float*)d_in[20];
  const float* g2w = (const float*)d_in[21];
  const float* g2b = (const float*)d_in[22];
  const float* b2w = (const float*)d_in[23];
  const float* b2b = (const float*)d_in[24];
  const float* c2w = (const float*)d_in[25];
  const float* c2b = (const float*)d_in[26];

  float* outf = (float*)d_out;

  unsigned short* xtbuf = (unsigned short*)d_ws;                 // 4*98*98*256 bf16
  unsigned short* wf1   = xtbuf + (size_t)BATCH * XT_PLANE;      // 589824
  unsigned short* wf2   = wf1 + 9 * 256 * 256;
  float* fws  = (float*)(wf2 + 9 * 256 * 256);
  float* warp = fws;                   // 4096
  float* gb1  = warp + 4 * 1024;       // 2048
  float* gb2  = gb1 + 2 * 1024;        // 2048
  float* nrm1 = gb2 + 2 * 1024;        // 2048
  float* nrm2 = nrm1 + 2 * 1024;       // 2048
  float* part = nrm2 + 2 * 1024;       // 4096*2 floats

  params_kernel<<<4, 256, 0, stream>>>(para, style, cw, cb, sw, sb, rw, rb, tw, tb,
      a1w, a1b, g1w, g1b, b1w, b1b, a2w, a2b, g2w, g2b, b2w, b2b, warp, gb1, gb2);
  prep_weights_kernel<<<512, 256, 0, stream>>>(c1w, c2w, wf1, wf2);
  adaat_kernel<<<4096, 256, 0, stream>>>(fm, warp, outf, part);
  finalize_nrm_kernel<<<4, 256, 0, stream>>>(part, gb1, nrm1);
  transpose_norm_kernel<<<dim3(98, 4), 256, 0, stream>>>(outf, nrm1, xtbuf);
  conv_mfma_kernel<<<dim3(48, 4, 4), 256, 0, stream>>>(xtbuf, wf1, c1b, outf);
  stats_kernel<<<1024, 256, 0, stream>>>(outf, gb2, nrm2);
  transpose_norm_kernel<<<dim3(98, 4), 256, 0, stream>>>(outf, nrm2, xtbuf);
  conv_mfma_kernel<<<dim3(48, 4, 4), 256, 0, stream>>>(xtbuf, wf2, c2b, outf);
}

// Round 8
// 221.329 us; speedup vs baseline: 1.2196x; 1.1644x over previous
//
#include <hip/hip_runtime.h>
#include <hip/hip_bf16.h>
#include <cstddef>

#define BATCH 4
#define CH 256
#define HH 96
#define WW 96
#define HWN (HH*WW)               // 9216
#define NTOT (BATCH*CH*HWN)       // 9437184
#define XT_H 98
#define XT_W 98
#define XT_PLANE (XT_H*XT_W*CH)   // per-batch elements in xt (bf16)

typedef __attribute__((ext_vector_type(16))) float f32x16;
typedef __attribute__((ext_vector_type(8))) __bf16 bfrag;
typedef __attribute__((ext_vector_type(8))) unsigned short u16x8;

static __device__ __forceinline__ unsigned short f2bf(float f) {
  unsigned int u = __float_as_uint(f);
  unsigned int r = (u + 0x7fffu + ((u >> 16) & 1u)) >> 16;
  return (unsigned short)r;
}

// ---------------------------------------------------------------------------
// Kernel 1: all the small MLPs (unchanged — proven).
// ---------------------------------------------------------------------------
__global__ __launch_bounds__(256) void params_kernel(
    const float* __restrict__ para, const float* __restrict__ style,
    const float* __restrict__ cw,  const float* __restrict__ cb,
    const float* __restrict__ sw,  const float* __restrict__ sb,
    const float* __restrict__ rw,  const float* __restrict__ rb,
    const float* __restrict__ tw,  const float* __restrict__ tb,
    const float* __restrict__ a1w, const float* __restrict__ a1b,
    const float* __restrict__ g1w, const float* __restrict__ g1b,
    const float* __restrict__ b1w, const float* __restrict__ b1b,
    const float* __restrict__ a2w, const float* __restrict__ a2b,
    const float* __restrict__ g2w, const float* __restrict__ g2b,
    const float* __restrict__ b2w, const float* __restrict__ b2b,
    float* __restrict__ warp, float* __restrict__ gb1, float* __restrict__ gb2)
{
  __shared__ float s_para[256], s_sty[256], s_pc[256], s_a1[128], s_a2[128];
  int b = blockIdx.x;
  int t = threadIdx.x;
  s_para[t] = para[b*256 + t];
  s_sty[t]  = style[b*256 + t];
  __syncthreads();

  float acc = cb[t];
  for (int i = 0; i < 256; i++) acc = fmaf(s_para[i], cw[i*256 + t], acc);
  s_pc[t] = fmaxf(acc, 0.f);

  if (t < 128) {
    float a = a1b[t];
    for (int i = 0; i < 256; i++) a = fmaf(s_sty[i], a1w[i*128 + t], a);
    s_a1[t] = fmaxf(a, 0.f);
  } else {
    int u = t - 128;
    float a = a2b[u];
    for (int i = 0; i < 256; i++) a = fmaf(s_sty[i], a2w[i*128 + u], a);
    s_a2[u] = fmaxf(a, 0.f);
  }
  __syncthreads();

  int c = t;
  float ds = sb[c], dr = rb[c], dtx = tb[2*c], dty = tb[2*c + 1];
  for (int i = 0; i < 256; i++) {
    float p = s_pc[i];
    ds  = fmaf(p, sw[i*256 + c], ds);
    dr  = fmaf(p, rw[i*256 + c], dr);
    dtx = fmaf(p, tw[i*512 + 2*c], dtx);
    dty = fmaf(p, tw[i*512 + 2*c + 1], dty);
  }
  float scale = 2.f / (1.f + expf(-ds));
  float ang = tanhf(dr) * 3.14159f;
  float sn, cs;
  sincosf(ang, &sn, &cs);
  int bc = b*256 + c;
  warp[bc*4 + 0] = cs * scale;
  warp[bc*4 + 1] = sn * scale;
  warp[bc*4 + 2] = tanhf(dtx);
  warp[bc*4 + 3] = tanhf(dty);

  float g1 = g1b[c], be1 = b1b[c], g2 = g2b[c], be2 = b2b[c];
  for (int i = 0; i < 128; i++) {
    float a = s_a1[i];
    g1  = fmaf(a, g1w[i*256 + c], g1);
    be1 = fmaf(a, b1w[i*256 + c], be1);
  }
  for (int i = 0; i < 128; i++) {
    float a = s_a2[i];
    g2  = fmaf(a, g2w[i*256 + c], g2);
    be2 = fmaf(a, b2w[i*256 + c], be2);
  }
  gb1[bc*2] = g1; gb1[bc*2 + 1] = be1;
  gb2[bc*2] = g2; gb2[bc*2 + 1] = be2;
}

// ---------------------------------------------------------------------------
// Kernel 2: weight preconversion into per-lane MFMA fragment order (proven).
// wf[coblk4][ks16][tap9][m2][lane64][8]
// ---------------------------------------------------------------------------
__global__ __launch_bounds__(256) void prep_weights_kernel(
    const float* __restrict__ w1, const float* __restrict__ w2,
    unsigned short* __restrict__ wf1, unsigned short* __restrict__ wf2)
{
  int co = blockIdx.x & 255;
  const float* src = (blockIdx.x < 256) ? w1 : w2;
  unsigned short* dst = (blockIdx.x < 256) ? wf1 : wf2;
  int ci = threadIdx.x;
  int coblk = co >> 6, m = (co >> 5) & 1;
  int l = (co & 31) | (((ci >> 3) & 1) << 5);
  int ks = ci >> 4, j = ci & 7;
  const float* p = src + ((size_t)co * 256 + ci) * 9;
  #pragma unroll
  for (int tap = 0; tap < 9; tap++) {
    size_t idx = (((size_t)((coblk * 16 + ks) * 9 + tap) * 2 + m) * 64 + l) * 8 + j;
    dst[idx] = f2bf(p[tap]);
  }
}

// ---------------------------------------------------------------------------
// Kernel 3 (R8): AdaAT warp via LDS gather of the z-FUSED plane.
// pz = (1-wz)*p0 + wz*p1 staged to LDS once per (b,c); per-px bilinear is
// 4 ds_read_b32 + ~25 VALU. One block per (b,c); writes nrm1 directly.
// LDS row stride 100 (16B aligned; decouples y-stride bank aliasing).
// ---------------------------------------------------------------------------
__global__ __launch_bounds__(256) void adaat_kernel(
    const float* __restrict__ fm, const float* __restrict__ warp,
    const float* __restrict__ gb1, float* __restrict__ tout,
    float* __restrict__ nrm1)
{
  __shared__ float s[96 * 100];
  int bc = blockIdx.x;
  int b = bc >> 8, c = bc & 255;
  float csc = warp[bc*4 + 0], ssc = warp[bc*4 + 1];
  float tx = warp[bc*4 + 2], ty = warp[bc*4 + 3];

  // affine px->sample: ix = axw*w + axh*h + ax0 (iy analogous)
  const float axw = csc * (96.f / 95.f);
  const float axh = -ssc * (96.f / 95.f);
  const float ax0 = 48.f * (tx - csc + ssc) + 47.5f;
  const float ayw = ssc * (96.f / 95.f);
  const float ayh = csc * (96.f / 95.f);
  const float ay0 = 48.f * (ty - ssc - csc) + 47.5f;

  float iz = 256.f * (float)c / 255.f - 0.5f;
  float z0f = floorf(iz);
  float wz = iz - z0f;
  int z0 = (int)z0f;
  const float* p0 = (z0 >= 0) ? fm + (size_t)(b*256 + z0) * HWN : nullptr;
  const float* p1 = (z0 + 1 < 256) ? fm + (size_t)(b*256 + z0 + 1) * HWN : nullptr;
  float w0 = 1.f - wz, w1 = wz;

  int t = threadIdx.x;
  // stage fused plane: 2304 float4 chunks, 24 chunks per row of 96
  const float4* q0 = (const float4*)p0;
  const float4* q1 = (const float4*)p1;
  for (int i = t; i < 2304; i += 256) {
    int row = i / 24, col = i - row * 24;
    float4 r = {0.f, 0.f, 0.f, 0.f};
    if (q0) {
      float4 v = q0[i];
      r.x = w0 * v.x; r.y = w0 * v.y; r.z = w0 * v.z; r.w = w0 * v.w;
    }
    if (q1) {
      float4 v = q1[i];
      r.x = fmaf(w1, v.x, r.x); r.y = fmaf(w1, v.y, r.y);
      r.z = fmaf(w1, v.z, r.z); r.w = fmaf(w1, v.w, r.w);
    }
    *(float4*)&s[row * 100 + col * 4] = r;
  }
  __syncthreads();

  int h = t / 96, w = t - (t / 96) * 96;
  float* dst = tout + (size_t)bc * HWN;
  float sum = 0.f, sumsq = 0.f;
  #pragma unroll
  for (int k = 0; k < 36; k++) {
    float ix = fmaf(axw, (float)w, fmaf(axh, (float)h, ax0));
    float iy = fmaf(ayw, (float)w, fmaf(ayh, (float)h, ay0));
    float x0f = floorf(ix), y0f = floorf(iy);
    float wx = ix - x0f, wy = iy - y0f;
    int x0 = (int)x0f, y0 = (int)y0f;
    int x0c = min(max(x0, 0), 95), x1c = min(max(x0 + 1, 0), 95);
    int y0c = min(max(y0, 0), 95), y1c = min(max(y0 + 1, 0), 95);
    bool vx0 = (unsigned)x0 < 96u, vx1 = (unsigned)(x0 + 1) < 96u;
    bool vy0 = (unsigned)y0 < 96u, vy1 = (unsigned)(y0 + 1) < 96u;
    float a00 = s[y0c * 100 + x0c], a01 = s[y0c * 100 + x1c];
    float a10 = s[y1c * 100 + x0c], a11 = s[y1c * 100 + x1c];
    float wxm = 1.f - wx, wym = 1.f - wy;
    float w00 = (vy0 && vx0) ? wym * wxm : 0.f;
    float w01 = (vy0 && vx1) ? wym * wx  : 0.f;
    float w10 = (vy1 && vx0) ? wy * wxm  : 0.f;
    float w11 = (vy1 && vx1) ? wy * wx   : 0.f;
    float v = w00 * a00;
    v = fmaf(w01, a01, v);
    v = fmaf(w10, a10, v);
    v = fmaf(w11, a11, v);
    dst[t + k * 256] = v;
    sum += v;
    sumsq = fmaf(v, v, sumsq);
    int wn = w + 64;
    int carry = (wn >= 96) ? 1 : 0;
    w = wn - (carry ? 96 : 0);
    h += 2 + carry;
  }

  for (int off = 32; off > 0; off >>= 1) {
    sum   += __shfl_down(sum, off, 64);
    sumsq += __shfl_down(sumsq, off, 64);
  }
  __shared__ float rs[4], rq[4];
  int lane = t & 63, wvi = t >> 6;
  if (lane == 0) { rs[wvi] = sum; rq[wvi] = sumsq; }
  __syncthreads();
  if (t == 0) {
    float S = rs[0] + rs[1] + rs[2] + rs[3];
    float Q = rq[0] + rq[1] + rq[2] + rq[3];
    float m = S * (1.f / 9216.f);
    float var = Q * (1.f / 9216.f) - m * m;
    float rstd = rsqrtf(var + 1e-5f);
    float sc = (1.f + gb1[bc*2]) * rstd;
    nrm1[bc*2] = sc;
    nrm1[bc*2 + 1] = gb1[bc*2 + 1] - m * sc;
  }
}

// ---------------------------------------------------------------------------
// Kernel 4: per-plane stats of conv1 output (for AdaIN-2) — unchanged.
// ---------------------------------------------------------------------------
__global__ __launch_bounds__(256) void stats_kernel(
    const float* __restrict__ x, const float* __restrict__ gb,
    float* __restrict__ nrm)
{
  int bc = blockIdx.x;
  const float4* p = (const float4*)(x + (size_t)bc * HWN);
  float sum = 0.f, sumsq = 0.f;
  for (int i = threadIdx.x; i < HWN / 4; i += 256) {
    float4 v = p[i];
    sum   += v.x + v.y + v.z + v.w;
    sumsq += v.x*v.x + v.y*v.y + v.z*v.z + v.w*v.w;
  }
  for (int off = 32; off > 0; off >>= 1) {
    sum   += __shfl_down(sum, off, 64);
    sumsq += __shfl_down(sumsq, off, 64);
  }
  __shared__ float rs[4], rq[4];
  int lane = threadIdx.x & 63, wv = threadIdx.x >> 6;
  if (lane == 0) { rs[wv] = sum; rq[wv] = sumsq; }
  __syncthreads();
  if (threadIdx.x == 0) {
    float S = rs[0] + rs[1] + rs[2] + rs[3];
    float Q = rq[0] + rq[1] + rq[2] + rq[3];
    float m = S * (1.f / 9216.f);
    float var = Q * (1.f / 9216.f) - m * m;
    float rstd = rsqrtf(var + 1e-5f);
    float sc = (1.f + gb[bc*2]) * rstd;
    nrm[bc*2] = sc;
    nrm[bc*2 + 1] = gb[bc*2 + 1] - m * sc;
  }
}

// ---------------------------------------------------------------------------
// Kernel 5: transpose + fused AdaIN(scale/bias) + lrelu + bf16 cvt (unchanged).
// ---------------------------------------------------------------------------
__global__ __launch_bounds__(256) void transpose_norm_kernel(
    const float* __restrict__ x, const float* __restrict__ nrm,
    unsigned short* __restrict__ xt)
{
  int hi = blockIdx.x;
  int b  = blockIdx.y;
  unsigned short* dst = xt + (size_t)b * XT_PLANE + (size_t)hi * (XT_W * CH);
  int t = threadIdx.x;
  int h = hi - 1;
  u16x8 zero = {0,0,0,0,0,0,0,0};
  if (h < 0 || h >= 96) {
    for (int c = t; c < XT_W * CH / 8; c += 256) ((u16x8*)dst)[c] = zero;
    return;
  }
  __shared__ unsigned short s[96 * 256];  // [w][ci]
  int ci = t;
  float sc = nrm[(b*256 + ci)*2], bi = nrm[(b*256 + ci)*2 + 1];
  const float* src = x + ((size_t)(b*256 + ci)) * HWN + h * 96;
  for (int wg = 0; wg < 24; wg++) {
    float4 v = *(const float4*)(src + wg * 4);
    float y0 = fmaf(v.x, sc, bi); y0 = (y0 >= 0.f) ? y0 : 0.2f * y0;
    float y1 = fmaf(v.y, sc, bi); y1 = (y1 >= 0.f) ? y1 : 0.2f * y1;
    float y2 = fmaf(v.z, sc, bi); y2 = (y2 >= 0.f) ? y2 : 0.2f * y2;
    float y3 = fmaf(v.w, sc, bi); y3 = (y3 >= 0.f) ? y3 : 0.2f * y3;
    s[(wg*4 + 0) * 256 + ci] = f2bf(y0);
    s[(wg*4 + 1) * 256 + ci] = f2bf(y1);
    s[(wg*4 + 2) * 256 + ci] = f2bf(y2);
    s[(wg*4 + 3) * 256 + ci] = f2bf(y3);
  }
  __syncthreads();
  for (int c = t; c < 98 * 32; c += 256) {
    int w = c >> 5, p = c & 31;
    u16x8 v = zero;
    if (w >= 1 && w <= 96) v = *(const u16x8*)&s[(w - 1) * 256 + p * 8];
    ((u16x8*)dst)[c] = v;
  }
}

// ---------------------------------------------------------------------------
// Kernel 6: 3x3 conv 256->256, bf16 MFMA (unchanged from R7).
// ---------------------------------------------------------------------------
__global__ __launch_bounds__(256, 3) void conv_mfma_kernel(
    const unsigned short* __restrict__ xt,   // [4][98][98][256] bf16
    const unsigned short* __restrict__ wf,   // frag layout (see prep)
    const float* __restrict__ cb,
    float* __restrict__ out)                 // [4][256][96][96] f32
{
  __shared__ __align__(16) unsigned short s_in[2][784 * 8];

  int hb = blockIdx.x, coblk = blockIdx.y, b = blockIdx.z;
  int co0 = coblk * 64, h0 = hb * 2;
  int t = threadIdx.x, lane = t & 63, wv = t >> 6;
  int rw = wv >> 1, mh = wv & 1;
  int l31 = lane & 31, lhi = lane >> 5;
  const unsigned short* xtb = xt + (size_t)b * XT_PLANE;

  int pre_g[4];
  #pragma unroll
  for (int i = 0; i < 4; i++) {
    int c = t + i * 256;
    if (c < 784) {
      int r = c / 196;
      int rem = c - r * 196;
      int half = rem / 98;
      int w = rem - half * 98;
      pre_g[i] = ((h0 + r) * 98 + w) * 256 + half * 8;
    }
  }

  f32x16 acc[3];
  #pragma unroll
  for (int n = 0; n < 3; n++)
    #pragma unroll
    for (int i = 0; i < 16; i++) acc[n][i] = 0.f;

  const unsigned short* wfb = wf + (size_t)(coblk * 16) * 9216 + mh * 512 + lane * 8;

  u16x8 stg[4];
  #pragma unroll
  for (int i = 0; i < 3; i++) stg[i] = *(const u16x8*)(xtb + pre_g[i]);
  if (t < 16) stg[3] = *(const u16x8*)(xtb + pre_g[3]);
  #pragma unroll
  for (int i = 0; i < 3; i++) *(u16x8*)(&s_in[0][(t + i * 256) * 8]) = stg[i];
  if (t < 16) *(u16x8*)(&s_in[0][(t + 3 * 256) * 8]) = stg[3];

  bfrag wa[9];
  #pragma unroll
  for (int tap = 0; tap < 9; tap++) wa[tap] = *(const bfrag*)(wfb + tap * 1024);

  #pragma unroll
  for (int i = 0; i < 3; i++) stg[i] = *(const u16x8*)(xtb + pre_g[i] + 16);
  if (t < 16) stg[3] = *(const u16x8*)(xtb + pre_g[3] + 16);
  __syncthreads();

  int buf = 0;
  #pragma unroll 1
  for (int ks = 0; ks < 16; ks++) {
    const unsigned short* sb = s_in[buf];
    int ksn = (ks < 15) ? (ks + 1) : 15;
    const unsigned short* wkn = wfb + (size_t)ksn * 9216;
    #pragma unroll
    for (int ky = 0; ky < 3; ky++) {
      const unsigned short* srow = sb + (((rw + ky) * 2 + lhi) * 98) * 8;
      bfrag bb[9];
      #pragma unroll
      for (int kx = 0; kx < 3; kx++)
        #pragma unroll
        for (int n = 0; n < 3; n++)
          bb[kx * 3 + n] = *(const bfrag*)(srow + (n * 32 + kx + l31) * 8);
      #pragma unroll
      for (int kx = 0; kx < 3; kx++) {
        int tap = ky * 3 + kx;
        acc[0] = __builtin_amdgcn_mfma_f32_32x32x16_bf16(wa[tap], bb[kx*3+0], acc[0], 0, 0, 0);
        acc[1] = __builtin_amdgcn_mfma_f32_32x32x16_bf16(wa[tap], bb[kx*3+1], acc[1], 0, 0, 0);
        acc[2] = __builtin_amdgcn_mfma_f32_32x32x16_bf16(wa[tap], bb[kx*3+2], acc[2], 0, 0, 0);
        wa[tap] = *(const bfrag*)(wkn + tap * 1024);
      }
    }
    if (ks < 15) {
      unsigned short* sn = s_in[buf ^ 1];
      #pragma unroll
      for (int i = 0; i < 3; i++) *(u16x8*)(&sn[(t + i * 256) * 8]) = stg[i];
      if (t < 16) *(u16x8*)(&sn[(t + 3 * 256) * 8]) = stg[3];
      if (ks < 14) {
        int off = (ks + 2) * 16;
        #pragma unroll
        for (int i = 0; i < 3; i++) stg[i] = *(const u16x8*)(xtb + pre_g[i] + off);
        if (t < 16) stg[3] = *(const u16x8*)(xtb + pre_g[3] + off);
      }
    }
    __syncthreads();
    buf ^= 1;
  }

  int h = h0 + rw;
  #pragma unroll
  for (int r = 0; r < 16; r++) {
    int row = (r & 3) + 8 * (r >> 2) + 4 * lhi;
    int co = co0 + mh * 32 + row;
    float bv = cb[co];
    size_t base = ((size_t)(b * 256 + co) * 96 + h) * 96;
    #pragma unroll
    for (int n = 0; n < 3; n++) {
      out[base + n * 32 + l31] = acc[n][r] + bv;
    }
  }
}

// ---------------------------------------------------------------------------
extern "C" void kernel_launch(void* const* d_in, const int* in_sizes, int n_in,
                              void* d_out, int out_size, void* d_ws, size_t ws_size,
                              hipStream_t stream)
{
  const float* fm    = (const float*)d_in[0];
  const float* para  = (const float*)d_in[1];
  const float* style = (const float*)d_in[2];
  const float* cw  = (const float*)d_in[3];
  const float* cb  = (const float*)d_in[4];
  const float* sw  = (const float*)d_in[5];
  const float* sb  = (const float*)d_in[6];
  const float* rw  = (const float*)d_in[7];
  const float* rb  = (const float*)d_in[8];
  const float* tw  = (const float*)d_in[9];
  const float* tb  = (const float*)d_in[10];
  const float* a1w = (const float*)d_in[11];
  const float* a1b = (const float*)d_in[12];
  const float* g1w = (const float*)d_in[13];
  const float* g1b = (const float*)d_in[14];
  const float* b1w = (const float*)d_in[15];
  const float* b1b = (const float*)d_in[16];
  const float* c1w = (const float*)d_in[17];
  const float* c1b = (const float*)d_in[18];
  const float* a2w = (const float*)d_in[19];
  const float* a2b = (const float*)d_in[20];
  const float* g2w = (const float*)d_in[21];
  const float* g2b = (const float*)d_in[22];
  const float* b2w = (const float*)d_in[23];
  const float* b2b = (const float*)d_in[24];
  const float* c2w = (const float*)d_in[25];
  const float* c2b = (const float*)d_in[26];

  float* outf = (float*)d_out;

  unsigned short* xtbuf = (unsigned short*)d_ws;                 // 4*98*98*256 bf16
  unsigned short* wf1   = xtbuf + (size_t)BATCH * XT_PLANE;      // 589824
  unsigned short* wf2   = wf1 + 9 * 256 * 256;
  float* fws  = (float*)(wf2 + 9 * 256 * 256);
  float* warp = fws;                   // 4096
  float* gb1  = warp + 4 * 1024;       // 2048
  float* gb2  = gb1 + 2 * 1024;        // 2048
  float* nrm1 = gb2 + 2 * 1024;        // 2048
  float* nrm2 = nrm1 + 2 * 1024;       // 2048

  params_kernel<<<4, 256, 0, stream>>>(para, style, cw, cb, sw, sb, rw, rb, tw, tb,
      a1w, a1b, g1w, g1b, b1w, b1b, a2w, a2b, g2w, g2b, b2w, b2b, warp, gb1, gb2);
  prep_weights_kernel<<<512, 256, 0, stream>>>(c1w, c2w, wf1, wf2);
  adaat_kernel<<<1024, 256, 0, stream>>>(fm, warp, gb1, outf, nrm1);
  transpose_norm_kernel<<<dim3(98, 4), 256, 0, stream>>>(outf, nrm1, xtbuf);
  conv_mfma_kernel<<<dim3(48, 4, 4), 256, 0, stream>>>(xtbuf, wf1, c1b, outf);
  stats_kernel<<<1024, 256, 0, stream>>>(outf, gb2, nrm2);
  transpose_norm_kernel<<<dim3(98, 4), 256, 0, stream>>>(outf, nrm2, xtbuf);
  conv_mfma_kernel<<<dim3(48, 4, 4), 256, 0, stream>>>(xtbuf, wf2, c2b, outf);
}

// Round 9
// 191.327 us; speedup vs baseline: 1.4108x; 1.1568x over previous
//
#include <hip/hip_runtime.h>
#include <hip/hip_bf16.h>
#include <cstddef>

#define BATCH 4
#define CH 256
#define HH 96
#define WW 96
#define HWN (HH*WW)               // 9216
#define NTOT (BATCH*CH*HWN)       // 9437184
#define XT_H 98
#define XT_W 98
#define XT_PLANE (XT_H*XT_W*CH)   // per-batch elements in xt (bf16)

typedef __attribute__((ext_vector_type(16))) float f32x16;
typedef __attribute__((ext_vector_type(8))) __bf16 bfrag;
typedef __attribute__((ext_vector_type(8))) unsigned short u16x8;

static __device__ __forceinline__ unsigned short f2bf(float f) {
  unsigned int u = __float_as_uint(f);
  unsigned int r = (u + 0x7fffu + ((u >> 16) & 1u)) >> 16;
  return (unsigned short)r;
}

// ---------------------------------------------------------------------------
// Kernel 1a (R9): stage-1 GEMVs, wide-parallel.
// part 0..3: pc[64 outputs] (k-split 4x64); part 4: a1; part 5: a2 (k-split 2).
// ---------------------------------------------------------------------------
__global__ __launch_bounds__(256) void params_stage1_kernel(
    const float* __restrict__ para, const float* __restrict__ style,
    const float* __restrict__ cw,  const float* __restrict__ cb,
    const float* __restrict__ a1w, const float* __restrict__ a1b,
    const float* __restrict__ a2w, const float* __restrict__ a2b,
    float* __restrict__ pcbuf, float* __restrict__ a1buf, float* __restrict__ a2buf)
{
  __shared__ float s_in[256];
  __shared__ float red[256];
  int part = blockIdx.x, b = blockIdx.y, t = threadIdx.x;
  s_in[t] = (part < 4) ? para[b*256 + t] : style[b*256 + t];
  __syncthreads();
  if (part < 4) {
    int o = t & 63, ks = t >> 6, co0 = part * 64;
    const float* wcol = cw + co0 + o;
    float acc = 0.f;
    #pragma unroll 8
    for (int i = 0; i < 64; i++) {
      int k = ks * 64 + i;
      acc = fmaf(s_in[k], wcol[k * 256], acc);
    }
    red[t] = acc;
    __syncthreads();
    if (t < 64) {
      float s = red[t] + red[t + 64] + red[t + 128] + red[t + 192];
      pcbuf[b*256 + co0 + t] = fmaxf(s + cb[co0 + t], 0.f);
    }
  } else {
    const float* w  = (part == 4) ? a1w : a2w;
    const float* bb = (part == 4) ? a1b : a2b;
    float* outp = (part == 4) ? a1buf : a2buf;
    int o = t & 127, ks = t >> 7;
    const float* wcol = w + o;
    float acc = 0.f;
    #pragma unroll 8
    for (int i = 0; i < 128; i++) {
      int k = ks * 128 + i;
      acc = fmaf(s_in[k], wcol[k * 128], acc);
    }
    red[t] = acc;
    __syncthreads();
    if (t < 128) {
      float s = red[t] + red[t + 128];
      outp[b*128 + t] = fmaxf(s + bb[t], 0.f);
    }
  }
}

// ---------------------------------------------------------------------------
// Kernel 1b (R9): stage-2 — 8 dot-products per (b,c), 16 c per block,
// 16-way k-split per c, shuffle+LDS reduce, finalize transcendentals.
// ---------------------------------------------------------------------------
__global__ __launch_bounds__(256) void params_stage2_kernel(
    const float* __restrict__ pcbuf, const float* __restrict__ a1buf,
    const float* __restrict__ a2buf,
    const float* __restrict__ sw,  const float* __restrict__ sb,
    const float* __restrict__ rw,  const float* __restrict__ rb,
    const float* __restrict__ tw,  const float* __restrict__ tb,
    const float* __restrict__ g1w, const float* __restrict__ g1b,
    const float* __restrict__ b1w, const float* __restrict__ b1b,
    const float* __restrict__ g2w, const float* __restrict__ g2b,
    const float* __restrict__ b2w, const float* __restrict__ b2b,
    float* __restrict__ warp, float* __restrict__ gb1, float* __restrict__ gb2)
{
  __shared__ float s_pc[256], s_a1[128], s_a2[128];
  __shared__ float red[8][4][16];
  int co0 = blockIdx.x * 16, b = blockIdx.y, t = threadIdx.x;
  s_pc[t] = pcbuf[b*256 + t];
  if (t < 128) s_a1[t] = a1buf[b*128 + t];
  else         s_a2[t - 128] = a2buf[b*128 + (t - 128)];
  __syncthreads();

  int cl = t & 15, klane = t >> 4;
  int c = co0 + cl;
  const float2* tw2 = (const float2*)tw;
  float ds = 0.f, dr = 0.f, dtx = 0.f, dty = 0.f;
  float g1 = 0.f, be1 = 0.f, g2 = 0.f, be2 = 0.f;
  #pragma unroll 4
  for (int kk = 0; kk < 16; kk++) {
    int i = klane * 16 + kk;
    float p = s_pc[i];
    ds  = fmaf(p, sw[i*256 + c], ds);
    dr  = fmaf(p, rw[i*256 + c], dr);
    float2 tv = tw2[i*256 + c];
    dtx = fmaf(p, tv.x, dtx);
    dty = fmaf(p, tv.y, dty);
  }
  #pragma unroll 4
  for (int kk = 0; kk < 8; kk++) {
    int i = klane * 8 + kk;
    float a = s_a1[i];
    g1  = fmaf(a, g1w[i*256 + c], g1);
    be1 = fmaf(a, b1w[i*256 + c], be1);
    float a2v = s_a2[i];
    g2  = fmaf(a2v, g2w[i*256 + c], g2);
    be2 = fmaf(a2v, b2w[i*256 + c], be2);
  }
  // in-wave reduce over the wave's 4 klanes (lane stride 16)
  ds  += __shfl_down(ds, 32, 64);  ds  += __shfl_down(ds, 16, 64);
  dr  += __shfl_down(dr, 32, 64);  dr  += __shfl_down(dr, 16, 64);
  dtx += __shfl_down(dtx, 32, 64); dtx += __shfl_down(dtx, 16, 64);
  dty += __shfl_down(dty, 32, 64); dty += __shfl_down(dty, 16, 64);
  g1  += __shfl_down(g1, 32, 64);  g1  += __shfl_down(g1, 16, 64);
  be1 += __shfl_down(be1, 32, 64); be1 += __shfl_down(be1, 16, 64);
  g2  += __shfl_down(g2, 32, 64);  g2  += __shfl_down(g2, 16, 64);
  be2 += __shfl_down(be2, 32, 64); be2 += __shfl_down(be2, 16, 64);
  int wv = t >> 6;
  if ((t & 63) < 16) {
    red[0][wv][cl] = ds;  red[1][wv][cl] = dr;
    red[2][wv][cl] = dtx; red[3][wv][cl] = dty;
    red[4][wv][cl] = g1;  red[5][wv][cl] = be1;
    red[6][wv][cl] = g2;  red[7][wv][cl] = be2;
  }
  __syncthreads();
  if (t < 16) {
    float v[8];
    #pragma unroll
    for (int o = 0; o < 8; o++)
      v[o] = red[o][0][t] + red[o][1][t] + red[o][2][t] + red[o][3][t];
    int cc = co0 + t;
    int bc = b*256 + cc;
    float scale = 2.f / (1.f + expf(-(v[0] + sb[cc])));
    float ang = tanhf(v[1] + rb[cc]) * 3.14159f;
    float sn, cs;
    sincosf(ang, &sn, &cs);
    warp[bc*4 + 0] = cs * scale;
    warp[bc*4 + 1] = sn * scale;
    warp[bc*4 + 2] = tanhf(v[2] + tb[2*cc]);
    warp[bc*4 + 3] = tanhf(v[3] + tb[2*cc + 1]);
    gb1[bc*2]     = v[4] + g1b[cc];
    gb1[bc*2 + 1] = v[5] + b1b[cc];
    gb2[bc*2]     = v[6] + g2b[cc];
    gb2[bc*2 + 1] = v[7] + b2b[cc];
  }
}

// ---------------------------------------------------------------------------
// Kernel 2: weight preconversion into per-lane MFMA fragment order (proven).
// wf[coblk4][ks16][tap9][m2][lane64][8]
// ---------------------------------------------------------------------------
__global__ __launch_bounds__(256) void prep_weights_kernel(
    const float* __restrict__ w1, const float* __restrict__ w2,
    unsigned short* __restrict__ wf1, unsigned short* __restrict__ wf2)
{
  int co = blockIdx.x & 255;
  const float* src = (blockIdx.x < 256) ? w1 : w2;
  unsigned short* dst = (blockIdx.x < 256) ? wf1 : wf2;
  int ci = threadIdx.x;
  int coblk = co >> 6, m = (co >> 5) & 1;
  int l = (co & 31) | (((ci >> 3) & 1) << 5);
  int ks = ci >> 4, j = ci & 7;
  const float* p = src + ((size_t)co * 256 + ci) * 9;
  #pragma unroll
  for (int tap = 0; tap < 9; tap++) {
    size_t idx = (((size_t)((coblk * 16 + ks) * 9 + tap) * 2 + m) * 64 + l) * 8 + j;
    dst[idx] = f2bf(p[tap]);
  }
}

// ---------------------------------------------------------------------------
// Kernel 3: AdaAT warp via LDS gather of the z-fused plane (unchanged R8).
// ---------------------------------------------------------------------------
__global__ __launch_bounds__(256) void adaat_kernel(
    const float* __restrict__ fm, const float* __restrict__ warp,
    const float* __restrict__ gb1, float* __restrict__ tout,
    float* __restrict__ nrm1)
{
  __shared__ float s[96 * 100];
  int bc = blockIdx.x;
  int b = bc >> 8, c = bc & 255;
  float csc = warp[bc*4 + 0], ssc = warp[bc*4 + 1];
  float tx = warp[bc*4 + 2], ty = warp[bc*4 + 3];

  const float axw = csc * (96.f / 95.f);
  const float axh = -ssc * (96.f / 95.f);
  const float ax0 = 48.f * (tx - csc + ssc) + 47.5f;
  const float ayw = ssc * (96.f / 95.f);
  const float ayh = csc * (96.f / 95.f);
  const float ay0 = 48.f * (ty - ssc - csc) + 47.5f;

  float iz = 256.f * (float)c / 255.f - 0.5f;
  float z0f = floorf(iz);
  float wz = iz - z0f;
  int z0 = (int)z0f;
  const float* p0 = (z0 >= 0) ? fm + (size_t)(b*256 + z0) * HWN : nullptr;
  const float* p1 = (z0 + 1 < 256) ? fm + (size_t)(b*256 + z0 + 1) * HWN : nullptr;
  float w0 = 1.f - wz, w1 = wz;

  int t = threadIdx.x;
  const float4* q0 = (const float4*)p0;
  const float4* q1 = (const float4*)p1;
  for (int i = t; i < 2304; i += 256) {
    int row = i / 24, col = i - row * 24;
    float4 r = {0.f, 0.f, 0.f, 0.f};
    if (q0) {
      float4 v = q0[i];
      r.x = w0 * v.x; r.y = w0 * v.y; r.z = w0 * v.z; r.w = w0 * v.w;
    }
    if (q1) {
      float4 v = q1[i];
      r.x = fmaf(w1, v.x, r.x); r.y = fmaf(w1, v.y, r.y);
      r.z = fmaf(w1, v.z, r.z); r.w = fmaf(w1, v.w, r.w);
    }
    *(float4*)&s[row * 100 + col * 4] = r;
  }
  __syncthreads();

  int h = t / 96, w = t - (t / 96) * 96;
  float* dst = tout + (size_t)bc * HWN;
  float sum = 0.f, sumsq = 0.f;
  #pragma unroll
  for (int k = 0; k < 36; k++) {
    float ix = fmaf(axw, (float)w, fmaf(axh, (float)h, ax0));
    float iy = fmaf(ayw, (float)w, fmaf(ayh, (float)h, ay0));
    float x0f = floorf(ix), y0f = floorf(iy);
    float wx = ix - x0f, wy = iy - y0f;
    int x0 = (int)x0f, y0 = (int)y0f;
    int x0c = min(max(x0, 0), 95), x1c = min(max(x0 + 1, 0), 95);
    int y0c = min(max(y0, 0), 95), y1c = min(max(y0 + 1, 0), 95);
    bool vx0 = (unsigned)x0 < 96u, vx1 = (unsigned)(x0 + 1) < 96u;
    bool vy0 = (unsigned)y0 < 96u, vy1 = (unsigned)(y0 + 1) < 96u;
    float a00 = s[y0c * 100 + x0c], a01 = s[y0c * 100 + x1c];
    float a10 = s[y1c * 100 + x0c], a11 = s[y1c * 100 + x1c];
    float wxm = 1.f - wx, wym = 1.f - wy;
    float w00 = (vy0 && vx0) ? wym * wxm : 0.f;
    float w01 = (vy0 && vx1) ? wym * wx  : 0.f;
    float w10 = (vy1 && vx0) ? wy * wxm  : 0.f;
    float w11 = (vy1 && vx1) ? wy * wx   : 0.f;
    float v = w00 * a00;
    v = fmaf(w01, a01, v);
    v = fmaf(w10, a10, v);
    v = fmaf(w11, a11, v);
    dst[t + k * 256] = v;
    sum += v;
    sumsq = fmaf(v, v, sumsq);
    int wn = w + 64;
    int carry = (wn >= 96) ? 1 : 0;
    w = wn - (carry ? 96 : 0);
    h += 2 + carry;
  }

  for (int off = 32; off > 0; off >>= 1) {
    sum   += __shfl_down(sum, off, 64);
    sumsq += __shfl_down(sumsq, off, 64);
  }
  __shared__ float rs[4], rq[4];
  int lane = t & 63, wvi = t >> 6;
  if (lane == 0) { rs[wvi] = sum; rq[wvi] = sumsq; }
  __syncthreads();
  if (t == 0) {
    float S = rs[0] + rs[1] + rs[2] + rs[3];
    float Q = rq[0] + rq[1] + rq[2] + rq[3];
    float m = S * (1.f / 9216.f);
    float var = Q * (1.f / 9216.f) - m * m;
    float rstd = rsqrtf(var + 1e-5f);
    float sc = (1.f + gb1[bc*2]) * rstd;
    nrm1[bc*2] = sc;
    nrm1[bc*2 + 1] = gb1[bc*2 + 1] - m * sc;
  }
}

// ---------------------------------------------------------------------------
// Kernel 4: per-plane stats of conv1 output (for AdaIN-2) — unchanged.
// ---------------------------------------------------------------------------
__global__ __launch_bounds__(256) void stats_kernel(
    const float* __restrict__ x, const float* __restrict__ gb,
    float* __restrict__ nrm)
{
  int bc = blockIdx.x;
  const float4* p = (const float4*)(x + (size_t)bc * HWN);
  float sum = 0.f, sumsq = 0.f;
  for (int i = threadIdx.x; i < HWN / 4; i += 256) {
    float4 v = p[i];
    sum   += v.x + v.y + v.z + v.w;
    sumsq += v.x*v.x + v.y*v.y + v.z*v.z + v.w*v.w;
  }
  for (int off = 32; off > 0; off >>= 1) {
    sum   += __shfl_down(sum, off, 64);
    sumsq += __shfl_down(sumsq, off, 64);
  }
  __shared__ float rs[4], rq[4];
  int lane = threadIdx.x & 63, wv = threadIdx.x >> 6;
  if (lane == 0) { rs[wv] = sum; rq[wv] = sumsq; }
  __syncthreads();
  if (threadIdx.x == 0) {
    float S = rs[0] + rs[1] + rs[2] + rs[3];
    float Q = rq[0] + rq[1] + rq[2] + rq[3];
    float m = S * (1.f / 9216.f);
    float var = Q * (1.f / 9216.f) - m * m;
    float rstd = rsqrtf(var + 1e-5f);
    float sc = (1.f + gb[bc*2]) * rstd;
    nrm[bc*2] = sc;
    nrm[bc*2 + 1] = gb[bc*2 + 1] - m * sc;
  }
}

// ---------------------------------------------------------------------------
// Kernel 5: transpose + fused AdaIN(scale/bias) + lrelu + bf16 cvt (unchanged).
// ---------------------------------------------------------------------------
__global__ __launch_bounds__(256) void transpose_norm_kernel(
    const float* __restrict__ x, const float* __restrict__ nrm,
    unsigned short* __restrict__ xt)
{
  int hi = blockIdx.x;
  int b  = blockIdx.y;
  unsigned short* dst = xt + (size_t)b * XT_PLANE + (size_t)hi * (XT_W * CH);
  int t = threadIdx.x;
  int h = hi - 1;
  u16x8 zero = {0,0,0,0,0,0,0,0};
  if (h < 0 || h >= 96) {
    for (int c = t; c < XT_W * CH / 8; c += 256) ((u16x8*)dst)[c] = zero;
    return;
  }
  __shared__ unsigned short s[96 * 256];  // [w][ci]
  int ci = t;
  float sc = nrm[(b*256 + ci)*2], bi = nrm[(b*256 + ci)*2 + 1];
  const float* src = x + ((size_t)(b*256 + ci)) * HWN + h * 96;
  for (int wg = 0; wg < 24; wg++) {
    float4 v = *(const float4*)(src + wg * 4);
    float y0 = fmaf(v.x, sc, bi); y0 = (y0 >= 0.f) ? y0 : 0.2f * y0;
    float y1 = fmaf(v.y, sc, bi); y1 = (y1 >= 0.f) ? y1 : 0.2f * y1;
    float y2 = fmaf(v.z, sc, bi); y2 = (y2 >= 0.f) ? y2 : 0.2f * y2;
    float y3 = fmaf(v.w, sc, bi); y3 = (y3 >= 0.f) ? y3 : 0.2f * y3;
    s[(wg*4 + 0) * 256 + ci] = f2bf(y0);
    s[(wg*4 + 1) * 256 + ci] = f2bf(y1);
    s[(wg*4 + 2) * 256 + ci] = f2bf(y2);
    s[(wg*4 + 3) * 256 + ci] = f2bf(y3);
  }
  __syncthreads();
  for (int c = t; c < 98 * 32; c += 256) {
    int w = c >> 5, p = c & 31;
    u16x8 v = zero;
    if (w >= 1 && w <= 96) v = *(const u16x8*)&s[(w - 1) * 256 + p * 8];
    ((u16x8*)dst)[c] = v;
  }
}

// ---------------------------------------------------------------------------
// Kernel 6: 3x3 conv 256->256, bf16 MFMA (unchanged from R7).
// ---------------------------------------------------------------------------
__global__ __launch_bounds__(256, 3) void conv_mfma_kernel(
    const unsigned short* __restrict__ xt,   // [4][98][98][256] bf16
    const unsigned short* __restrict__ wf,   // frag layout (see prep)
    const float* __restrict__ cb,
    float* __restrict__ out)                 // [4][256][96][96] f32
{
  __shared__ __align__(16) unsigned short s_in[2][784 * 8];

  int hb = blockIdx.x, coblk = blockIdx.y, b = blockIdx.z;
  int co0 = coblk * 64, h0 = hb * 2;
  int t = threadIdx.x, lane = t & 63, wv = t >> 6;
  int rw = wv >> 1, mh = wv & 1;
  int l31 = lane & 31, lhi = lane >> 5;
  const unsigned short* xtb = xt + (size_t)b * XT_PLANE;

  int pre_g[4];
  #pragma unroll
  for (int i = 0; i < 4; i++) {
    int c = t + i * 256;
    if (c < 784) {
      int r = c / 196;
      int rem = c - r * 196;
      int half = rem / 98;
      int w = rem - half * 98;
      pre_g[i] = ((h0 + r) * 98 + w) * 256 + half * 8;
    }
  }

  f32x16 acc[3];
  #pragma unroll
  for (int n = 0; n < 3; n++)
    #pragma unroll
    for (int i = 0; i < 16; i++) acc[n][i] = 0.f;

  const unsigned short* wfb = wf + (size_t)(coblk * 16) * 9216 + mh * 512 + lane * 8;

  u16x8 stg[4];
  #pragma unroll
  for (int i = 0; i < 3; i++) stg[i] = *(const u16x8*)(xtb + pre_g[i]);
  if (t < 16) stg[3] = *(const u16x8*)(xtb + pre_g[3]);
  #pragma unroll
  for (int i = 0; i < 3; i++) *(u16x8*)(&s_in[0][(t + i * 256) * 8]) = stg[i];
  if (t < 16) *(u16x8*)(&s_in[0][(t + 3 * 256) * 8]) = stg[3];

  bfrag wa[9];
  #pragma unroll
  for (int tap = 0; tap < 9; tap++) wa[tap] = *(const bfrag*)(wfb + tap * 1024);

  #pragma unroll
  for (int i = 0; i < 3; i++) stg[i] = *(const u16x8*)(xtb + pre_g[i] + 16);
  if (t < 16) stg[3] = *(const u16x8*)(xtb + pre_g[3] + 16);
  __syncthreads();

  int buf = 0;
  #pragma unroll 1
  for (int ks = 0; ks < 16; ks++) {
    const unsigned short* sb = s_in[buf];
    int ksn = (ks < 15) ? (ks + 1) : 15;
    const unsigned short* wkn = wfb + (size_t)ksn * 9216;
    #pragma unroll
    for (int ky = 0; ky < 3; ky++) {
      const unsigned short* srow = sb + (((rw + ky) * 2 + lhi) * 98) * 8;
      bfrag bb[9];
      #pragma unroll
      for (int kx = 0; kx < 3; kx++)
        #pragma unroll
        for (int n = 0; n < 3; n++)
          bb[kx * 3 + n] = *(const bfrag*)(srow + (n * 32 + kx + l31) * 8);
      #pragma unroll
      for (int kx = 0; kx < 3; kx++) {
        int tap = ky * 3 + kx;
        acc[0] = __builtin_amdgcn_mfma_f32_32x32x16_bf16(wa[tap], bb[kx*3+0], acc[0], 0, 0, 0);
        acc[1] = __builtin_amdgcn_mfma_f32_32x32x16_bf16(wa[tap], bb[kx*3+1], acc[1], 0, 0, 0);
        acc[2] = __builtin_amdgcn_mfma_f32_32x32x16_bf16(wa[tap], bb[kx*3+2], acc[2], 0, 0, 0);
        wa[tap] = *(const bfrag*)(wkn + tap * 1024);
      }
    }
    if (ks < 15) {
      unsigned short* sn = s_in[buf ^ 1];
      #pragma unroll
      for (int i = 0; i < 3; i++) *(u16x8*)(&sn[(t + i * 256) * 8]) = stg[i];
      if (t < 16) *(u16x8*)(&sn[(t + 3 * 256) * 8]) = stg[3];
      if (ks < 14) {
        int off = (ks + 2) * 16;
        #pragma unroll
        for (int i = 0; i < 3; i++) stg[i] = *(const u16x8*)(xtb + pre_g[i] + off);
        if (t < 16) stg[3] = *(const u16x8*)(xtb + pre_g[3] + off);
      }
    }
    __syncthreads();
    buf ^= 1;
  }

  int h = h0 + rw;
  #pragma unroll
  for (int r = 0; r < 16; r++) {
    int row = (r & 3) + 8 * (r >> 2) + 4 * lhi;
    int co = co0 + mh * 32 + row;
    float bv = cb[co];
    size_t base = ((size_t)(b * 256 + co) * 96 + h) * 96;
    #pragma unroll
    for (int n = 0; n < 3; n++) {
      out[base + n * 32 + l31] = acc[n][r] + bv;
    }
  }
}

// ---------------------------------------------------------------------------
extern "C" void kernel_launch(void* const* d_in, const int* in_sizes, int n_in,
                              void* d_out, int out_size, void* d_ws, size_t ws_size,
                              hipStream_t stream)
{
  const float* fm    = (const float*)d_in[0];
  const float* para  = (const float*)d_in[1];
  const float* style = (const float*)d_in[2];
  const float* cw  = (const float*)d_in[3];
  const float* cb  = (const float*)d_in[4];
  const float* sw  = (const float*)d_in[5];
  const float* sb  = (const float*)d_in[6];
  const float* rw  = (const float*)d_in[7];
  const float* rb  = (const float*)d_in[8];
  const float* tw  = (const float*)d_in[9];
  const float* tb  = (const float*)d_in[10];
  const float* a1w = (const float*)d_in[11];
  const float* a1b = (const float*)d_in[12];
  const float* g1w = (const float*)d_in[13];
  const float* g1b = (const float*)d_in[14];
  const float* b1w = (const float*)d_in[15];
  const float* b1b = (const float*)d_in[16];
  const float* c1w = (const float*)d_in[17];
  const float* c1b = (const float*)d_in[18];
  const float* a2w = (const float*)d_in[19];
  const float* a2b = (const float*)d_in[20];
  const float* g2w = (const float*)d_in[21];
  const float* g2b = (const float*)d_in[22];
  const float* b2w = (const float*)d_in[23];
  const float* b2b = (const float*)d_in[24];
  const float* c2w = (const float*)d_in[25];
  const float* c2b = (const float*)d_in[26];

  float* outf = (float*)d_out;

  unsigned short* xtbuf = (unsigned short*)d_ws;                 // 4*98*98*256 bf16
  unsigned short* wf1   = xtbuf + (size_t)BATCH * XT_PLANE;      // 589824
  unsigned short* wf2   = wf1 + 9 * 256 * 256;
  float* fws  = (float*)(wf2 + 9 * 256 * 256);
  float* warp = fws;                   // 4096
  float* gb1  = warp + 4 * 1024;       // 2048
  float* gb2  = gb1 + 2 * 1024;        // 2048
  float* nrm1 = gb2 + 2 * 1024;        // 2048
  float* nrm2 = nrm1 + 2 * 1024;       // 2048
  float* pcbuf = nrm2 + 2 * 1024;      // 1024
  float* a1buf = pcbuf + 1024;         // 512
  float* a2buf = a1buf + 512;          // 512

  params_stage1_kernel<<<dim3(6, 4), 256, 0, stream>>>(para, style, cw, cb,
      a1w, a1b, a2w, a2b, pcbuf, a1buf, a2buf);
  params_stage2_kernel<<<dim3(16, 4), 256, 0, stream>>>(pcbuf, a1buf, a2buf,
      sw, sb, rw, rb, tw, tb, g1w, g1b, b1w, b1b, g2w, g2b, b2w, b2b,
      warp, gb1, gb2);
  prep_weights_kernel<<<512, 256, 0, stream>>>(c1w, c2w, wf1, wf2);
  adaat_kernel<<<1024, 256, 0, stream>>>(fm, warp, gb1, outf, nrm1);
  transpose_norm_kernel<<<dim3(98, 4), 256, 0, stream>>>(outf, nrm1, xtbuf);
  conv_mfma_kernel<<<dim3(48, 4, 4), 256, 0, stream>>>(xtbuf, wf1, c1b, outf);
  stats_kernel<<<1024, 256, 0, stream>>>(outf, gb2, nrm2);
  transpose_norm_kernel<<<dim3(98, 4), 256, 0, stream>>>(outf, nrm2, xtbuf);
  conv_mfma_kernel<<<dim3(48, 4, 4), 256, 0, stream>>>(xtbuf, wf2, c2b, outf);
}

// Round 10
// 191.083 us; speedup vs baseline: 1.4126x; 1.0013x over previous
//
#include <hip/hip_runtime.h>
#include <hip/hip_bf16.h>
#include <cstddef>

#define BATCH 4
#define CH 256
#define HH 96
#define WW 96
#define HWN (HH*WW)               // 9216
#define NTOT (BATCH*CH*HWN)       // 9437184
#define XT_H 98
#define XT_W 98
#define XT_PLANE (XT_H*XT_W*CH)   // per-batch elements in xt (bf16)

typedef __attribute__((ext_vector_type(16))) float f32x16;
typedef __attribute__((ext_vector_type(8))) __bf16 bfrag;
typedef __attribute__((ext_vector_type(8))) unsigned short u16x8;

static __device__ __forceinline__ unsigned short f2bf(float f) {
  unsigned int u = __float_as_uint(f);
  unsigned int r = (u + 0x7fffu + ((u >> 16) & 1u)) >> 16;
  return (unsigned short)r;
}

// lgkm-only barrier: LDS-write visibility without draining outstanding
// global loads (T4: counted vmcnt survives the barrier).
static __device__ __forceinline__ void barrier_lgkm() {
  __builtin_amdgcn_sched_barrier(0);
  asm volatile("s_waitcnt lgkmcnt(0)" ::: "memory");
  __builtin_amdgcn_s_barrier();
  __builtin_amdgcn_sched_barrier(0);
}

// ---------------------------------------------------------------------------
// Kernel 1a: stage-1 GEMVs, wide-parallel (unchanged R9).
// ---------------------------------------------------------------------------
__global__ __launch_bounds__(256) void params_stage1_kernel(
    const float* __restrict__ para, const float* __restrict__ style,
    const float* __restrict__ cw,  const float* __restrict__ cb,
    const float* __restrict__ a1w, const float* __restrict__ a1b,
    const float* __restrict__ a2w, const float* __restrict__ a2b,
    float* __restrict__ pcbuf, float* __restrict__ a1buf, float* __restrict__ a2buf)
{
  __shared__ float s_in[256];
  __shared__ float red[256];
  int part = blockIdx.x, b = blockIdx.y, t = threadIdx.x;
  s_in[t] = (part < 4) ? para[b*256 + t] : style[b*256 + t];
  __syncthreads();
  if (part < 4) {
    int o = t & 63, ks = t >> 6, co0 = part * 64;
    const float* wcol = cw + co0 + o;
    float acc = 0.f;
    #pragma unroll 8
    for (int i = 0; i < 64; i++) {
      int k = ks * 64 + i;
      acc = fmaf(s_in[k], wcol[k * 256], acc);
    }
    red[t] = acc;
    __syncthreads();
    if (t < 64) {
      float s = red[t] + red[t + 64] + red[t + 128] + red[t + 192];
      pcbuf[b*256 + co0 + t] = fmaxf(s + cb[co0 + t], 0.f);
    }
  } else {
    const float* w  = (part == 4) ? a1w : a2w;
    const float* bb = (part == 4) ? a1b : a2b;
    float* outp = (part == 4) ? a1buf : a2buf;
    int o = t & 127, ks = t >> 7;
    const float* wcol = w + o;
    float acc = 0.f;
    #pragma unroll 8
    for (int i = 0; i < 128; i++) {
      int k = ks * 128 + i;
      acc = fmaf(s_in[k], wcol[k * 128], acc);
    }
    red[t] = acc;
    __syncthreads();
    if (t < 128) {
      float s = red[t] + red[t + 128];
      outp[b*128 + t] = fmaxf(s + bb[t], 0.f);
    }
  }
}

// ---------------------------------------------------------------------------
// Kernel 1b: stage-2 params (unchanged R9).
// ---------------------------------------------------------------------------
__global__ __launch_bounds__(256) void params_stage2_kernel(
    const float* __restrict__ pcbuf, const float* __restrict__ a1buf,
    const float* __restrict__ a2buf,
    const float* __restrict__ sw,  const float* __restrict__ sb,
    const float* __restrict__ rw,  const float* __restrict__ rb,
    const float* __restrict__ tw,  const float* __restrict__ tb,
    const float* __restrict__ g1w, const float* __restrict__ g1b,
    const float* __restrict__ b1w, const float* __restrict__ b1b,
    const float* __restrict__ g2w, const float* __restrict__ g2b,
    const float* __restrict__ b2w, const float* __restrict__ b2b,
    float* __restrict__ warp, float* __restrict__ gb1, float* __restrict__ gb2)
{
  __shared__ float s_pc[256], s_a1[128], s_a2[128];
  __shared__ float red[8][4][16];
  int co0 = blockIdx.x * 16, b = blockIdx.y, t = threadIdx.x;
  s_pc[t] = pcbuf[b*256 + t];
  if (t < 128) s_a1[t] = a1buf[b*128 + t];
  else         s_a2[t - 128] = a2buf[b*128 + (t - 128)];
  __syncthreads();

  int cl = t & 15, klane = t >> 4;
  int c = co0 + cl;
  const float2* tw2 = (const float2*)tw;
  float ds = 0.f, dr = 0.f, dtx = 0.f, dty = 0.f;
  float g1 = 0.f, be1 = 0.f, g2 = 0.f, be2 = 0.f;
  #pragma unroll 4
  for (int kk = 0; kk < 16; kk++) {
    int i = klane * 16 + kk;
    float p = s_pc[i];
    ds  = fmaf(p, sw[i*256 + c], ds);
    dr  = fmaf(p, rw[i*256 + c], dr);
    float2 tv = tw2[i*256 + c];
    dtx = fmaf(p, tv.x, dtx);
    dty = fmaf(p, tv.y, dty);
  }
  #pragma unroll 4
  for (int kk = 0; kk < 8; kk++) {
    int i = klane * 8 + kk;
    float a = s_a1[i];
    g1  = fmaf(a, g1w[i*256 + c], g1);
    be1 = fmaf(a, b1w[i*256 + c], be1);
    float a2v = s_a2[i];
    g2  = fmaf(a2v, g2w[i*256 + c], g2);
    be2 = fmaf(a2v, b2w[i*256 + c], be2);
  }
  ds  += __shfl_down(ds, 32, 64);  ds  += __shfl_down(ds, 16, 64);
  dr  += __shfl_down(dr, 32, 64);  dr  += __shfl_down(dr, 16, 64);
  dtx += __shfl_down(dtx, 32, 64); dtx += __shfl_down(dtx, 16, 64);
  dty += __shfl_down(dty, 32, 64); dty += __shfl_down(dty, 16, 64);
  g1  += __shfl_down(g1, 32, 64);  g1  += __shfl_down(g1, 16, 64);
  be1 += __shfl_down(be1, 32, 64); be1 += __shfl_down(be1, 16, 64);
  g2  += __shfl_down(g2, 32, 64);  g2  += __shfl_down(g2, 16, 64);
  be2 += __shfl_down(be2, 32, 64); be2 += __shfl_down(be2, 16, 64);
  int wv = t >> 6;
  if ((t & 63) < 16) {
    red[0][wv][cl] = ds;  red[1][wv][cl] = dr;
    red[2][wv][cl] = dtx; red[3][wv][cl] = dty;
    red[4][wv][cl] = g1;  red[5][wv][cl] = be1;
    red[6][wv][cl] = g2;  red[7][wv][cl] = be2;
  }
  __syncthreads();
  if (t < 16) {
    float v[8];
    #pragma unroll
    for (int o = 0; o < 8; o++)
      v[o] = red[o][0][t] + red[o][1][t] + red[o][2][t] + red[o][3][t];
    int cc = co0 + t;
    int bc = b*256 + cc;
    float scale = 2.f / (1.f + expf(-(v[0] + sb[cc])));
    float ang = tanhf(v[1] + rb[cc]) * 3.14159f;
    float sn, cs;
    sincosf(ang, &sn, &cs);
    warp[bc*4 + 0] = cs * scale;
    warp[bc*4 + 1] = sn * scale;
    warp[bc*4 + 2] = tanhf(v[2] + tb[2*cc]);
    warp[bc*4 + 3] = tanhf(v[3] + tb[2*cc + 1]);
    gb1[bc*2]     = v[4] + g1b[cc];
    gb1[bc*2 + 1] = v[5] + b1b[cc];
    gb2[bc*2]     = v[6] + g2b[cc];
    gb2[bc*2 + 1] = v[7] + b2b[cc];
  }
}

// ---------------------------------------------------------------------------
// Kernel 2: weight preconversion (unchanged).
// wf[coblk4][ks16][tap9][m2][lane64][8]
// ---------------------------------------------------------------------------
__global__ __launch_bounds__(256) void prep_weights_kernel(
    const float* __restrict__ w1, const float* __restrict__ w2,
    unsigned short* __restrict__ wf1, unsigned short* __restrict__ wf2)
{
  int co = blockIdx.x & 255;
  const float* src = (blockIdx.x < 256) ? w1 : w2;
  unsigned short* dst = (blockIdx.x < 256) ? wf1 : wf2;
  int ci = threadIdx.x;
  int coblk = co >> 6, m = (co >> 5) & 1;
  int l = (co & 31) | (((ci >> 3) & 1) << 5);
  int ks = ci >> 4, j = ci & 7;
  const float* p = src + ((size_t)co * 256 + ci) * 9;
  #pragma unroll
  for (int tap = 0; tap < 9; tap++) {
    size_t idx = (((size_t)((coblk * 16 + ks) * 9 + tap) * 2 + m) * 64 + l) * 8 + j;
    dst[idx] = f2bf(p[tap]);
  }
}

// ---------------------------------------------------------------------------
// Kernel 3: AdaAT warp via LDS gather of the z-fused plane (unchanged R8).
// ---------------------------------------------------------------------------
__global__ __launch_bounds__(256) void adaat_kernel(
    const float* __restrict__ fm, const float* __restrict__ warp,
    const float* __restrict__ gb1, float* __restrict__ tout,
    float* __restrict__ nrm1)
{
  __shared__ float s[96 * 100];
  int bc = blockIdx.x;
  int b = bc >> 8, c = bc & 255;
  float csc = warp[bc*4 + 0], ssc = warp[bc*4 + 1];
  float tx = warp[bc*4 + 2], ty = warp[bc*4 + 3];

  const float axw = csc * (96.f / 95.f);
  const float axh = -ssc * (96.f / 95.f);
  const float ax0 = 48.f * (tx - csc + ssc) + 47.5f;
  const float ayw = ssc * (96.f / 95.f);
  const float ayh = csc * (96.f / 95.f);
  const float ay0 = 48.f * (ty - ssc - csc) + 47.5f;

  float iz = 256.f * (float)c / 255.f - 0.5f;
  float z0f = floorf(iz);
  float wz = iz - z0f;
  int z0 = (int)z0f;
  const float* p0 = (z0 >= 0) ? fm + (size_t)(b*256 + z0) * HWN : nullptr;
  const float* p1 = (z0 + 1 < 256) ? fm + (size_t)(b*256 + z0 + 1) * HWN : nullptr;
  float w0 = 1.f - wz, w1 = wz;

  int t = threadIdx.x;
  const float4* q0 = (const float4*)p0;
  const float4* q1 = (const float4*)p1;
  for (int i = t; i < 2304; i += 256) {
    int row = i / 24, col = i - row * 24;
    float4 r = {0.f, 0.f, 0.f, 0.f};
    if (q0) {
      float4 v = q0[i];
      r.x = w0 * v.x; r.y = w0 * v.y; r.z = w0 * v.z; r.w = w0 * v.w;
    }
    if (q1) {
      float4 v = q1[i];
      r.x = fmaf(w1, v.x, r.x); r.y = fmaf(w1, v.y, r.y);
      r.z = fmaf(w1, v.z, r.z); r.w = fmaf(w1, v.w, r.w);
    }
    *(float4*)&s[row * 100 + col * 4] = r;
  }
  __syncthreads();

  int h = t / 96, w = t - (t / 96) * 96;
  float* dst = tout + (size_t)bc * HWN;
  float sum = 0.f, sumsq = 0.f;
  #pragma unroll
  for (int k = 0; k < 36; k++) {
    float ix = fmaf(axw, (float)w, fmaf(axh, (float)h, ax0));
    float iy = fmaf(ayw, (float)w, fmaf(ayh, (float)h, ay0));
    float x0f = floorf(ix), y0f = floorf(iy);
    float wx = ix - x0f, wy = iy - y0f;
    int x0 = (int)x0f, y0 = (int)y0f;
    int x0c = min(max(x0, 0), 95), x1c = min(max(x0 + 1, 0), 95);
    int y0c = min(max(y0, 0), 95), y1c = min(max(y0 + 1, 0), 95);
    bool vx0 = (unsigned)x0 < 96u, vx1 = (unsigned)(x0 + 1) < 96u;
    bool vy0 = (unsigned)y0 < 96u, vy1 = (unsigned)(y0 + 1) < 96u;
    float a00 = s[y0c * 100 + x0c], a01 = s[y0c * 100 + x1c];
    float a10 = s[y1c * 100 + x0c], a11 = s[y1c * 100 + x1c];
    float wxm = 1.f - wx, wym = 1.f - wy;
    float w00 = (vy0 && vx0) ? wym * wxm : 0.f;
    float w01 = (vy0 && vx1) ? wym * wx  : 0.f;
    float w10 = (vy1 && vx0) ? wy * wxm  : 0.f;
    float w11 = (vy1 && vx1) ? wy * wx   : 0.f;
    float v = w00 * a00;
    v = fmaf(w01, a01, v);
    v = fmaf(w10, a10, v);
    v = fmaf(w11, a11, v);
    dst[t + k * 256] = v;
    sum += v;
    sumsq = fmaf(v, v, sumsq);
    int wn = w + 64;
    int carry = (wn >= 96) ? 1 : 0;
    w = wn - (carry ? 96 : 0);
    h += 2 + carry;
  }

  for (int off = 32; off > 0; off >>= 1) {
    sum   += __shfl_down(sum, off, 64);
    sumsq += __shfl_down(sumsq, off, 64);
  }
  __shared__ float rs[4], rq[4];
  int lane = t & 63, wvi = t >> 6;
  if (lane == 0) { rs[wvi] = sum; rq[wvi] = sumsq; }
  __syncthreads();
  if (t == 0) {
    float S = rs[0] + rs[1] + rs[2] + rs[3];
    float Q = rq[0] + rq[1] + rq[2] + rq[3];
    float m = S * (1.f / 9216.f);
    float var = Q * (1.f / 9216.f) - m * m;
    float rstd = rsqrtf(var + 1e-5f);
    float sc = (1.f + gb1[bc*2]) * rstd;
    nrm1[bc*2] = sc;
    nrm1[bc*2 + 1] = gb1[bc*2 + 1] - m * sc;
  }
}

// ---------------------------------------------------------------------------
// Kernel 4: per-plane stats of conv1 output (unchanged).
// ---------------------------------------------------------------------------
__global__ __launch_bounds__(256) void stats_kernel(
    const float* __restrict__ x, const float* __restrict__ gb,
    float* __restrict__ nrm)
{
  int bc = blockIdx.x;
  const float4* p = (const float4*)(x + (size_t)bc * HWN);
  float sum = 0.f, sumsq = 0.f;
  for (int i = threadIdx.x; i < HWN / 4; i += 256) {
    float4 v = p[i];
    sum   += v.x + v.y + v.z + v.w;
    sumsq += v.x*v.x + v.y*v.y + v.z*v.z + v.w*v.w;
  }
  for (int off = 32; off > 0; off >>= 1) {
    sum   += __shfl_down(sum, off, 64);
    sumsq += __shfl_down(sumsq, off, 64);
  }
  __shared__ float rs[4], rq[4];
  int lane = threadIdx.x & 63, wv = threadIdx.x >> 6;
  if (lane == 0) { rs[wv] = sum; rq[wv] = sumsq; }
  __syncthreads();
  if (threadIdx.x == 0) {
    float S = rs[0] + rs[1] + rs[2] + rs[3];
    float Q = rq[0] + rq[1] + rq[2] + rq[3];
    float m = S * (1.f / 9216.f);
    float var = Q * (1.f / 9216.f) - m * m;
    float rstd = rsqrtf(var + 1e-5f);
    float sc = (1.f + gb[bc*2]) * rstd;
    nrm[bc*2] = sc;
    nrm[bc*2 + 1] = gb[bc*2 + 1] - m * sc;
  }
}

// ---------------------------------------------------------------------------
// Kernel 5: transpose + fused AdaIN + lrelu + bf16 cvt (unchanged).
// ---------------------------------------------------------------------------
__global__ __launch_bounds__(256) void transpose_norm_kernel(
    const float* __restrict__ x, const float* __restrict__ nrm,
    unsigned short* __restrict__ xt)
{
  int hi = blockIdx.x;
  int b  = blockIdx.y;
  unsigned short* dst = xt + (size_t)b * XT_PLANE + (size_t)hi * (XT_W * CH);
  int t = threadIdx.x;
  int h = hi - 1;
  u16x8 zero = {0,0,0,0,0,0,0,0};
  if (h < 0 || h >= 96) {
    for (int c = t; c < XT_W * CH / 8; c += 256) ((u16x8*)dst)[c] = zero;
    return;
  }
  __shared__ unsigned short s[96 * 256];  // [w][ci]
  int ci = t;
  float sc = nrm[(b*256 + ci)*2], bi = nrm[(b*256 + ci)*2 + 1];
  const float* src = x + ((size_t)(b*256 + ci)) * HWN + h * 96;
  for (int wg = 0; wg < 24; wg++) {
    float4 v = *(const float4*)(src + wg * 4);
    float y0 = fmaf(v.x, sc, bi); y0 = (y0 >= 0.f) ? y0 : 0.2f * y0;
    float y1 = fmaf(v.y, sc, bi); y1 = (y1 >= 0.f) ? y1 : 0.2f * y1;
    float y2 = fmaf(v.z, sc, bi); y2 = (y2 >= 0.f) ? y2 : 0.2f * y2;
    float y3 = fmaf(v.w, sc, bi); y3 = (y3 >= 0.f) ? y3 : 0.2f * y3;
    s[(wg*4 + 0) * 256 + ci] = f2bf(y0);
    s[(wg*4 + 1) * 256 + ci] = f2bf(y1);
    s[(wg*4 + 2) * 256 + ci] = f2bf(y2);
    s[(wg*4 + 3) * 256 + ci] = f2bf(y3);
  }
  __syncthreads();
  for (int c = t; c < 98 * 32; c += 256) {
    int w = c >> 5, p = c & 31;
    u16x8 v = zero;
    if (w >= 1 && w <= 96) v = *(const u16x8*)&s[(w - 1) * 256 + p * 8];
    ((u16x8*)dst)[c] = v;
  }
}

// ---------------------------------------------------------------------------
// Kernel 6 (R10): conv as R9, but the per-K-step barrier is lgkm-only
// (raw s_barrier) so the wa-rotation and stage prefetch loads stay in
// flight across it (counted vmcnt at their use points).
// ---------------------------------------------------------------------------
__global__ __launch_bounds__(256, 3) void conv_mfma_kernel(
    const unsigned short* __restrict__ xt,   // [4][98][98][256] bf16
    const unsigned short* __restrict__ wf,   // frag layout (see prep)
    const float* __restrict__ cb,
    float* __restrict__ out)                 // [4][256][96][96] f32
{
  __shared__ __align__(16) unsigned short s_in[2][784 * 8];

  int hb = blockIdx.x, coblk = blockIdx.y, b = blockIdx.z;
  int co0 = coblk * 64, h0 = hb * 2;
  int t = threadIdx.x, lane = t & 63, wv = t >> 6;
  int rw = wv >> 1, mh = wv & 1;
  int l31 = lane & 31, lhi = lane >> 5;
  const unsigned short* xtb = xt + (size_t)b * XT_PLANE;

  int pre_g[4];
  #pragma unroll
  for (int i = 0; i < 4; i++) {
    int c = t + i * 256;
    if (c < 784) {
      int r = c / 196;
      int rem = c - r * 196;
      int half = rem / 98;
      int w = rem - half * 98;
      pre_g[i] = ((h0 + r) * 98 + w) * 256 + half * 8;
    }
  }

  f32x16 acc[3];
  #pragma unroll
  for (int n = 0; n < 3; n++)
    #pragma unroll
    for (int i = 0; i < 16; i++) acc[n][i] = 0.f;

  const unsigned short* wfb = wf + (size_t)(coblk * 16) * 9216 + mh * 512 + lane * 8;

  u16x8 stg[4];
  #pragma unroll
  for (int i = 0; i < 3; i++) stg[i] = *(const u16x8*)(xtb + pre_g[i]);
  if (t < 16) stg[3] = *(const u16x8*)(xtb + pre_g[3]);
  #pragma unroll
  for (int i = 0; i < 3; i++) *(u16x8*)(&s_in[0][(t + i * 256) * 8]) = stg[i];
  if (t < 16) *(u16x8*)(&s_in[0][(t + 3 * 256) * 8]) = stg[3];

  bfrag wa[9];
  #pragma unroll
  for (int tap = 0; tap < 9; tap++) wa[tap] = *(const bfrag*)(wfb + tap * 1024);

  #pragma unroll
  for (int i = 0; i < 3; i++) stg[i] = *(const u16x8*)(xtb + pre_g[i] + 16);
  if (t < 16) stg[3] = *(const u16x8*)(xtb + pre_g[3] + 16);
  barrier_lgkm();

  int buf = 0;
  #pragma unroll 1
  for (int ks = 0; ks < 16; ks++) {
    const unsigned short* sb = s_in[buf];
    int ksn = (ks < 15) ? (ks + 1) : 15;
    const unsigned short* wkn = wfb + (size_t)ksn * 9216;
    #pragma unroll
    for (int ky = 0; ky < 3; ky++) {
      const unsigned short* srow = sb + (((rw + ky) * 2 + lhi) * 98) * 8;
      bfrag bb[9];
      #pragma unroll
      for (int kx = 0; kx < 3; kx++)
        #pragma unroll
        for (int n = 0; n < 3; n++)
          bb[kx * 3 + n] = *(const bfrag*)(srow + (n * 32 + kx + l31) * 8);
      #pragma unroll
      for (int kx = 0; kx < 3; kx++) {
        int tap = ky * 3 + kx;
        acc[0] = __builtin_amdgcn_mfma_f32_32x32x16_bf16(wa[tap], bb[kx*3+0], acc[0], 0, 0, 0);
        acc[1] = __builtin_amdgcn_mfma_f32_32x32x16_bf16(wa[tap], bb[kx*3+1], acc[1], 0, 0, 0);
        acc[2] = __builtin_amdgcn_mfma_f32_32x32x16_bf16(wa[tap], bb[kx*3+2], acc[2], 0, 0, 0);
        wa[tap] = *(const bfrag*)(wkn + tap * 1024);
      }
    }
    if (ks < 15) {
      unsigned short* sn = s_in[buf ^ 1];
      #pragma unroll
      for (int i = 0; i < 3; i++) *(u16x8*)(&sn[(t + i * 256) * 8]) = stg[i];
      if (t < 16) *(u16x8*)(&sn[(t + 3 * 256) * 8]) = stg[3];
      if (ks < 14) {
        int off = (ks + 2) * 16;
        #pragma unroll
        for (int i = 0; i < 3; i++) stg[i] = *(const u16x8*)(xtb + pre_g[i] + off);
        if (t < 16) stg[3] = *(const u16x8*)(xtb + pre_g[3] + off);
      }
    }
    barrier_lgkm();
    buf ^= 1;
  }

  int h = h0 + rw;
  #pragma unroll
  for (int r = 0; r < 16; r++) {
    int row = (r & 3) + 8 * (r >> 2) + 4 * lhi;
    int co = co0 + mh * 32 + row;
    float bv = cb[co];
    size_t base = ((size_t)(b * 256 + co) * 96 + h) * 96;
    #pragma unroll
    for (int n = 0; n < 3; n++) {
      out[base + n * 32 + l31] = acc[n][r] + bv;
    }
  }
}

// ---------------------------------------------------------------------------
extern "C" void kernel_launch(void* const* d_in, const int* in_sizes, int n_in,
                              void* d_out, int out_size, void* d_ws, size_t ws_size,
                              hipStream_t stream)
{
  const float* fm    = (const float*)d_in[0];
  const float* para  = (const float*)d_in[1];
  const float* style = (const float*)d_in[2];
  const float* cw  = (const float*)d_in[3];
  const float* cb  = (const float*)d_in[4];
  const float* sw  = (const float*)d_in[5];
  const float* sb  = (const float*)d_in[6];
  const float* rw  = (const float*)d_in[7];
  const float* rb  = (const float*)d_in[8];
  const float* tw  = (const float*)d_in[9];
  const float* tb  = (const float*)d_in[10];
  const float* a1w = (const float*)d_in[11];
  const float* a1b = (const float*)d_in[12];
  const float* g1w = (const float*)d_in[13];
  const float* g1b = (const float*)d_in[14];
  const float* b1w = (const float*)d_in[15];
  const float* b1b = (const float*)d_in[16];
  const float* c1w = (const float*)d_in[17];
  const float* c1b = (const float*)d_in[18];
  const float* a2w = (const float*)d_in[19];
  const float* a2b = (const float*)d_in[20];
  const float* g2w = (const float*)d_in[21];
  const float* g2b = (const float*)d_in[22];
  const float* b2w = (const float*)d_in[23];
  const float* b2b = (const float*)d_in[24];
  const float* c2w = (const float*)d_in[25];
  const float* c2b = (const float*)d_in[26];

  float* outf = (float*)d_out;

  unsigned short* xtbuf = (unsigned short*)d_ws;                 // 4*98*98*256 bf16
  unsigned short* wf1   = xtbuf + (size_t)BATCH * XT_PLANE;      // 589824
  unsigned short* wf2   = wf1 + 9 * 256 * 256;
  float* fws  = (float*)(wf2 + 9 * 256 * 256);
  float* warp = fws;                   // 4096
  float* gb1  = warp + 4 * 1024;       // 2048
  float* gb2  = gb1 + 2 * 1024;        // 2048
  float* nrm1 = gb2 + 2 * 1024;        // 2048
  float* nrm2 = nrm1 + 2 * 1024;       // 2048
  float* pcbuf = nrm2 + 2 * 1024;      // 1024
  float* a1buf = pcbuf + 1024;         // 512
  float* a2buf = a1buf + 512;          // 512

  params_stage1_kernel<<<dim3(6, 4), 256, 0, stream>>>(para, style, cw, cb,
      a1w, a1b, a2w, a2b, pcbuf, a1buf, a2buf);
  params_stage2_kernel<<<dim3(16, 4), 256, 0, stream>>>(pcbuf, a1buf, a2buf,
      sw, sb, rw, rb, tw, tb, g1w, g1b, b1w, b1b, g2w, g2b, b2w, b2b,
      warp, gb1, gb2);
  prep_weights_kernel<<<512, 256, 0, stream>>>(c1w, c2w, wf1, wf2);
  adaat_kernel<<<1024, 256, 0, stream>>>(fm, warp, gb1, outf, nrm1);
  transpose_norm_kernel<<<dim3(98, 4), 256, 0, stream>>>(outf, nrm1, xtbuf);
  conv_mfma_kernel<<<dim3(48, 4, 4), 256, 0, stream>>>(xtbuf, wf1, c1b, outf);
  stats_kernel<<<1024, 256, 0, stream>>>(outf, gb2, nrm2);
  transpose_norm_kernel<<<dim3(98, 4), 256, 0, stream>>>(outf, nrm2, xtbuf);
  conv_mfma_kernel<<<dim3(48, 4, 4), 256, 0, stream>>>(xtbuf, wf2, c2b, outf);
}

// Round 11
// 188.904 us; speedup vs baseline: 1.4289x; 1.0115x over previous
//
#include <hip/hip_runtime.h>
#include <hip/hip_bf16.h>
#include <cstddef>

#define BATCH 4
#define CH 256
#define HH 96
#define WW 96
#define HWN (HH*WW)               // 9216
#define NTOT (BATCH*CH*HWN)       // 9437184
#define XT_H 98
#define XT_W 98
#define XT_PLANE (XT_H*XT_W*CH)   // per-batch elements in xt (bf16)

typedef __attribute__((ext_vector_type(16))) float f32x16;
typedef __attribute__((ext_vector_type(8))) __bf16 bfrag;
typedef __attribute__((ext_vector_type(8))) unsigned short u16x8;

static __device__ __forceinline__ unsigned short f2bf(float f) {
  unsigned int u = __float_as_uint(f);
  unsigned int r = (u + 0x7fffu + ((u >> 16) & 1u)) >> 16;
  return (unsigned short)r;
}

// async global->LDS, 16B per lane; LDS dest = wave-uniform base + lane*16
static __device__ __forceinline__ void gload16(const unsigned short* g,
                                               unsigned short* l) {
  __builtin_amdgcn_global_load_lds(
      (const __attribute__((address_space(1))) unsigned int*)g,
      (__attribute__((address_space(3))) unsigned int*)l, 16, 0, 0);
}

// ---------------------------------------------------------------------------
// Kernel 1a: stage-1 GEMVs, wide-parallel (unchanged R9).
// ---------------------------------------------------------------------------
__global__ __launch_bounds__(256) void params_stage1_kernel(
    const float* __restrict__ para, const float* __restrict__ style,
    const float* __restrict__ cw,  const float* __restrict__ cb,
    const float* __restrict__ a1w, const float* __restrict__ a1b,
    const float* __restrict__ a2w, const float* __restrict__ a2b,
    float* __restrict__ pcbuf, float* __restrict__ a1buf, float* __restrict__ a2buf)
{
  __shared__ float s_in[256];
  __shared__ float red[256];
  int part = blockIdx.x, b = blockIdx.y, t = threadIdx.x;
  s_in[t] = (part < 4) ? para[b*256 + t] : style[b*256 + t];
  __syncthreads();
  if (part < 4) {
    int o = t & 63, ks = t >> 6, co0 = part * 64;
    const float* wcol = cw + co0 + o;
    float acc = 0.f;
    #pragma unroll 8
    for (int i = 0; i < 64; i++) {
      int k = ks * 64 + i;
      acc = fmaf(s_in[k], wcol[k * 256], acc);
    }
    red[t] = acc;
    __syncthreads();
    if (t < 64) {
      float s = red[t] + red[t + 64] + red[t + 128] + red[t + 192];
      pcbuf[b*256 + co0 + t] = fmaxf(s + cb[co0 + t], 0.f);
    }
  } else {
    const float* w  = (part == 4) ? a1w : a2w;
    const float* bb = (part == 4) ? a1b : a2b;
    float* outp = (part == 4) ? a1buf : a2buf;
    int o = t & 127, ks = t >> 7;
    const float* wcol = w + o;
    float acc = 0.f;
    #pragma unroll 8
    for (int i = 0; i < 128; i++) {
      int k = ks * 128 + i;
      acc = fmaf(s_in[k], wcol[k * 128], acc);
    }
    red[t] = acc;
    __syncthreads();
    if (t < 128) {
      float s = red[t] + red[t + 128];
      outp[b*128 + t] = fmaxf(s + bb[t], 0.f);
    }
  }
}

// ---------------------------------------------------------------------------
// Kernel 1b: stage-2 params (unchanged R9).
// ---------------------------------------------------------------------------
__global__ __launch_bounds__(256) void params_stage2_kernel(
    const float* __restrict__ pcbuf, const float* __restrict__ a1buf,
    const float* __restrict__ a2buf,
    const float* __restrict__ sw,  const float* __restrict__ sb,
    const float* __restrict__ rw,  const float* __restrict__ rb,
    const float* __restrict__ tw,  const float* __restrict__ tb,
    const float* __restrict__ g1w, const float* __restrict__ g1b,
    const float* __restrict__ b1w, const float* __restrict__ b1b,
    const float* __restrict__ g2w, const float* __restrict__ g2b,
    const float* __restrict__ b2w, const float* __restrict__ b2b,
    float* __restrict__ warp, float* __restrict__ gb1, float* __restrict__ gb2)
{
  __shared__ float s_pc[256], s_a1[128], s_a2[128];
  __shared__ float red[8][4][16];
  int co0 = blockIdx.x * 16, b = blockIdx.y, t = threadIdx.x;
  s_pc[t] = pcbuf[b*256 + t];
  if (t < 128) s_a1[t] = a1buf[b*128 + t];
  else         s_a2[t - 128] = a2buf[b*128 + (t - 128)];
  __syncthreads();

  int cl = t & 15, klane = t >> 4;
  int c = co0 + cl;
  const float2* tw2 = (const float2*)tw;
  float ds = 0.f, dr = 0.f, dtx = 0.f, dty = 0.f;
  float g1 = 0.f, be1 = 0.f, g2 = 0.f, be2 = 0.f;
  #pragma unroll 4
  for (int kk = 0; kk < 16; kk++) {
    int i = klane * 16 + kk;
    float p = s_pc[i];
    ds  = fmaf(p, sw[i*256 + c], ds);
    dr  = fmaf(p, rw[i*256 + c], dr);
    float2 tv = tw2[i*256 + c];
    dtx = fmaf(p, tv.x, dtx);
    dty = fmaf(p, tv.y, dty);
  }
  #pragma unroll 4
  for (int kk = 0; kk < 8; kk++) {
    int i = klane * 8 + kk;
    float a = s_a1[i];
    g1  = fmaf(a, g1w[i*256 + c], g1);
    be1 = fmaf(a, b1w[i*256 + c], be1);
    float a2v = s_a2[i];
    g2  = fmaf(a2v, g2w[i*256 + c], g2);
    be2 = fmaf(a2v, b2w[i*256 + c], be2);
  }
  ds  += __shfl_down(ds, 32, 64);  ds  += __shfl_down(ds, 16, 64);
  dr  += __shfl_down(dr, 32, 64);  dr  += __shfl_down(dr, 16, 64);
  dtx += __shfl_down(dtx, 32, 64); dtx += __shfl_down(dtx, 16, 64);
  dty += __shfl_down(dty, 32, 64); dty += __shfl_down(dty, 16, 64);
  g1  += __shfl_down(g1, 32, 64);  g1  += __shfl_down(g1, 16, 64);
  be1 += __shfl_down(be1, 32, 64); be1 += __shfl_down(be1, 16, 64);
  g2  += __shfl_down(g2, 32, 64);  g2  += __shfl_down(g2, 16, 64);
  be2 += __shfl_down(be2, 32, 64); be2 += __shfl_down(be2, 16, 64);
  int wv = t >> 6;
  if ((t & 63) < 16) {
    red[0][wv][cl] = ds;  red[1][wv][cl] = dr;
    red[2][wv][cl] = dtx; red[3][wv][cl] = dty;
    red[4][wv][cl] = g1;  red[5][wv][cl] = be1;
    red[6][wv][cl] = g2;  red[7][wv][cl] = be2;
  }
  __syncthreads();
  if (t < 16) {
    float v[8];
    #pragma unroll
    for (int o = 0; o < 8; o++)
      v[o] = red[o][0][t] + red[o][1][t] + red[o][2][t] + red[o][3][t];
    int cc = co0 + t;
    int bc = b*256 + cc;
    float scale = 2.f / (1.f + expf(-(v[0] + sb[cc])));
    float ang = tanhf(v[1] + rb[cc]) * 3.14159f;
    float sn, cs;
    sincosf(ang, &sn, &cs);
    warp[bc*4 + 0] = cs * scale;
    warp[bc*4 + 1] = sn * scale;
    warp[bc*4 + 2] = tanhf(v[2] + tb[2*cc]);
    warp[bc*4 + 3] = tanhf(v[3] + tb[2*cc + 1]);
    gb1[bc*2]     = v[4] + g1b[cc];
    gb1[bc*2 + 1] = v[5] + b1b[cc];
    gb2[bc*2]     = v[6] + g2b[cc];
    gb2[bc*2 + 1] = v[7] + b2b[cc];
  }
}

// ---------------------------------------------------------------------------
// Kernel 2: weight preconversion (unchanged).
// wf[coblk4][ks16][tap9][m2][lane64][8]
// ---------------------------------------------------------------------------
__global__ __launch_bounds__(256) void prep_weights_kernel(
    const float* __restrict__ w1, const float* __restrict__ w2,
    unsigned short* __restrict__ wf1, unsigned short* __restrict__ wf2)
{
  int co = blockIdx.x & 255;
  const float* src = (blockIdx.x < 256) ? w1 : w2;
  unsigned short* dst = (blockIdx.x < 256) ? wf1 : wf2;
  int ci = threadIdx.x;
  int coblk = co >> 6, m = (co >> 5) & 1;
  int l = (co & 31) | (((ci >> 3) & 1) << 5);
  int ks = ci >> 4, j = ci & 7;
  const float* p = src + ((size_t)co * 256 + ci) * 9;
  #pragma unroll
  for (int tap = 0; tap < 9; tap++) {
    size_t idx = (((size_t)((coblk * 16 + ks) * 9 + tap) * 2 + m) * 64 + l) * 8 + j;
    dst[idx] = f2bf(p[tap]);
  }
}

// ---------------------------------------------------------------------------
// Kernel 3: AdaAT warp via LDS gather of the z-fused plane (unchanged R8).
// ---------------------------------------------------------------------------
__global__ __launch_bounds__(256) void adaat_kernel(
    const float* __restrict__ fm, const float* __restrict__ warp,
    const float* __restrict__ gb1, float* __restrict__ tout,
    float* __restrict__ nrm1)
{
  __shared__ float s[96 * 100];
  int bc = blockIdx.x;
  int b = bc >> 8, c = bc & 255;
  float csc = warp[bc*4 + 0], ssc = warp[bc*4 + 1];
  float tx = warp[bc*4 + 2], ty = warp[bc*4 + 3];

  const float axw = csc * (96.f / 95.f);
  const float axh = -ssc * (96.f / 95.f);
  const float ax0 = 48.f * (tx - csc + ssc) + 47.5f;
  const float ayw = ssc * (96.f / 95.f);
  const float ayh = csc * (96.f / 95.f);
  const float ay0 = 48.f * (ty - ssc - csc) + 47.5f;

  float iz = 256.f * (float)c / 255.f - 0.5f;
  float z0f = floorf(iz);
  float wz = iz - z0f;
  int z0 = (int)z0f;
  const float* p0 = (z0 >= 0) ? fm + (size_t)(b*256 + z0) * HWN : nullptr;
  const float* p1 = (z0 + 1 < 256) ? fm + (size_t)(b*256 + z0 + 1) * HWN : nullptr;
  float w0 = 1.f - wz, w1 = wz;

  int t = threadIdx.x;
  const float4* q0 = (const float4*)p0;
  const float4* q1 = (const float4*)p1;
  for (int i = t; i < 2304; i += 256) {
    int row = i / 24, col = i - row * 24;
    float4 r = {0.f, 0.f, 0.f, 0.f};
    if (q0) {
      float4 v = q0[i];
      r.x = w0 * v.x; r.y = w0 * v.y; r.z = w0 * v.z; r.w = w0 * v.w;
    }
    if (q1) {
      float4 v = q1[i];
      r.x = fmaf(w1, v.x, r.x); r.y = fmaf(w1, v.y, r.y);
      r.z = fmaf(w1, v.z, r.z); r.w = fmaf(w1, v.w, r.w);
    }
    *(float4*)&s[row * 100 + col * 4] = r;
  }
  __syncthreads();

  int h = t / 96, w = t - (t / 96) * 96;
  float* dst = tout + (size_t)bc * HWN;
  float sum = 0.f, sumsq = 0.f;
  #pragma unroll
  for (int k = 0; k < 36; k++) {
    float ix = fmaf(axw, (float)w, fmaf(axh, (float)h, ax0));
    float iy = fmaf(ayw, (float)w, fmaf(ayh, (float)h, ay0));
    float x0f = floorf(ix), y0f = floorf(iy);
    float wx = ix - x0f, wy = iy - y0f;
    int x0 = (int)x0f, y0 = (int)y0f;
    int x0c = min(max(x0, 0), 95), x1c = min(max(x0 + 1, 0), 95);
    int y0c = min(max(y0, 0), 95), y1c = min(max(y0 + 1, 0), 95);
    bool vx0 = (unsigned)x0 < 96u, vx1 = (unsigned)(x0 + 1) < 96u;
    bool vy0 = (unsigned)y0 < 96u, vy1 = (unsigned)(y0 + 1) < 96u;
    float a00 = s[y0c * 100 + x0c], a01 = s[y0c * 100 + x1c];
    float a10 = s[y1c * 100 + x0c], a11 = s[y1c * 100 + x1c];
    float wxm = 1.f - wx, wym = 1.f - wy;
    float w00 = (vy0 && vx0) ? wym * wxm : 0.f;
    float w01 = (vy0 && vx1) ? wym * wx  : 0.f;
    float w10 = (vy1 && vx0) ? wy * wxm  : 0.f;
    float w11 = (vy1 && vx1) ? wy * wx   : 0.f;
    float v = w00 * a00;
    v = fmaf(w01, a01, v);
    v = fmaf(w10, a10, v);
    v = fmaf(w11, a11, v);
    dst[t + k * 256] = v;
    sum += v;
    sumsq = fmaf(v, v, sumsq);
    int wn = w + 64;
    int carry = (wn >= 96) ? 1 : 0;
    w = wn - (carry ? 96 : 0);
    h += 2 + carry;
  }

  for (int off = 32; off > 0; off >>= 1) {
    sum   += __shfl_down(sum, off, 64);
    sumsq += __shfl_down(sumsq, off, 64);
  }
  __shared__ float rs[4], rq[4];
  int lane = t & 63, wvi = t >> 6;
  if (lane == 0) { rs[wvi] = sum; rq[wvi] = sumsq; }
  __syncthreads();
  if (t == 0) {
    float S = rs[0] + rs[1] + rs[2] + rs[3];
    float Q = rq[0] + rq[1] + rq[2] + rq[3];
    float m = S * (1.f / 9216.f);
    float var = Q * (1.f / 9216.f) - m * m;
    float rstd = rsqrtf(var + 1e-5f);
    float sc = (1.f + gb1[bc*2]) * rstd;
    nrm1[bc*2] = sc;
    nrm1[bc*2 + 1] = gb1[bc*2 + 1] - m * sc;
  }
}

// ---------------------------------------------------------------------------
// Kernel 4 (R11): finalize per-(b,co) stats from conv1's per-(block,row)
// partials -> nrm2 scale/bias. Replaces the 37.7MB stats re-read.
// psum layout: [b][hb48][row2][co256][2] (sum, sumsq)
// ---------------------------------------------------------------------------
__global__ __launch_bounds__(256) void finalize_stats_kernel(
    const float* __restrict__ psum, const float* __restrict__ gb,
    float* __restrict__ nrm)
{
  int bc = blockIdx.x * 256 + threadIdx.x;   // 4 blocks x 256
  int b = bc >> 8, co = bc & 255;
  float S = 0.f, Q = 0.f;
  for (int j = 0; j < 96; j++) {
    const float* p = psum + ((((size_t)b * 48 + (j >> 1)) * 2 + (j & 1)) * 256 + co) * 2;
    S += p[0];
    Q += p[1];
  }
  float m = S * (1.f / 9216.f);
  float var = Q * (1.f / 9216.f) - m * m;
  float rstd = rsqrtf(var + 1e-5f);
  float sc = (1.f + gb[bc*2]) * rstd;
  nrm[bc*2] = sc;
  nrm[bc*2 + 1] = gb[bc*2 + 1] - m * sc;
}

// ---------------------------------------------------------------------------
// Kernel 5: transpose + fused AdaIN + lrelu + bf16 cvt (unchanged).
// ---------------------------------------------------------------------------
__global__ __launch_bounds__(256) void transpose_norm_kernel(
    const float* __restrict__ x, const float* __restrict__ nrm,
    unsigned short* __restrict__ xt)
{
  int hi = blockIdx.x;
  int b  = blockIdx.y;
  unsigned short* dst = xt + (size_t)b * XT_PLANE + (size_t)hi * (XT_W * CH);
  int t = threadIdx.x;
  int h = hi - 1;
  u16x8 zero = {0,0,0,0,0,0,0,0};
  if (h < 0 || h >= 96) {
    for (int c = t; c < XT_W * CH / 8; c += 256) ((u16x8*)dst)[c] = zero;
    return;
  }
  __shared__ unsigned short s[96 * 256];  // [w][ci]
  int ci = t;
  float sc = nrm[(b*256 + ci)*2], bi = nrm[(b*256 + ci)*2 + 1];
  const float* src = x + ((size_t)(b*256 + ci)) * HWN + h * 96;
  for (int wg = 0; wg < 24; wg++) {
    float4 v = *(const float4*)(src + wg * 4);
    float y0 = fmaf(v.x, sc, bi); y0 = (y0 >= 0.f) ? y0 : 0.2f * y0;
    float y1 = fmaf(v.y, sc, bi); y1 = (y1 >= 0.f) ? y1 : 0.2f * y1;
    float y2 = fmaf(v.z, sc, bi); y2 = (y2 >= 0.f) ? y2 : 0.2f * y2;
    float y3 = fmaf(v.w, sc, bi); y3 = (y3 >= 0.f) ? y3 : 0.2f * y3;
    s[(wg*4 + 0) * 256 + ci] = f2bf(y0);
    s[(wg*4 + 1) * 256 + ci] = f2bf(y1);
    s[(wg*4 + 2) * 256 + ci] = f2bf(y2);
    s[(wg*4 + 3) * 256 + ci] = f2bf(y3);
  }
  __syncthreads();
  for (int c = t; c < 98 * 32; c += 256) {
    int w = c >> 5, p = c & 31;
    u16x8 v = zero;
    if (w >= 1 && w <= 96) v = *(const u16x8*)&s[(w - 1) * 256 + p * 8];
    ((u16x8*)dst)[c] = v;
  }
}

// ---------------------------------------------------------------------------
// Kernel 6 (R11): conv with (a) global_load_lds staging, (b) setprio around
// MFMA clusters, (c) fused per-(co,row) stats partials in the epilogue
// (psum != nullptr for conv1 only).
// ---------------------------------------------------------------------------
__global__ __launch_bounds__(256, 3) void conv_mfma_kernel(
    const unsigned short* __restrict__ xt,   // [4][98][98][256] bf16
    const unsigned short* __restrict__ wf,   // frag layout (see prep)
    const float* __restrict__ cb,
    float* __restrict__ out,                 // [4][256][96][96] f32
    float* __restrict__ psum)                // partials or nullptr
{
  __shared__ __align__(16) unsigned short s_in[2][784 * 8];

  int hb = blockIdx.x, coblk = blockIdx.y, b = blockIdx.z;
  int co0 = coblk * 64, h0 = hb * 2;
  int t = threadIdx.x, lane = t & 63, wv = t >> 6;
  int rw = wv >> 1, mh = wv & 1;
  int l31 = lane & 31, lhi = lane >> 5;
  const unsigned short* xtb = xt + (size_t)b * XT_PLANE;

  // stage descriptors: chunk c = t + i*256 (i<3 all threads; tail 768+t, t<16)
  int pre_g[4];
  #pragma unroll
  for (int i = 0; i < 4; i++) {
    int c = t + i * 256;
    if (c < 784) {
      int r = c / 196;
      int rem = c - r * 196;
      int half = rem / 98;
      int w = rem - half * 98;
      pre_g[i] = ((h0 + r) * 98 + w) * 256 + half * 8;
    }
  }

  f32x16 acc[3];
  #pragma unroll
  for (int n = 0; n < 3; n++)
    #pragma unroll
    for (int i = 0; i < 16; i++) acc[n][i] = 0.f;

  const unsigned short* wfb = wf + (size_t)(coblk * 16) * 9216 + mh * 512 + lane * 8;

  // prologue: stage ks=0 into buf0 (async DMA + reg tail), load wa(ks=0)
  {
    #pragma unroll
    for (int i = 0; i < 3; i++)
      gload16(xtb + pre_g[i], &s_in[0][(i * 256 + wv * 64) * 8]);
    u16x8 tail;
    if (t < 16) tail = *(const u16x8*)(xtb + pre_g[3]);
    if (t < 16) *(u16x8*)(&s_in[0][(768 + t) * 8]) = tail;
  }
  bfrag wa[9];
  #pragma unroll
  for (int tap = 0; tap < 9; tap++) wa[tap] = *(const bfrag*)(wfb + tap * 1024);
  __syncthreads();

  int buf = 0;
  u16x8 tail;
  #pragma unroll 1
  for (int ks = 0; ks < 16; ks++) {
    // issue next K-step's staging immediately (covered by full compute)
    if (ks < 15) {
      int cib = (ks + 1) * 16;
      unsigned short* nb = s_in[buf ^ 1];
      #pragma unroll
      for (int i = 0; i < 3; i++)
        gload16(xtb + pre_g[i] + cib, &nb[(i * 256 + wv * 64) * 8]);
      if (t < 16) tail = *(const u16x8*)(xtb + pre_g[3] + cib);
    }
    const unsigned short* sb = s_in[buf];
    int ksn = (ks < 15) ? (ks + 1) : 15;
    const unsigned short* wkn = wfb + (size_t)ksn * 9216;
    #pragma unroll
    for (int ky = 0; ky < 3; ky++) {
      const unsigned short* srow = sb + (((rw + ky) * 2 + lhi) * 98) * 8;
      bfrag bb[9];
      #pragma unroll
      for (int kx = 0; kx < 3; kx++)
        #pragma unroll
        for (int n = 0; n < 3; n++)
          bb[kx * 3 + n] = *(const bfrag*)(srow + (n * 32 + kx + l31) * 8);
      __builtin_amdgcn_s_setprio(1);
      #pragma unroll
      for (int kx = 0; kx < 3; kx++) {
        int tap = ky * 3 + kx;
        acc[0] = __builtin_amdgcn_mfma_f32_32x32x16_bf16(wa[tap], bb[kx*3+0], acc[0], 0, 0, 0);
        acc[1] = __builtin_amdgcn_mfma_f32_32x32x16_bf16(wa[tap], bb[kx*3+1], acc[1], 0, 0, 0);
        acc[2] = __builtin_amdgcn_mfma_f32_32x32x16_bf16(wa[tap], bb[kx*3+2], acc[2], 0, 0, 0);
        wa[tap] = *(const bfrag*)(wkn + tap * 1024);
      }
      __builtin_amdgcn_s_setprio(0);
    }
    if (ks < 15 && t < 16) *(u16x8*)(&s_in[buf ^ 1][(768 + t) * 8]) = tail;
    __syncthreads();
    buf ^= 1;
  }

  // epilogue: C col = lane&31 (px), row = (r&3)+8*(r>>2)+4*(lane>>5) (co)
  int h = h0 + rw;
  float bsum[16], bsq[16];
  #pragma unroll
  for (int r = 0; r < 16; r++) {
    int row = (r & 3) + 8 * (r >> 2) + 4 * lhi;
    int co = co0 + mh * 32 + row;
    float bv = cb[co];
    size_t base = ((size_t)(b * 256 + co) * 96 + h) * 96;
    float s = 0.f, q = 0.f;
    #pragma unroll
    for (int n = 0; n < 3; n++) {
      float y = acc[n][r] + bv;
      out[base + n * 32 + l31] = y;
      s += y;
      q = fmaf(y, y, q);
    }
    bsum[r] = s; bsq[r] = q;
  }
  if (psum) {
    // reduce across the 32 px-lanes of each lhi-half (xor strides < 32)
    #pragma unroll
    for (int r = 0; r < 16; r++) {
      float s = bsum[r], q = bsq[r];
      #pragma unroll
      for (int off = 16; off > 0; off >>= 1) {
        s += __shfl_xor(s, off, 64);
        q += __shfl_xor(q, off, 64);
      }
      bsum[r] = s; bsq[r] = q;
    }
    if (l31 == 0) {
      // psum[b][hb][row rw][co][2]
      float* pp = psum + ((((size_t)b * 48 + hb) * 2 + rw) * 256) * 2;
      #pragma unroll
      for (int r = 0; r < 16; r++) {
        int row = (r & 3) + 8 * (r >> 2) + 4 * lhi;
        int co = co0 + mh * 32 + row;
        pp[co * 2]     = bsum[r];
        pp[co * 2 + 1] = bsq[r];
      }
    }
  }
}

// ---------------------------------------------------------------------------
extern "C" void kernel_launch(void* const* d_in, const int* in_sizes, int n_in,
                              void* d_out, int out_size, void* d_ws, size_t ws_size,
                              hipStream_t stream)
{
  const float* fm    = (const float*)d_in[0];
  const float* para  = (const float*)d_in[1];
  const float* style = (const float*)d_in[2];
  const float* cw  = (const float*)d_in[3];
  const float* cb  = (const float*)d_in[4];
  const float* sw  = (const float*)d_in[5];
  const float* sb  = (const float*)d_in[6];
  const float* rw  = (const float*)d_in[7];
  const float* rb  = (const float*)d_in[8];
  const float* tw  = (const float*)d_in[9];
  const float* tb  = (const float*)d_in[10];
  const float* a1w = (const float*)d_in[11];
  const float* a1b = (const float*)d_in[12];
  const float* g1w = (const float*)d_in[13];
  const float* g1b = (const float*)d_in[14];
  const float* b1w = (const float*)d_in[15];
  const float* b1b = (const float*)d_in[16];
  const float* c1w = (const float*)d_in[17];
  const float* c1b = (const float*)d_in[18];
  const float* a2w = (const float*)d_in[19];
  const float* a2b = (const float*)d_in[20];
  const float* g2w = (const float*)d_in[21];
  const float* g2b = (const float*)d_in[22];
  const float* b2w = (const float*)d_in[23];
  const float* b2b = (const float*)d_in[24];
  const float* c2w = (const float*)d_in[25];
  const float* c2b = (const float*)d_in[26];

  float* outf = (float*)d_out;

  unsigned short* xtbuf = (unsigned short*)d_ws;                 // 4*98*98*256 bf16
  unsigned short* wf1   = xtbuf + (size_t)BATCH * XT_PLANE;      // 589824
  unsigned short* wf2   = wf1 + 9 * 256 * 256;
  float* fws  = (float*)(wf2 + 9 * 256 * 256);
  float* warp = fws;                   // 4096
  float* gb1  = warp + 4 * 1024;       // 2048
  float* gb2  = gb1 + 2 * 1024;        // 2048
  float* nrm1 = gb2 + 2 * 1024;        // 2048
  float* nrm2 = nrm1 + 2 * 1024;       // 2048
  float* pcbuf = nrm2 + 2 * 1024;      // 1024
  float* a1buf = pcbuf + 1024;         // 512
  float* a2buf = a1buf + 512;          // 512
  float* psum  = a2buf + 512;          // 4*48*2*256*2 = 98304 floats

  params_stage1_kernel<<<dim3(6, 4), 256, 0, stream>>>(para, style, cw, cb,
      a1w, a1b, a2w, a2b, pcbuf, a1buf, a2buf);
  params_stage2_kernel<<<dim3(16, 4), 256, 0, stream>>>(pcbuf, a1buf, a2buf,
      sw, sb, rw, rb, tw, tb, g1w, g1b, b1w, b1b, g2w, g2b, b2w, b2b,
      warp, gb1, gb2);
  prep_weights_kernel<<<512, 256, 0, stream>>>(c1w, c2w, wf1, wf2);
  adaat_kernel<<<1024, 256, 0, stream>>>(fm, warp, gb1, outf, nrm1);
  transpose_norm_kernel<<<dim3(98, 4), 256, 0, stream>>>(outf, nrm1, xtbuf);
  conv_mfma_kernel<<<dim3(48, 4, 4), 256, 0, stream>>>(xtbuf, wf1, c1b, outf, psum);
  finalize_stats_kernel<<<4, 256, 0, stream>>>(psum, gb2, nrm2);
  transpose_norm_kernel<<<dim3(98, 4), 256, 0, stream>>>(outf, nrm2, xtbuf);
  conv_mfma_kernel<<<dim3(48, 4, 4), 256, 0, stream>>>(xtbuf, wf2, c2b, outf, nullptr);
}

// Round 12
// 188.076 us; speedup vs baseline: 1.4352x; 1.0044x over previous
//
#include <hip/hip_runtime.h>
#include <hip/hip_bf16.h>
#include <cstddef>

#define BATCH 4
#define CH 256
#define HH 96
#define WW 96
#define HWN (HH*WW)               // 9216
#define NTOT (BATCH*CH*HWN)       // 9437184
#define XT_H 98
#define XT_W 98
#define XT_PLANE (XT_H*XT_W*CH)   // per-batch elements in xt (bf16)

typedef __attribute__((ext_vector_type(16))) float f32x16;
typedef __attribute__((ext_vector_type(8))) __bf16 bfrag;
typedef __attribute__((ext_vector_type(8))) unsigned short u16x8;

static __device__ __forceinline__ unsigned short f2bf(float f) {
  unsigned int u = __float_as_uint(f);
  unsigned int r = (u + 0x7fffu + ((u >> 16) & 1u)) >> 16;
  return (unsigned short)r;
}

// async global->LDS, 16B per lane; LDS dest = wave-uniform base + lane*16
static __device__ __forceinline__ void gload16(const unsigned short* g,
                                               unsigned short* l) {
  __builtin_amdgcn_global_load_lds(
      (const __attribute__((address_space(1))) unsigned int*)g,
      (__attribute__((address_space(3))) unsigned int*)l, 16, 0, 0);
}

// ---------------------------------------------------------------------------
// Kernel 1a: stage-1 GEMVs, wide-parallel (unchanged R9).
// ---------------------------------------------------------------------------
__global__ __launch_bounds__(256) void params_stage1_kernel(
    const float* __restrict__ para, const float* __restrict__ style,
    const float* __restrict__ cw,  const float* __restrict__ cb,
    const float* __restrict__ a1w, const float* __restrict__ a1b,
    const float* __restrict__ a2w, const float* __restrict__ a2b,
    float* __restrict__ pcbuf, float* __restrict__ a1buf, float* __restrict__ a2buf)
{
  __shared__ float s_in[256];
  __shared__ float red[256];
  int part = blockIdx.x, b = blockIdx.y, t = threadIdx.x;
  s_in[t] = (part < 4) ? para[b*256 + t] : style[b*256 + t];
  __syncthreads();
  if (part < 4) {
    int o = t & 63, ks = t >> 6, co0 = part * 64;
    const float* wcol = cw + co0 + o;
    float acc = 0.f;
    #pragma unroll 8
    for (int i = 0; i < 64; i++) {
      int k = ks * 64 + i;
      acc = fmaf(s_in[k], wcol[k * 256], acc);
    }
    red[t] = acc;
    __syncthreads();
    if (t < 64) {
      float s = red[t] + red[t + 64] + red[t + 128] + red[t + 192];
      pcbuf[b*256 + co0 + t] = fmaxf(s + cb[co0 + t], 0.f);
    }
  } else {
    const float* w  = (part == 4) ? a1w : a2w;
    const float* bb = (part == 4) ? a1b : a2b;
    float* outp = (part == 4) ? a1buf : a2buf;
    int o = t & 127, ks = t >> 7;
    const float* wcol = w + o;
    float acc = 0.f;
    #pragma unroll 8
    for (int i = 0; i < 128; i++) {
      int k = ks * 128 + i;
      acc = fmaf(s_in[k], wcol[k * 128], acc);
    }
    red[t] = acc;
    __syncthreads();
    if (t < 128) {
      float s = red[t] + red[t + 128];
      outp[b*128 + t] = fmaxf(s + bb[t], 0.f);
    }
  }
}

// ---------------------------------------------------------------------------
// Kernel 1b: stage-2 params (unchanged R9).
// ---------------------------------------------------------------------------
__global__ __launch_bounds__(256) void params_stage2_kernel(
    const float* __restrict__ pcbuf, const float* __restrict__ a1buf,
    const float* __restrict__ a2buf,
    const float* __restrict__ sw,  const float* __restrict__ sb,
    const float* __restrict__ rw,  const float* __restrict__ rb,
    const float* __restrict__ tw,  const float* __restrict__ tb,
    const float* __restrict__ g1w, const float* __restrict__ g1b,
    const float* __restrict__ b1w, const float* __restrict__ b1b,
    const float* __restrict__ g2w, const float* __restrict__ g2b,
    const float* __restrict__ b2w, const float* __restrict__ b2b,
    float* __restrict__ warp, float* __restrict__ gb1, float* __restrict__ gb2)
{
  __shared__ float s_pc[256], s_a1[128], s_a2[128];
  __shared__ float red[8][4][16];
  int co0 = blockIdx.x * 16, b = blockIdx.y, t = threadIdx.x;
  s_pc[t] = pcbuf[b*256 + t];
  if (t < 128) s_a1[t] = a1buf[b*128 + t];
  else         s_a2[t - 128] = a2buf[b*128 + (t - 128)];
  __syncthreads();

  int cl = t & 15, klane = t >> 4;
  int c = co0 + cl;
  const float2* tw2 = (const float2*)tw;
  float ds = 0.f, dr = 0.f, dtx = 0.f, dty = 0.f;
  float g1 = 0.f, be1 = 0.f, g2 = 0.f, be2 = 0.f;
  #pragma unroll 4
  for (int kk = 0; kk < 16; kk++) {
    int i = klane * 16 + kk;
    float p = s_pc[i];
    ds  = fmaf(p, sw[i*256 + c], ds);
    dr  = fmaf(p, rw[i*256 + c], dr);
    float2 tv = tw2[i*256 + c];
    dtx = fmaf(p, tv.x, dtx);
    dty = fmaf(p, tv.y, dty);
  }
  #pragma unroll 4
  for (int kk = 0; kk < 8; kk++) {
    int i = klane * 8 + kk;
    float a = s_a1[i];
    g1  = fmaf(a, g1w[i*256 + c], g1);
    be1 = fmaf(a, b1w[i*256 + c], be1);
    float a2v = s_a2[i];
    g2  = fmaf(a2v, g2w[i*256 + c], g2);
    be2 = fmaf(a2v, b2w[i*256 + c], be2);
  }
  ds  += __shfl_down(ds, 32, 64);  ds  += __shfl_down(ds, 16, 64);
  dr  += __shfl_down(dr, 32, 64);  dr  += __shfl_down(dr, 16, 64);
  dtx += __shfl_down(dtx, 32, 64); dtx += __shfl_down(dtx, 16, 64);
  dty += __shfl_down(dty, 32, 64); dty += __shfl_down(dty, 16, 64);
  g1  += __shfl_down(g1, 32, 64);  g1  += __shfl_down(g1, 16, 64);
  be1 += __shfl_down(be1, 32, 64); be1 += __shfl_down(be1, 16, 64);
  g2  += __shfl_down(g2, 32, 64);  g2  += __shfl_down(g2, 16, 64);
  be2 += __shfl_down(be2, 32, 64); be2 += __shfl_down(be2, 16, 64);
  int wv = t >> 6;
  if ((t & 63) < 16) {
    red[0][wv][cl] = ds;  red[1][wv][cl] = dr;
    red[2][wv][cl] = dtx; red[3][wv][cl] = dty;
    red[4][wv][cl] = g1;  red[5][wv][cl] = be1;
    red[6][wv][cl] = g2;  red[7][wv][cl] = be2;
  }
  __syncthreads();
  if (t < 16) {
    float v[8];
    #pragma unroll
    for (int o = 0; o < 8; o++)
      v[o] = red[o][0][t] + red[o][1][t] + red[o][2][t] + red[o][3][t];
    int cc = co0 + t;
    int bc = b*256 + cc;
    float scale = 2.f / (1.f + expf(-(v[0] + sb[cc])));
    float ang = tanhf(v[1] + rb[cc]) * 3.14159f;
    float sn, cs;
    sincosf(ang, &sn, &cs);
    warp[bc*4 + 0] = cs * scale;
    warp[bc*4 + 1] = sn * scale;
    warp[bc*4 + 2] = tanhf(v[2] + tb[2*cc]);
    warp[bc*4 + 3] = tanhf(v[3] + tb[2*cc + 1]);
    gb1[bc*2]     = v[4] + g1b[cc];
    gb1[bc*2 + 1] = v[5] + b1b[cc];
    gb2[bc*2]     = v[6] + g2b[cc];
    gb2[bc*2 + 1] = v[7] + b2b[cc];
  }
}

// ---------------------------------------------------------------------------
// Kernel 2: weight preconversion (unchanged).
// wf[coblk4][ks16][tap9][m2][lane64][8]
// ---------------------------------------------------------------------------
__global__ __launch_bounds__(256) void prep_weights_kernel(
    const float* __restrict__ w1, const float* __restrict__ w2,
    unsigned short* __restrict__ wf1, unsigned short* __restrict__ wf2)
{
  int co = blockIdx.x & 255;
  const float* src = (blockIdx.x < 256) ? w1 : w2;
  unsigned short* dst = (blockIdx.x < 256) ? wf1 : wf2;
  int ci = threadIdx.x;
  int coblk = co >> 6, m = (co >> 5) & 1;
  int l = (co & 31) | (((ci >> 3) & 1) << 5);
  int ks = ci >> 4, j = ci & 7;
  const float* p = src + ((size_t)co * 256 + ci) * 9;
  #pragma unroll
  for (int tap = 0; tap < 9; tap++) {
    size_t idx = (((size_t)((coblk * 16 + ks) * 9 + tap) * 2 + m) * 64 + l) * 8 + j;
    dst[idx] = f2bf(p[tap]);
  }
}

// ---------------------------------------------------------------------------
// Kernel 3: AdaAT warp via LDS gather of the z-fused plane (unchanged R8).
// ---------------------------------------------------------------------------
__global__ __launch_bounds__(256) void adaat_kernel(
    const float* __restrict__ fm, const float* __restrict__ warp,
    const float* __restrict__ gb1, float* __restrict__ tout,
    float* __restrict__ nrm1)
{
  __shared__ float s[96 * 100];
  int bc = blockIdx.x;
  int b = bc >> 8, c = bc & 255;
  float csc = warp[bc*4 + 0], ssc = warp[bc*4 + 1];
  float tx = warp[bc*4 + 2], ty = warp[bc*4 + 3];

  const float axw = csc * (96.f / 95.f);
  const float axh = -ssc * (96.f / 95.f);
  const float ax0 = 48.f * (tx - csc + ssc) + 47.5f;
  const float ayw = ssc * (96.f / 95.f);
  const float ayh = csc * (96.f / 95.f);
  const float ay0 = 48.f * (ty - ssc - csc) + 47.5f;

  float iz = 256.f * (float)c / 255.f - 0.5f;
  float z0f = floorf(iz);
  float wz = iz - z0f;
  int z0 = (int)z0f;
  const float* p0 = (z0 >= 0) ? fm + (size_t)(b*256 + z0) * HWN : nullptr;
  const float* p1 = (z0 + 1 < 256) ? fm + (size_t)(b*256 + z0 + 1) * HWN : nullptr;
  float w0 = 1.f - wz, w1 = wz;

  int t = threadIdx.x;
  const float4* q0 = (const float4*)p0;
  const float4* q1 = (const float4*)p1;
  for (int i = t; i < 2304; i += 256) {
    int row = i / 24, col = i - row * 24;
    float4 r = {0.f, 0.f, 0.f, 0.f};
    if (q0) {
      float4 v = q0[i];
      r.x = w0 * v.x; r.y = w0 * v.y; r.z = w0 * v.z; r.w = w0 * v.w;
    }
    if (q1) {
      float4 v = q1[i];
      r.x = fmaf(w1, v.x, r.x); r.y = fmaf(w1, v.y, r.y);
      r.z = fmaf(w1, v.z, r.z); r.w = fmaf(w1, v.w, r.w);
    }
    *(float4*)&s[row * 100 + col * 4] = r;
  }
  __syncthreads();

  int h = t / 96, w = t - (t / 96) * 96;
  float* dst = tout + (size_t)bc * HWN;
  float sum = 0.f, sumsq = 0.f;
  #pragma unroll
  for (int k = 0; k < 36; k++) {
    float ix = fmaf(axw, (float)w, fmaf(axh, (float)h, ax0));
    float iy = fmaf(ayw, (float)w, fmaf(ayh, (float)h, ay0));
    float x0f = floorf(ix), y0f = floorf(iy);
    float wx = ix - x0f, wy = iy - y0f;
    int x0 = (int)x0f, y0 = (int)y0f;
    int x0c = min(max(x0, 0), 95), x1c = min(max(x0 + 1, 0), 95);
    int y0c = min(max(y0, 0), 95), y1c = min(max(y0 + 1, 0), 95);
    bool vx0 = (unsigned)x0 < 96u, vx1 = (unsigned)(x0 + 1) < 96u;
    bool vy0 = (unsigned)y0 < 96u, vy1 = (unsigned)(y0 + 1) < 96u;
    float a00 = s[y0c * 100 + x0c], a01 = s[y0c * 100 + x1c];
    float a10 = s[y1c * 100 + x0c], a11 = s[y1c * 100 + x1c];
    float wxm = 1.f - wx, wym = 1.f - wy;
    float w00 = (vy0 && vx0) ? wym * wxm : 0.f;
    float w01 = (vy0 && vx1) ? wym * wx  : 0.f;
    float w10 = (vy1 && vx0) ? wy * wxm  : 0.f;
    float w11 = (vy1 && vx1) ? wy * wx   : 0.f;
    float v = w00 * a00;
    v = fmaf(w01, a01, v);
    v = fmaf(w10, a10, v);
    v = fmaf(w11, a11, v);
    dst[t + k * 256] = v;
    sum += v;
    sumsq = fmaf(v, v, sumsq);
    int wn = w + 64;
    int carry = (wn >= 96) ? 1 : 0;
    w = wn - (carry ? 96 : 0);
    h += 2 + carry;
  }

  for (int off = 32; off > 0; off >>= 1) {
    sum   += __shfl_down(sum, off, 64);
    sumsq += __shfl_down(sumsq, off, 64);
  }
  __shared__ float rs[4], rq[4];
  int lane = t & 63, wvi = t >> 6;
  if (lane == 0) { rs[wvi] = sum; rq[wvi] = sumsq; }
  __syncthreads();
  if (t == 0) {
    float S = rs[0] + rs[1] + rs[2] + rs[3];
    float Q = rq[0] + rq[1] + rq[2] + rq[3];
    float m = S * (1.f / 9216.f);
    float var = Q * (1.f / 9216.f) - m * m;
    float rstd = rsqrtf(var + 1e-5f);
    float sc = (1.f + gb1[bc*2]) * rstd;
    nrm1[bc*2] = sc;
    nrm1[bc*2 + 1] = gb1[bc*2 + 1] - m * sc;
  }
}

// ---------------------------------------------------------------------------
// Kernel 4: finalize per-(b,co) stats from conv1 partials (unchanged R11).
// psum layout: [b][hb48][row2][co256][2]
// ---------------------------------------------------------------------------
__global__ __launch_bounds__(256) void finalize_stats_kernel(
    const float* __restrict__ psum, const float* __restrict__ gb,
    float* __restrict__ nrm)
{
  int bc = blockIdx.x * 256 + threadIdx.x;   // 4 blocks x 256
  int b = bc >> 8, co = bc & 255;
  float S = 0.f, Q = 0.f;
  for (int j = 0; j < 96; j++) {
    const float* p = psum + ((((size_t)b * 48 + (j >> 1)) * 2 + (j & 1)) * 256 + co) * 2;
    S += p[0];
    Q += p[1];
  }
  float m = S * (1.f / 9216.f);
  float var = Q * (1.f / 9216.f) - m * m;
  float rstd = rsqrtf(var + 1e-5f);
  float sc = (1.f + gb[bc*2]) * rstd;
  nrm[bc*2] = sc;
  nrm[bc*2 + 1] = gb[bc*2 + 1] - m * sc;
}

// ---------------------------------------------------------------------------
// Kernel 5: transpose + fused AdaIN + lrelu + bf16 cvt (unchanged).
// ---------------------------------------------------------------------------
__global__ __launch_bounds__(256) void transpose_norm_kernel(
    const float* __restrict__ x, const float* __restrict__ nrm,
    unsigned short* __restrict__ xt)
{
  int hi = blockIdx.x;
  int b  = blockIdx.y;
  unsigned short* dst = xt + (size_t)b * XT_PLANE + (size_t)hi * (XT_W * CH);
  int t = threadIdx.x;
  int h = hi - 1;
  u16x8 zero = {0,0,0,0,0,0,0,0};
  if (h < 0 || h >= 96) {
    for (int c = t; c < XT_W * CH / 8; c += 256) ((u16x8*)dst)[c] = zero;
    return;
  }
  __shared__ unsigned short s[96 * 256];  // [w][ci]
  int ci = t;
  float sc = nrm[(b*256 + ci)*2], bi = nrm[(b*256 + ci)*2 + 1];
  const float* src = x + ((size_t)(b*256 + ci)) * HWN + h * 96;
  for (int wg = 0; wg < 24; wg++) {
    float4 v = *(const float4*)(src + wg * 4);
    float y0 = fmaf(v.x, sc, bi); y0 = (y0 >= 0.f) ? y0 : 0.2f * y0;
    float y1 = fmaf(v.y, sc, bi); y1 = (y1 >= 0.f) ? y1 : 0.2f * y1;
    float y2 = fmaf(v.z, sc, bi); y2 = (y2 >= 0.f) ? y2 : 0.2f * y2;
    float y3 = fmaf(v.w, sc, bi); y3 = (y3 >= 0.f) ? y3 : 0.2f * y3;
    s[(wg*4 + 0) * 256 + ci] = f2bf(y0);
    s[(wg*4 + 1) * 256 + ci] = f2bf(y1);
    s[(wg*4 + 2) * 256 + ci] = f2bf(y2);
    s[(wg*4 + 3) * 256 + ci] = f2bf(y3);
  }
  __syncthreads();
  for (int c = t; c < 98 * 32; c += 256) {
    int w = c >> 5, p = c & 31;
    u16x8 v = zero;
    if (w >= 1 && w <= 96) v = *(const u16x8*)&s[(w - 1) * 256 + p * 8];
    ((u16x8*)dst)[c] = v;
  }
}

// ---------------------------------------------------------------------------
// Kernel 6 (R12): conv, wave = 1 row x 96 px x 64 co (acc[2][3]) so each
// B-fragment LDS read feeds TWO MFMAs (LDS floor halves; MFMA-bound).
// 2-wave blocks, grid (48,4,4)=768 = 3 blocks/CU. gload_lds staging,
// weight register rotation, setprio, fused stats partials.
// ---------------------------------------------------------------------------
__global__ __launch_bounds__(128, 2) void conv_mfma_kernel(
    const unsigned short* __restrict__ xt,   // [4][98][98][256] bf16
    const unsigned short* __restrict__ wf,   // frag layout (see prep)
    const float* __restrict__ cb,
    float* __restrict__ out,                 // [4][256][96][96] f32
    float* __restrict__ psum)                // partials or nullptr
{
  __shared__ __align__(16) unsigned short s_in[2][784 * 8];

  int hb = blockIdx.x, coblk = blockIdx.y, b = blockIdx.z;
  int co0 = coblk * 64, h0 = hb * 2;
  int t = threadIdx.x, lane = t & 63, wv = t >> 6;
  int l31 = lane & 31, lhi = lane >> 5;
  const unsigned short* xtb = xt + (size_t)b * XT_PLANE;

  // stage chunk offsets: chunk c = t + i*128 (i<6), tail c = 768+t (t<16)
  int pre_g[6];
  #pragma unroll
  for (int i = 0; i < 6; i++) {
    int c = t + i * 128;
    int r = c / 196;
    int rem = c - r * 196;
    int half = rem / 98;
    int w = rem - half * 98;
    pre_g[i] = ((h0 + r) * 98 + w) * 256 + half * 8;
  }
  int tail_g = 0;
  if (t < 16) {
    int c = 768 + t;
    int r = c / 196;
    int rem = c - r * 196;
    int half = rem / 98;
    int w = rem - half * 98;
    tail_g = ((h0 + r) * 98 + w) * 256 + half * 8;
  }

  f32x16 acc[2][3];
  #pragma unroll
  for (int m = 0; m < 2; m++)
    #pragma unroll
    for (int n = 0; n < 3; n++)
      #pragma unroll
      for (int i = 0; i < 16; i++) acc[m][n][i] = 0.f;

  const unsigned short* wfb = wf + (size_t)(coblk * 16) * 9216 + lane * 8;

  // prologue: stage ks=0 into buf0 (async DMA + reg tail), load wa(ks=0)
  #pragma unroll
  for (int i = 0; i < 6; i++)
    gload16(xtb + pre_g[i], &s_in[0][(i * 128 + wv * 64) * 8]);
  u16x8 tl;
  if (t < 16) {
    tl = *(const u16x8*)(xtb + tail_g);
    *(u16x8*)(&s_in[0][(768 + t) * 8]) = tl;
  }
  bfrag wa[9][2];
  #pragma unroll
  for (int tap = 0; tap < 9; tap++) {
    wa[tap][0] = *(const bfrag*)(wfb + tap * 1024);
    wa[tap][1] = *(const bfrag*)(wfb + tap * 1024 + 512);
  }
  __syncthreads();

  int buf = 0;
  #pragma unroll 1
  for (int ks = 0; ks < 16; ks++) {
    // issue next K-step's staging immediately (covered by full compute)
    if (ks < 15) {
      int cib = (ks + 1) * 16;
      unsigned short* nb = s_in[buf ^ 1];
      #pragma unroll
      for (int i = 0; i < 6; i++)
        gload16(xtb + pre_g[i] + cib, &nb[(i * 128 + wv * 64) * 8]);
      if (t < 16) tl = *(const u16x8*)(xtb + tail_g + cib);
    }
    const unsigned short* sb = s_in[buf];
    int ksn = (ks < 15) ? (ks + 1) : 15;
    const unsigned short* wkn = wfb + (size_t)ksn * 9216;
    #pragma unroll
    for (int ky = 0; ky < 3; ky++) {
      const unsigned short* srow = sb + (((wv + ky) * 2 + lhi) * 98) * 8;
      bfrag bb[9];
      #pragma unroll
      for (int kx = 0; kx < 3; kx++)
        #pragma unroll
        for (int n = 0; n < 3; n++)
          bb[kx * 3 + n] = *(const bfrag*)(srow + (n * 32 + kx + l31) * 8);
      __builtin_amdgcn_s_setprio(1);
      #pragma unroll
      for (int kx = 0; kx < 3; kx++) {
        int tap = ky * 3 + kx;
        acc[0][0] = __builtin_amdgcn_mfma_f32_32x32x16_bf16(wa[tap][0], bb[kx*3+0], acc[0][0], 0, 0, 0);
        acc[1][0] = __builtin_amdgcn_mfma_f32_32x32x16_bf16(wa[tap][1], bb[kx*3+0], acc[1][0], 0, 0, 0);
        acc[0][1] = __builtin_amdgcn_mfma_f32_32x32x16_bf16(wa[tap][0], bb[kx*3+1], acc[0][1], 0, 0, 0);
        acc[1][1] = __builtin_amdgcn_mfma_f32_32x32x16_bf16(wa[tap][1], bb[kx*3+1], acc[1][1], 0, 0, 0);
        acc[0][2] = __builtin_amdgcn_mfma_f32_32x32x16_bf16(wa[tap][0], bb[kx*3+2], acc[0][2], 0, 0, 0);
        acc[1][2] = __builtin_amdgcn_mfma_f32_32x32x16_bf16(wa[tap][1], bb[kx*3+2], acc[1][2], 0, 0, 0);
        // rotate: reload this tap's frags for the NEXT K-step
        wa[tap][0] = *(const bfrag*)(wkn + tap * 1024);
        wa[tap][1] = *(const bfrag*)(wkn + tap * 1024 + 512);
      }
      __builtin_amdgcn_s_setprio(0);
    }
    if (ks < 15 && t < 16) *(u16x8*)(&s_in[buf ^ 1][(768 + t) * 8]) = tl;
    __syncthreads();
    buf ^= 1;
  }

  // epilogue: C col = lane&31 (px), row = (r&3)+8*(r>>2)+4*(lane>>5) (co)
  int h = h0 + wv;
  float bsum[2][16], bsq[2][16];
  #pragma unroll
  for (int m = 0; m < 2; m++) {
    #pragma unroll
    for (int r = 0; r < 16; r++) {
      int row = (r & 3) + 8 * (r >> 2) + 4 * lhi;
      int co = co0 + m * 32 + row;
      float bv = cb[co];
      size_t base = ((size_t)(b * 256 + co) * 96 + h) * 96;
      float s = 0.f, q = 0.f;
      #pragma unroll
      for (int n = 0; n < 3; n++) {
        float y = acc[m][n][r] + bv;
        out[base + n * 32 + l31] = y;
        s += y;
        q = fmaf(y, y, q);
      }
      bsum[m][r] = s; bsq[m][r] = q;
    }
  }
  if (psum) {
    #pragma unroll
    for (int m = 0; m < 2; m++)
      #pragma unroll
      for (int r = 0; r < 16; r++) {
        float s = bsum[m][r], q = bsq[m][r];
        #pragma unroll
        for (int off = 16; off > 0; off >>= 1) {
          s += __shfl_xor(s, off, 64);
          q += __shfl_xor(q, off, 64);
        }
        bsum[m][r] = s; bsq[m][r] = q;
      }
    if (l31 == 0) {
      float* pp = psum + ((((size_t)b * 48 + hb) * 2 + wv) * 256) * 2;
      #pragma unroll
      for (int m = 0; m < 2; m++)
        #pragma unroll
        for (int r = 0; r < 16; r++) {
          int row = (r & 3) + 8 * (r >> 2) + 4 * lhi;
          int co = co0 + m * 32 + row;
          pp[co * 2]     = bsum[m][r];
          pp[co * 2 + 1] = bsq[m][r];
        }
    }
  }
}

// ---------------------------------------------------------------------------
extern "C" void kernel_launch(void* const* d_in, const int* in_sizes, int n_in,
                              void* d_out, int out_size, void* d_ws, size_t ws_size,
                              hipStream_t stream)
{
  const float* fm    = (const float*)d_in[0];
  const float* para  = (const float*)d_in[1];
  const float* style = (const float*)d_in[2];
  const float* cw  = (const float*)d_in[3];
  const float* cb  = (const float*)d_in[4];
  const float* sw  = (const float*)d_in[5];
  const float* sb  = (const float*)d_in[6];
  const float* rw  = (const float*)d_in[7];
  const float* rb  = (const float*)d_in[8];
  const float* tw  = (const float*)d_in[9];
  const float* tb  = (const float*)d_in[10];
  const float* a1w = (const float*)d_in[11];
  const float* a1b = (const float*)d_in[12];
  const float* g1w = (const float*)d_in[13];
  const float* g1b = (const float*)d_in[14];
  const float* b1w = (const float*)d_in[15];
  const float* b1b = (const float*)d_in[16];
  const float* c1w = (const float*)d_in[17];
  const float* c1b = (const float*)d_in[18];
  const float* a2w = (const float*)d_in[19];
  const float* a2b = (const float*)d_in[20];
  const float* g2w = (const float*)d_in[21];
  const float* g2b = (const float*)d_in[22];
  const float* b2w = (const float*)d_in[23];
  const float* b2b = (const float*)d_in[24];
  const float* c2w = (const float*)d_in[25];
  const float* c2b = (const float*)d_in[26];

  float* outf = (float*)d_out;

  unsigned short* xtbuf = (unsigned short*)d_ws;                 // 4*98*98*256 bf16
  unsigned short* wf1   = xtbuf + (size_t)BATCH * XT_PLANE;      // 589824
  unsigned short* wf2   = wf1 + 9 * 256 * 256;
  float* fws  = (float*)(wf2 + 9 * 256 * 256);
  float* warp = fws;                   // 4096
  float* gb1  = warp + 4 * 1024;       // 2048
  float* gb2  = gb1 + 2 * 1024;        // 2048
  float* nrm1 = gb2 + 2 * 1024;        // 2048
  float* nrm2 = nrm1 + 2 * 1024;       // 2048
  float* pcbuf = nrm2 + 2 * 1024;      // 1024
  float* a1buf = pcbuf + 1024;         // 512
  float* a2buf = a1buf + 512;          // 512
  float* psum  = a2buf + 512;          // 4*48*2*256*2 = 98304 floats

  params_stage1_kernel<<<dim3(6, 4), 256, 0, stream>>>(para, style, cw, cb,
      a1w, a1b, a2w, a2b, pcbuf, a1buf, a2buf);
  params_stage2_kernel<<<dim3(16, 4), 256, 0, stream>>>(pcbuf, a1buf, a2buf,
      sw, sb, rw, rb, tw, tb, g1w, g1b, b1w, b1b, g2w, g2b, b2w, b2b,
      warp, gb1, gb2);
  prep_weights_kernel<<<512, 256, 0, stream>>>(c1w, c2w, wf1, wf2);
  adaat_kernel<<<1024, 256, 0, stream>>>(fm, warp, gb1, outf, nrm1);
  transpose_norm_kernel<<<dim3(98, 4), 256, 0, stream>>>(outf, nrm1, xtbuf);
  conv_mfma_kernel<<<dim3(48, 4, 4), 128, 0, stream>>>(xtbuf, wf1, c1b, outf, psum);
  finalize_stats_kernel<<<4, 256, 0, stream>>>(psum, gb2, nrm2);
  transpose_norm_kernel<<<dim3(98, 4), 256, 0, stream>>>(outf, nrm2, xtbuf);
  conv_mfma_kernel<<<dim3(48, 4, 4), 128, 0, stream>>>(xtbuf, wf2, c2b, outf, nullptr);
}

// Round 13
// 185.097 us; speedup vs baseline: 1.4583x; 1.0161x over previous
//
#include <hip/hip_runtime.h>
#include <hip/hip_bf16.h>
#include <cstddef>

#define BATCH 4
#define CH 256
#define HH 96
#define WW 96
#define HWN (HH*WW)               // 9216
#define NTOT (BATCH*CH*HWN)       // 9437184
#define XT_H 98
#define XT_W 98
#define XT_PLANE (XT_H*XT_W*CH)   // per-batch elements in xt (bf16)

typedef __attribute__((ext_vector_type(16))) float f32x16;
typedef __attribute__((ext_vector_type(8))) __bf16 bfrag;
typedef __attribute__((ext_vector_type(8))) unsigned short u16x8;

static __device__ __forceinline__ unsigned short f2bf(float f) {
  unsigned int u = __float_as_uint(f);
  unsigned int r = (u + 0x7fffu + ((u >> 16) & 1u)) >> 16;
  return (unsigned short)r;
}
static __device__ __forceinline__ float bf2f(unsigned short s) {
  return __uint_as_float(((unsigned int)s) << 16);
}

// async global->LDS, 16B per lane; LDS dest = wave-uniform base + lane*16
static __device__ __forceinline__ void gload16(const unsigned short* g,
                                               unsigned short* l) {
  __builtin_amdgcn_global_load_lds(
      (const __attribute__((address_space(1))) unsigned int*)g,
      (__attribute__((address_space(3))) unsigned int*)l, 16, 0, 0);
}

// ---------------------------------------------------------------------------
// Kernel 1a: stage-1 GEMVs, wide-parallel (unchanged R9).
// ---------------------------------------------------------------------------
__global__ __launch_bounds__(256) void params_stage1_kernel(
    const float* __restrict__ para, const float* __restrict__ style,
    const float* __restrict__ cw,  const float* __restrict__ cb,
    const float* __restrict__ a1w, const float* __restrict__ a1b,
    const float* __restrict__ a2w, const float* __restrict__ a2b,
    float* __restrict__ pcbuf, float* __restrict__ a1buf, float* __restrict__ a2buf)
{
  __shared__ float s_in[256];
  __shared__ float red[256];
  int part = blockIdx.x, b = blockIdx.y, t = threadIdx.x;
  s_in[t] = (part < 4) ? para[b*256 + t] : style[b*256 + t];
  __syncthreads();
  if (part < 4) {
    int o = t & 63, ks = t >> 6, co0 = part * 64;
    const float* wcol = cw + co0 + o;
    float acc = 0.f;
    #pragma unroll 8
    for (int i = 0; i < 64; i++) {
      int k = ks * 64 + i;
      acc = fmaf(s_in[k], wcol[k * 256], acc);
    }
    red[t] = acc;
    __syncthreads();
    if (t < 64) {
      float s = red[t] + red[t + 64] + red[t + 128] + red[t + 192];
      pcbuf[b*256 + co0 + t] = fmaxf(s + cb[co0 + t], 0.f);
    }
  } else {
    const float* w  = (part == 4) ? a1w : a2w;
    const float* bb = (part == 4) ? a1b : a2b;
    float* outp = (part == 4) ? a1buf : a2buf;
    int o = t & 127, ks = t >> 7;
    const float* wcol = w + o;
    float acc = 0.f;
    #pragma unroll 8
    for (int i = 0; i < 128; i++) {
      int k = ks * 128 + i;
      acc = fmaf(s_in[k], wcol[k * 128], acc);
    }
    red[t] = acc;
    __syncthreads();
    if (t < 128) {
      float s = red[t] + red[t + 128];
      outp[b*128 + t] = fmaxf(s + bb[t], 0.f);
    }
  }
}

// ---------------------------------------------------------------------------
// Kernel 1b: stage-2 params (unchanged R9).
// ---------------------------------------------------------------------------
__global__ __launch_bounds__(256) void params_stage2_kernel(
    const float* __restrict__ pcbuf, const float* __restrict__ a1buf,
    const float* __restrict__ a2buf,
    const float* __restrict__ sw,  const float* __restrict__ sb,
    const float* __restrict__ rw,  const float* __restrict__ rb,
    const float* __restrict__ tw,  const float* __restrict__ tb,
    const float* __restrict__ g1w, const float* __restrict__ g1b,
    const float* __restrict__ b1w, const float* __restrict__ b1b,
    const float* __restrict__ g2w, const float* __restrict__ g2b,
    const float* __restrict__ b2w, const float* __restrict__ b2b,
    float* __restrict__ warp, float* __restrict__ gb1, float* __restrict__ gb2)
{
  __shared__ float s_pc[256], s_a1[128], s_a2[128];
  __shared__ float red[8][4][16];
  int co0 = blockIdx.x * 16, b = blockIdx.y, t = threadIdx.x;
  s_pc[t] = pcbuf[b*256 + t];
  if (t < 128) s_a1[t] = a1buf[b*128 + t];
  else         s_a2[t - 128] = a2buf[b*128 + (t - 128)];
  __syncthreads();

  int cl = t & 15, klane = t >> 4;
  int c = co0 + cl;
  const float2* tw2 = (const float2*)tw;
  float ds = 0.f, dr = 0.f, dtx = 0.f, dty = 0.f;
  float g1 = 0.f, be1 = 0.f, g2 = 0.f, be2 = 0.f;
  #pragma unroll 4
  for (int kk = 0; kk < 16; kk++) {
    int i = klane * 16 + kk;
    float p = s_pc[i];
    ds  = fmaf(p, sw[i*256 + c], ds);
    dr  = fmaf(p, rw[i*256 + c], dr);
    float2 tv = tw2[i*256 + c];
    dtx = fmaf(p, tv.x, dtx);
    dty = fmaf(p, tv.y, dty);
  }
  #pragma unroll 4
  for (int kk = 0; kk < 8; kk++) {
    int i = klane * 8 + kk;
    float a = s_a1[i];
    g1  = fmaf(a, g1w[i*256 + c], g1);
    be1 = fmaf(a, b1w[i*256 + c], be1);
    float a2v = s_a2[i];
    g2  = fmaf(a2v, g2w[i*256 + c], g2);
    be2 = fmaf(a2v, b2w[i*256 + c], be2);
  }
  ds  += __shfl_down(ds, 32, 64);  ds  += __shfl_down(ds, 16, 64);
  dr  += __shfl_down(dr, 32, 64);  dr  += __shfl_down(dr, 16, 64);
  dtx += __shfl_down(dtx, 32, 64); dtx += __shfl_down(dtx, 16, 64);
  dty += __shfl_down(dty, 32, 64); dty += __shfl_down(dty, 16, 64);
  g1  += __shfl_down(g1, 32, 64);  g1  += __shfl_down(g1, 16, 64);
  be1 += __shfl_down(be1, 32, 64); be1 += __shfl_down(be1, 16, 64);
  g2  += __shfl_down(g2, 32, 64);  g2  += __shfl_down(g2, 16, 64);
  be2 += __shfl_down(be2, 32, 64); be2 += __shfl_down(be2, 16, 64);
  int wv = t >> 6;
  if ((t & 63) < 16) {
    red[0][wv][cl] = ds;  red[1][wv][cl] = dr;
    red[2][wv][cl] = dtx; red[3][wv][cl] = dty;
    red[4][wv][cl] = g1;  red[5][wv][cl] = be1;
    red[6][wv][cl] = g2;  red[7][wv][cl] = be2;
  }
  __syncthreads();
  if (t < 16) {
    float v[8];
    #pragma unroll
    for (int o = 0; o < 8; o++)
      v[o] = red[o][0][t] + red[o][1][t] + red[o][2][t] + red[o][3][t];
    int cc = co0 + t;
    int bc = b*256 + cc;
    float scale = 2.f / (1.f + expf(-(v[0] + sb[cc])));
    float ang = tanhf(v[1] + rb[cc]) * 3.14159f;
    float sn, cs;
    sincosf(ang, &sn, &cs);
    warp[bc*4 + 0] = cs * scale;
    warp[bc*4 + 1] = sn * scale;
    warp[bc*4 + 2] = tanhf(v[2] + tb[2*cc]);
    warp[bc*4 + 3] = tanhf(v[3] + tb[2*cc + 1]);
    gb1[bc*2]     = v[4] + g1b[cc];
    gb1[bc*2 + 1] = v[5] + b1b[cc];
    gb2[bc*2]     = v[6] + g2b[cc];
    gb2[bc*2 + 1] = v[7] + b2b[cc];
  }
}

// ---------------------------------------------------------------------------
// Kernel 2: weight preconversion (unchanged).
// wf[coblk4][ks16][tap9][m2][lane64][8]
// ---------------------------------------------------------------------------
__global__ __launch_bounds__(256) void prep_weights_kernel(
    const float* __restrict__ w1, const float* __restrict__ w2,
    unsigned short* __restrict__ wf1, unsigned short* __restrict__ wf2)
{
  int co = blockIdx.x & 255;
  const float* src = (blockIdx.x < 256) ? w1 : w2;
  unsigned short* dst = (blockIdx.x < 256) ? wf1 : wf2;
  int ci = threadIdx.x;
  int coblk = co >> 6, m = (co >> 5) & 1;
  int l = (co & 31) | (((ci >> 3) & 1) << 5);
  int ks = ci >> 4, j = ci & 7;
  const float* p = src + ((size_t)co * 256 + ci) * 9;
  #pragma unroll
  for (int tap = 0; tap < 9; tap++) {
    size_t idx = (((size_t)((coblk * 16 + ks) * 9 + tap) * 2 + m) * 64 + l) * 8 + j;
    dst[idx] = f2bf(p[tap]);
  }
}

// ---------------------------------------------------------------------------
// Kernel 3: AdaAT warp via LDS gather of the z-fused plane (unchanged R8).
// ---------------------------------------------------------------------------
__global__ __launch_bounds__(256) void adaat_kernel(
    const float* __restrict__ fm, const float* __restrict__ warp,
    const float* __restrict__ gb1, float* __restrict__ tout,
    float* __restrict__ nrm1)
{
  __shared__ float s[96 * 100];
  int bc = blockIdx.x;
  int b = bc >> 8, c = bc & 255;
  float csc = warp[bc*4 + 0], ssc = warp[bc*4 + 1];
  float tx = warp[bc*4 + 2], ty = warp[bc*4 + 3];

  const float axw = csc * (96.f / 95.f);
  const float axh = -ssc * (96.f / 95.f);
  const float ax0 = 48.f * (tx - csc + ssc) + 47.5f;
  const float ayw = ssc * (96.f / 95.f);
  const float ayh = csc * (96.f / 95.f);
  const float ay0 = 48.f * (ty - ssc - csc) + 47.5f;

  float iz = 256.f * (float)c / 255.f - 0.5f;
  float z0f = floorf(iz);
  float wz = iz - z0f;
  int z0 = (int)z0f;
  const float* p0 = (z0 >= 0) ? fm + (size_t)(b*256 + z0) * HWN : nullptr;
  const float* p1 = (z0 + 1 < 256) ? fm + (size_t)(b*256 + z0 + 1) * HWN : nullptr;
  float w0 = 1.f - wz, w1 = wz;

  int t = threadIdx.x;
  const float4* q0 = (const float4*)p0;
  const float4* q1 = (const float4*)p1;
  for (int i = t; i < 2304; i += 256) {
    int row = i / 24, col = i - row * 24;
    float4 r = {0.f, 0.f, 0.f, 0.f};
    if (q0) {
      float4 v = q0[i];
      r.x = w0 * v.x; r.y = w0 * v.y; r.z = w0 * v.z; r.w = w0 * v.w;
    }
    if (q1) {
      float4 v = q1[i];
      r.x = fmaf(w1, v.x, r.x); r.y = fmaf(w1, v.y, r.y);
      r.z = fmaf(w1, v.z, r.z); r.w = fmaf(w1, v.w, r.w);
    }
    *(float4*)&s[row * 100 + col * 4] = r;
  }
  __syncthreads();

  int h = t / 96, w = t - (t / 96) * 96;
  float* dst = tout + (size_t)bc * HWN;
  float sum = 0.f, sumsq = 0.f;
  #pragma unroll
  for (int k = 0; k < 36; k++) {
    float ix = fmaf(axw, (float)w, fmaf(axh, (float)h, ax0));
    float iy = fmaf(ayw, (float)w, fmaf(ayh, (float)h, ay0));
    float x0f = floorf(ix), y0f = floorf(iy);
    float wx = ix - x0f, wy = iy - y0f;
    int x0 = (int)x0f, y0 = (int)y0f;
    int x0c = min(max(x0, 0), 95), x1c = min(max(x0 + 1, 0), 95);
    int y0c = min(max(y0, 0), 95), y1c = min(max(y0 + 1, 0), 95);
    bool vx0 = (unsigned)x0 < 96u, vx1 = (unsigned)(x0 + 1) < 96u;
    bool vy0 = (unsigned)y0 < 96u, vy1 = (unsigned)(y0 + 1) < 96u;
    float a00 = s[y0c * 100 + x0c], a01 = s[y0c * 100 + x1c];
    float a10 = s[y1c * 100 + x0c], a11 = s[y1c * 100 + x1c];
    float wxm = 1.f - wx, wym = 1.f - wy;
    float w00 = (vy0 && vx0) ? wym * wxm : 0.f;
    float w01 = (vy0 && vx1) ? wym * wx  : 0.f;
    float w10 = (vy1 && vx0) ? wy * wxm  : 0.f;
    float w11 = (vy1 && vx1) ? wy * wx   : 0.f;
    float v = w00 * a00;
    v = fmaf(w01, a01, v);
    v = fmaf(w10, a10, v);
    v = fmaf(w11, a11, v);
    dst[t + k * 256] = v;
    sum += v;
    sumsq = fmaf(v, v, sumsq);
    int wn = w + 64;
    int carry = (wn >= 96) ? 1 : 0;
    w = wn - (carry ? 96 : 0);
    h += 2 + carry;
  }

  for (int off = 32; off > 0; off >>= 1) {
    sum   += __shfl_down(sum, off, 64);
    sumsq += __shfl_down(sumsq, off, 64);
  }
  __shared__ float rs[4], rq[4];
  int lane = t & 63, wvi = t >> 6;
  if (lane == 0) { rs[wvi] = sum; rq[wvi] = sumsq; }
  __syncthreads();
  if (t == 0) {
    float S = rs[0] + rs[1] + rs[2] + rs[3];
    float Q = rq[0] + rq[1] + rq[2] + rq[3];
    float m = S * (1.f / 9216.f);
    float var = Q * (1.f / 9216.f) - m * m;
    float rstd = rsqrtf(var + 1e-5f);
    float sc = (1.f + gb1[bc*2]) * rstd;
    nrm1[bc*2] = sc;
    nrm1[bc*2 + 1] = gb1[bc*2 + 1] - m * sc;
  }
}

// ---------------------------------------------------------------------------
// Kernel 4: finalize per-(b,co) stats from conv1 partials (unchanged R11).
// psum layout: [b][hb48][row2][co256][2]
// ---------------------------------------------------------------------------
__global__ __launch_bounds__(256) void finalize_stats_kernel(
    const float* __restrict__ psum, const float* __restrict__ gb,
    float* __restrict__ nrm)
{
  int bc = blockIdx.x * 256 + threadIdx.x;   // 4 blocks x 256
  int b = bc >> 8, co = bc & 255;
  float S = 0.f, Q = 0.f;
  for (int j = 0; j < 96; j++) {
    const float* p = psum + ((((size_t)b * 48 + (j >> 1)) * 2 + (j & 1)) * 256 + co) * 2;
    S += p[0];
    Q += p[1];
  }
  float m = S * (1.f / 9216.f);
  float var = Q * (1.f / 9216.f) - m * m;
  float rstd = rsqrtf(var + 1e-5f);
  float sc = (1.f + gb[bc*2]) * rstd;
  nrm[bc*2] = sc;
  nrm[bc*2 + 1] = gb[bc*2 + 1] - m * sc;
}

// ---------------------------------------------------------------------------
// Kernel 5: transpose + fused AdaIN-1 + lrelu + bf16 cvt (t -> xt1; unchanged).
// ---------------------------------------------------------------------------
__global__ __launch_bounds__(256) void transpose_norm_kernel(
    const float* __restrict__ x, const float* __restrict__ nrm,
    unsigned short* __restrict__ xt)
{
  int hi = blockIdx.x;
  int b  = blockIdx.y;
  unsigned short* dst = xt + (size_t)b * XT_PLANE + (size_t)hi * (XT_W * CH);
  int t = threadIdx.x;
  int h = hi - 1;
  u16x8 zero = {0,0,0,0,0,0,0,0};
  if (h < 0 || h >= 96) {
    for (int c = t; c < XT_W * CH / 8; c += 256) ((u16x8*)dst)[c] = zero;
    return;
  }
  __shared__ unsigned short s[96 * 256];  // [w][ci]
  int ci = t;
  float sc = nrm[(b*256 + ci)*2], bi = nrm[(b*256 + ci)*2 + 1];
  const float* src = x + ((size_t)(b*256 + ci)) * HWN + h * 96;
  for (int wg = 0; wg < 24; wg++) {
    float4 v = *(const float4*)(src + wg * 4);
    float y0 = fmaf(v.x, sc, bi); y0 = (y0 >= 0.f) ? y0 : 0.2f * y0;
    float y1 = fmaf(v.y, sc, bi); y1 = (y1 >= 0.f) ? y1 : 0.2f * y1;
    float y2 = fmaf(v.z, sc, bi); y2 = (y2 >= 0.f) ? y2 : 0.2f * y2;
    float y3 = fmaf(v.w, sc, bi); y3 = (y3 >= 0.f) ? y3 : 0.2f * y3;
    s[(wg*4 + 0) * 256 + ci] = f2bf(y0);
    s[(wg*4 + 1) * 256 + ci] = f2bf(y1);
    s[(wg*4 + 2) * 256 + ci] = f2bf(y2);
    s[(wg*4 + 3) * 256 + ci] = f2bf(y3);
  }
  __syncthreads();
  for (int c = t; c < 98 * 32; c += 256) {
    int w = c >> 5, p = c & 31;
    u16x8 v = zero;
    if (w >= 1 && w <= 96) v = *(const u16x8*)&s[(w - 1) * 256 + p * 8];
    ((u16x8*)dst)[c] = v;
  }
}

// ---------------------------------------------------------------------------
// Kernel 5b (R13): elementwise AdaIN-2 + lrelu on the bf16 xt2 buffer,
// in place, plus border zeroing. conv1 wrote the interior (pre-norm bf16).
// ---------------------------------------------------------------------------
__global__ __launch_bounds__(256) void norm2_kernel(
    unsigned short* __restrict__ xt, const float* __restrict__ nrm)
{
  int hi = blockIdx.x, b = blockIdx.y;
  unsigned short* row = xt + (size_t)b * XT_PLANE + (size_t)hi * (XT_W * CH);
  int t = threadIdx.x;
  u16x8 zero = {0,0,0,0,0,0,0,0};
  if (hi == 0 || hi == 97) {
    for (int c = t; c < XT_W * CH / 8; c += 256) ((u16x8*)row)[c] = zero;
    return;
  }
  int p = t & 31;
  float sc[8], bi[8];
  #pragma unroll
  for (int j = 0; j < 8; j++) {
    int co = p * 8 + j;
    sc[j] = nrm[(b*256 + co)*2];
    bi[j] = nrm[(b*256 + co)*2 + 1];
  }
  for (int wi = t >> 5; wi < 98; wi += 8) {
    int c = wi * 32 + p;
    if (wi == 0 || wi == 97) { ((u16x8*)row)[c] = zero; continue; }
    u16x8 v = ((u16x8*)row)[c];
    u16x8 o;
    #pragma unroll
    for (int j = 0; j < 8; j++) {
      float x = bf2f(v[j]);
      float y = fmaf(x, sc[j], bi[j]);
      y = (y >= 0.f) ? y : 0.2f * y;
      o[j] = f2bf(y);
    }
    ((u16x8*)row)[c] = o;
  }
}

// ---------------------------------------------------------------------------
// Kernel 6 (R13): conv main loop = R11-exact. Epilogue: if psum != nullptr
// (conv1), write bf16 TRANSPOSED output (xt layout) via conflict-free LDS
// bounce + stats partials; else (conv2) write f32 plane-major + bias.
// ---------------------------------------------------------------------------
__global__ __launch_bounds__(256, 3) void conv_mfma_kernel(
    const unsigned short* __restrict__ xt,   // input [4][98][98][256] bf16
    const unsigned short* __restrict__ wf,   // frag layout (see prep)
    const float* __restrict__ cb,
    float* __restrict__ out,                 // f32 output (conv2 path)
    unsigned short* __restrict__ xt2,        // bf16 transposed output (conv1)
    float* __restrict__ psum)                // partials or nullptr
{
  // staging: [2][784 chunks][8 u16]; epilogue bounce reuses as u16[13056]
  __shared__ __align__(16) unsigned short s_in[2][6528];

  int hb = blockIdx.x, coblk = blockIdx.y, b = blockIdx.z;
  int co0 = coblk * 64, h0 = hb * 2;
  int t = threadIdx.x, lane = t & 63, wv = t >> 6;
  int rw = wv >> 1, mh = wv & 1;
  int l31 = lane & 31, lhi = lane >> 5;
  const unsigned short* xtb = xt + (size_t)b * XT_PLANE;

  int pre_g[4];
  #pragma unroll
  for (int i = 0; i < 4; i++) {
    int c = t + i * 256;
    if (c < 784) {
      int r = c / 196;
      int rem = c - r * 196;
      int half = rem / 98;
      int w = rem - half * 98;
      pre_g[i] = ((h0 + r) * 98 + w) * 256 + half * 8;
    }
  }

  f32x16 acc[3];
  #pragma unroll
  for (int n = 0; n < 3; n++)
    #pragma unroll
    for (int i = 0; i < 16; i++) acc[n][i] = 0.f;

  const unsigned short* wfb = wf + (size_t)(coblk * 16) * 9216 + mh * 512 + lane * 8;

  // prologue: stage ks=0 into buf0 (async DMA + reg tail), load wa(ks=0)
  {
    #pragma unroll
    for (int i = 0; i < 3; i++)
      gload16(xtb + pre_g[i], &s_in[0][(i * 256 + wv * 64) * 8]);
    u16x8 tail0;
    if (t < 16) tail0 = *(const u16x8*)(xtb + pre_g[3]);
    if (t < 16) *(u16x8*)(&s_in[0][(768 + t) * 8]) = tail0;
  }
  bfrag wa[9];
  #pragma unroll
  for (int tap = 0; tap < 9; tap++) wa[tap] = *(const bfrag*)(wfb + tap * 1024);
  __syncthreads();

  int buf = 0;
  u16x8 tail;
  #pragma unroll 1
  for (int ks = 0; ks < 16; ks++) {
    if (ks < 15) {
      int cib = (ks + 1) * 16;
      unsigned short* nb = s_in[buf ^ 1];
      #pragma unroll
      for (int i = 0; i < 3; i++)
        gload16(xtb + pre_g[i] + cib, &nb[(i * 256 + wv * 64) * 8]);
      if (t < 16) tail = *(const u16x8*)(xtb + pre_g[3] + cib);
    }
    const unsigned short* sb = s_in[buf];
    int ksn = (ks < 15) ? (ks + 1) : 15;
    const unsigned short* wkn = wfb + (size_t)ksn * 9216;
    #pragma unroll
    for (int ky = 0; ky < 3; ky++) {
      const unsigned short* srow = sb + (((rw + ky) * 2 + lhi) * 98) * 8;
      bfrag bb[9];
      #pragma unroll
      for (int kx = 0; kx < 3; kx++)
        #pragma unroll
        for (int n = 0; n < 3; n++)
          bb[kx * 3 + n] = *(const bfrag*)(srow + (n * 32 + kx + l31) * 8);
      __builtin_amdgcn_s_setprio(1);
      #pragma unroll
      for (int kx = 0; kx < 3; kx++) {
        int tap = ky * 3 + kx;
        acc[0] = __builtin_amdgcn_mfma_f32_32x32x16_bf16(wa[tap], bb[kx*3+0], acc[0], 0, 0, 0);
        acc[1] = __builtin_amdgcn_mfma_f32_32x32x16_bf16(wa[tap], bb[kx*3+1], acc[1], 0, 0, 0);
        acc[2] = __builtin_amdgcn_mfma_f32_32x32x16_bf16(wa[tap], bb[kx*3+2], acc[2], 0, 0, 0);
        wa[tap] = *(const bfrag*)(wkn + tap * 1024);
      }
      __builtin_amdgcn_s_setprio(0);
    }
    if (ks < 15 && t < 16) *(u16x8*)(&s_in[buf ^ 1][(768 + t) * 8]) = tail;
    __syncthreads();
    buf ^= 1;
  }

  // epilogue
  int h = h0 + rw;
  if (psum) {
    // --- conv1: bf16 transposed output via LDS bounce + stats partials ---
    unsigned short* tb = (unsigned short*)s_in;   // [2 rows][96 px][68 co-pad]
    float bsum[16], bsq[16];
    #pragma unroll
    for (int r = 0; r < 16; r++) {
      int row = (r & 3) + 8 * (r >> 2) + 4 * lhi;
      int col = mh * 32 + row;                    // co within 64-tile
      float bv = cb[co0 + col];
      float s = 0.f, q = 0.f;
      #pragma unroll
      for (int n = 0; n < 3; n++) {
        float y = acc[n][r] + bv;
        int px = n * 32 + l31;
        tb[(rw * 96 + px) * 68 + col] = f2bf(y);
        s += y;
        q = fmaf(y, y, q);
      }
      bsum[r] = s; bsq[r] = q;
    }
    // stats partial: reduce across the 32 px-lanes (xor strides < 32)
    #pragma unroll
    for (int r = 0; r < 16; r++) {
      float s = bsum[r], q = bsq[r];
      #pragma unroll
      for (int off = 16; off > 0; off >>= 1) {
        s += __shfl_xor(s, off, 64);
        q += __shfl_xor(q, off, 64);
      }
      bsum[r] = s; bsq[r] = q;
    }
    if (l31 == 0) {
      float* pp = psum + ((((size_t)b * 48 + hb) * 2 + rw) * 256) * 2;
      #pragma unroll
      for (int r = 0; r < 16; r++) {
        int row = (r & 3) + 8 * (r >> 2) + 4 * lhi;
        int co = co0 + mh * 32 + row;
        pp[co * 2]     = bsum[r];
        pp[co * 2 + 1] = bsq[r];
      }
    }
    __syncthreads();
    // read back coalesced: 1536 16B chunks = [row2][wi 0..95][p8 0..7]
    unsigned short* dstb = xt2 + (size_t)b * XT_PLANE;
    #pragma unroll
    for (int i = 0; i < 6; i++) {
      int c = t + i * 256;
      int row2 = c / 768;
      int rem = c - row2 * 768;
      int wi = rem >> 3, p8 = rem & 7;
      const unsigned short* lsrc = &tb[(row2 * 96 + wi) * 68 + p8 * 8];
      uint2 lo = *(const uint2*)lsrc;
      uint2 hi2 = *(const uint2*)(lsrc + 4);
      size_t ga = ((size_t)(h0 + 1 + row2) * 98 + (wi + 1)) * 256 + co0 + p8 * 8;
      uint4 vv; vv.x = lo.x; vv.y = lo.y; vv.z = hi2.x; vv.w = hi2.y;
      *(uint4*)&dstb[ga] = vv;
    }
  } else {
    // --- conv2: f32 plane-major output ---
    #pragma unroll
    for (int r = 0; r < 16; r++) {
      int row = (r & 3) + 8 * (r >> 2) + 4 * lhi;
      int co = co0 + mh * 32 + row;
      float bv = cb[co];
      size_t base = ((size_t)(b * 256 + co) * 96 + h) * 96;
      #pragma unroll
      for (int n = 0; n < 3; n++) {
        out[base + n * 32 + l31] = acc[n][r] + bv;
      }
    }
  }
}

// ---------------------------------------------------------------------------
extern "C" void kernel_launch(void* const* d_in, const int* in_sizes, int n_in,
                              void* d_out, int out_size, void* d_ws, size_t ws_size,
                              hipStream_t stream)
{
  const float* fm    = (const float*)d_in[0];
  const float* para  = (const float*)d_in[1];
  const float* style = (const float*)d_in[2];
  const float* cw  = (const float*)d_in[3];
  const float* cb  = (const float*)d_in[4];
  const float* sw  = (const float*)d_in[5];
  const float* sb  = (const float*)d_in[6];
  const float* rw  = (const float*)d_in[7];
  const float* rb  = (const float*)d_in[8];
  const float* tw  = (const float*)d_in[9];
  const float* tb  = (const float*)d_in[10];
  const float* a1w = (const float*)d_in[11];
  const float* a1b = (const float*)d_in[12];
  const float* g1w = (const float*)d_in[13];
  const float* g1b = (const float*)d_in[14];
  const float* b1w = (const float*)d_in[15];
  const float* b1b = (const float*)d_in[16];
  const float* c1w = (const float*)d_in[17];
  const float* c1b = (const float*)d_in[18];
  const float* a2w = (const float*)d_in[19];
  const float* a2b = (const float*)d_in[20];
  const float* g2w = (const float*)d_in[21];
  const float* g2b = (const float*)d_in[22];
  const float* b2w = (const float*)d_in[23];
  const float* b2b = (const float*)d_in[24];
  const float* c2w = (const float*)d_in[25];
  const float* c2b = (const float*)d_in[26];

  float* outf = (float*)d_out;

  unsigned short* xtbuf  = (unsigned short*)d_ws;                 // xt1
  unsigned short* xt2buf = xtbuf + (size_t)BATCH * XT_PLANE;      // xt2
  unsigned short* wf1    = xt2buf + (size_t)BATCH * XT_PLANE;
  unsigned short* wf2    = wf1 + 9 * 256 * 256;
  float* fws  = (float*)(wf2 + 9 * 256 * 256);
  float* warp = fws;                   // 4096
  float* gb1  = warp + 4 * 1024;       // 2048
  float* gb2  = gb1 + 2 * 1024;        // 2048
  float* nrm1 = gb2 + 2 * 1024;        // 2048
  float* nrm2 = nrm1 + 2 * 1024;       // 2048
  float* pcbuf = nrm2 + 2 * 1024;      // 1024
  float* a1buf = pcbuf + 1024;         // 512
  float* a2buf = a1buf + 512;          // 512
  float* psum  = a2buf + 512;          // 4*48*2*256*2 = 98304 floats

  params_stage1_kernel<<<dim3(6, 4), 256, 0, stream>>>(para, style, cw, cb,
      a1w, a1b, a2w, a2b, pcbuf, a1buf, a2buf);
  params_stage2_kernel<<<dim3(16, 4), 256, 0, stream>>>(pcbuf, a1buf, a2buf,
      sw, sb, rw, rb, tw, tb, g1w, g1b, b1w, b1b, g2w, g2b, b2w, b2b,
      warp, gb1, gb2);
  prep_weights_kernel<<<512, 256, 0, stream>>>(c1w, c2w, wf1, wf2);
  // t (f32 plane-major) lives in d_out until transpose_norm consumes it
  adaat_kernel<<<1024, 256, 0, stream>>>(fm, warp, gb1, outf, nrm1);
  transpose_norm_kernel<<<dim3(98, 4), 256, 0, stream>>>(outf, nrm1, xtbuf);
  // conv1: writes xt2 (bf16 transposed, pre-norm) + stats partials
  conv_mfma_kernel<<<dim3(48, 4, 4), 256, 0, stream>>>(xtbuf, wf1, c1b,
      outf, xt2buf, psum);
  finalize_stats_kernel<<<4, 256, 0, stream>>>(psum, gb2, nrm2);
  // AdaIN-2 + lrelu in place on xt2 (+ border zeroing)
  norm2_kernel<<<dim3(98, 4), 256, 0, stream>>>(xt2buf, nrm2);
  // conv2: final f32 output
  conv_mfma_kernel<<<dim3(48, 4, 4), 256, 0, stream>>>(xt2buf, wf2, c2b,
      outf, nullptr, nullptr);
}

// Round 14
// 183.524 us; speedup vs baseline: 1.4708x; 1.0086x over previous
//
#include <hip/hip_runtime.h>
#include <hip/hip_bf16.h>
#include <cstddef>

#define BATCH 4
#define CH 256
#define HH 96
#define WW 96
#define HWN (HH*WW)               // 9216
#define NTOT (BATCH*CH*HWN)       // 9437184
#define XT_H 98
#define XT_W 98
#define XT_PLANE (XT_H*XT_W*CH)   // per-batch elements in xt (bf16)

typedef __attribute__((ext_vector_type(16))) float f32x16;
typedef __attribute__((ext_vector_type(8))) __bf16 bfrag;
typedef __attribute__((ext_vector_type(8))) unsigned short u16x8;

static __device__ __forceinline__ unsigned short f2bf(float f) {
  unsigned int u = __float_as_uint(f);
  unsigned int r = (u + 0x7fffu + ((u >> 16) & 1u)) >> 16;
  return (unsigned short)r;
}
static __device__ __forceinline__ float bf2f(unsigned short s) {
  return __uint_as_float(((unsigned int)s) << 16);
}

// async global->LDS, 16B per lane; LDS dest = wave-uniform base + lane*16
static __device__ __forceinline__ void gload16(const unsigned short* g,
                                               unsigned short* l) {
  __builtin_amdgcn_global_load_lds(
      (const __attribute__((address_space(1))) unsigned int*)g,
      (__attribute__((address_space(3))) unsigned int*)l, 16, 0, 0);
}

// ---------------------------------------------------------------------------
// Kernel 1a: stage-1 GEMVs, wide-parallel (unchanged R9).
// ---------------------------------------------------------------------------
__global__ __launch_bounds__(256) void params_stage1_kernel(
    const float* __restrict__ para, const float* __restrict__ style,
    const float* __restrict__ cw,  const float* __restrict__ cb,
    const float* __restrict__ a1w, const float* __restrict__ a1b,
    const float* __restrict__ a2w, const float* __restrict__ a2b,
    float* __restrict__ pcbuf, float* __restrict__ a1buf, float* __restrict__ a2buf)
{
  __shared__ float s_in[256];
  __shared__ float red[256];
  int part = blockIdx.x, b = blockIdx.y, t = threadIdx.x;
  s_in[t] = (part < 4) ? para[b*256 + t] : style[b*256 + t];
  __syncthreads();
  if (part < 4) {
    int o = t & 63, ks = t >> 6, co0 = part * 64;
    const float* wcol = cw + co0 + o;
    float acc = 0.f;
    #pragma unroll 8
    for (int i = 0; i < 64; i++) {
      int k = ks * 64 + i;
      acc = fmaf(s_in[k], wcol[k * 256], acc);
    }
    red[t] = acc;
    __syncthreads();
    if (t < 64) {
      float s = red[t] + red[t + 64] + red[t + 128] + red[t + 192];
      pcbuf[b*256 + co0 + t] = fmaxf(s + cb[co0 + t], 0.f);
    }
  } else {
    const float* w  = (part == 4) ? a1w : a2w;
    const float* bb = (part == 4) ? a1b : a2b;
    float* outp = (part == 4) ? a1buf : a2buf;
    int o = t & 127, ks = t >> 7;
    const float* wcol = w + o;
    float acc = 0.f;
    #pragma unroll 8
    for (int i = 0; i < 128; i++) {
      int k = ks * 128 + i;
      acc = fmaf(s_in[k], wcol[k * 128], acc);
    }
    red[t] = acc;
    __syncthreads();
    if (t < 128) {
      float s = red[t] + red[t + 128];
      outp[b*128 + t] = fmaxf(s + bb[t], 0.f);
    }
  }
}

// ---------------------------------------------------------------------------
// Kernel 1b: stage-2 params (unchanged R9).
// ---------------------------------------------------------------------------
__global__ __launch_bounds__(256) void params_stage2_kernel(
    const float* __restrict__ pcbuf, const float* __restrict__ a1buf,
    const float* __restrict__ a2buf,
    const float* __restrict__ sw,  const float* __restrict__ sb,
    const float* __restrict__ rw,  const float* __restrict__ rb,
    const float* __restrict__ tw,  const float* __restrict__ tb,
    const float* __restrict__ g1w, const float* __restrict__ g1b,
    const float* __restrict__ b1w, const float* __restrict__ b1b,
    const float* __restrict__ g2w, const float* __restrict__ g2b,
    const float* __restrict__ b2w, const float* __restrict__ b2b,
    float* __restrict__ warp, float* __restrict__ gb1, float* __restrict__ gb2)
{
  __shared__ float s_pc[256], s_a1[128], s_a2[128];
  __shared__ float red[8][4][16];
  int co0 = blockIdx.x * 16, b = blockIdx.y, t = threadIdx.x;
  s_pc[t] = pcbuf[b*256 + t];
  if (t < 128) s_a1[t] = a1buf[b*128 + t];
  else         s_a2[t - 128] = a2buf[b*128 + (t - 128)];
  __syncthreads();

  int cl = t & 15, klane = t >> 4;
  int c = co0 + cl;
  const float2* tw2 = (const float2*)tw;
  float ds = 0.f, dr = 0.f, dtx = 0.f, dty = 0.f;
  float g1 = 0.f, be1 = 0.f, g2 = 0.f, be2 = 0.f;
  #pragma unroll 4
  for (int kk = 0; kk < 16; kk++) {
    int i = klane * 16 + kk;
    float p = s_pc[i];
    ds  = fmaf(p, sw[i*256 + c], ds);
    dr  = fmaf(p, rw[i*256 + c], dr);
    float2 tv = tw2[i*256 + c];
    dtx = fmaf(p, tv.x, dtx);
    dty = fmaf(p, tv.y, dty);
  }
  #pragma unroll 4
  for (int kk = 0; kk < 8; kk++) {
    int i = klane * 8 + kk;
    float a = s_a1[i];
    g1  = fmaf(a, g1w[i*256 + c], g1);
    be1 = fmaf(a, b1w[i*256 + c], be1);
    float a2v = s_a2[i];
    g2  = fmaf(a2v, g2w[i*256 + c], g2);
    be2 = fmaf(a2v, b2w[i*256 + c], be2);
  }
  ds  += __shfl_down(ds, 32, 64);  ds  += __shfl_down(ds, 16, 64);
  dr  += __shfl_down(dr, 32, 64);  dr  += __shfl_down(dr, 16, 64);
  dtx += __shfl_down(dtx, 32, 64); dtx += __shfl_down(dtx, 16, 64);
  dty += __shfl_down(dty, 32, 64); dty += __shfl_down(dty, 16, 64);
  g1  += __shfl_down(g1, 32, 64);  g1  += __shfl_down(g1, 16, 64);
  be1 += __shfl_down(be1, 32, 64); be1 += __shfl_down(be1, 16, 64);
  g2  += __shfl_down(g2, 32, 64);  g2  += __shfl_down(g2, 16, 64);
  be2 += __shfl_down(be2, 32, 64); be2 += __shfl_down(be2, 16, 64);
  int wv = t >> 6;
  if ((t & 63) < 16) {
    red[0][wv][cl] = ds;  red[1][wv][cl] = dr;
    red[2][wv][cl] = dtx; red[3][wv][cl] = dty;
    red[4][wv][cl] = g1;  red[5][wv][cl] = be1;
    red[6][wv][cl] = g2;  red[7][wv][cl] = be2;
  }
  __syncthreads();
  if (t < 16) {
    float v[8];
    #pragma unroll
    for (int o = 0; o < 8; o++)
      v[o] = red[o][0][t] + red[o][1][t] + red[o][2][t] + red[o][3][t];
    int cc = co0 + t;
    int bc = b*256 + cc;
    float scale = 2.f / (1.f + expf(-(v[0] + sb[cc])));
    float ang = tanhf(v[1] + rb[cc]) * 3.14159f;
    float sn, cs;
    sincosf(ang, &sn, &cs);
    warp[bc*4 + 0] = cs * scale;
    warp[bc*4 + 1] = sn * scale;
    warp[bc*4 + 2] = tanhf(v[2] + tb[2*cc]);
    warp[bc*4 + 3] = tanhf(v[3] + tb[2*cc + 1]);
    gb1[bc*2]     = v[4] + g1b[cc];
    gb1[bc*2 + 1] = v[5] + b1b[cc];
    gb2[bc*2]     = v[6] + g2b[cc];
    gb2[bc*2 + 1] = v[7] + b2b[cc];
  }
}

// ---------------------------------------------------------------------------
// Kernel 2: weight preconversion (unchanged).
// wf[coblk4][ks16][tap9][m2][lane64][8]
// ---------------------------------------------------------------------------
__global__ __launch_bounds__(256) void prep_weights_kernel(
    const float* __restrict__ w1, const float* __restrict__ w2,
    unsigned short* __restrict__ wf1, unsigned short* __restrict__ wf2)
{
  int co = blockIdx.x & 255;
  const float* src = (blockIdx.x < 256) ? w1 : w2;
  unsigned short* dst = (blockIdx.x < 256) ? wf1 : wf2;
  int ci = threadIdx.x;
  int coblk = co >> 6, m = (co >> 5) & 1;
  int l = (co & 31) | (((ci >> 3) & 1) << 5);
  int ks = ci >> 4, j = ci & 7;
  const float* p = src + ((size_t)co * 256 + ci) * 9;
  #pragma unroll
  for (int tap = 0; tap < 9; tap++) {
    size_t idx = (((size_t)((coblk * 16 + ks) * 9 + tap) * 2 + m) * 64 + l) * 8 + j;
    dst[idx] = f2bf(p[tap]);
  }
}

// ---------------------------------------------------------------------------
// Kernel 3 (R14): AdaAT warp + fused stats + AdaIN-1 + lrelu + bf16 cvt.
// Gathers into registers (vals[36]), block-reduces stats, applies norm
// in-register, writes bf16 t (plane-major). Identical rounding to R13.
// ---------------------------------------------------------------------------
__global__ __launch_bounds__(256) void adaat_kernel(
    const float* __restrict__ fm, const float* __restrict__ warp,
    const float* __restrict__ gb1, unsigned short* __restrict__ tout)
{
  __shared__ float s[96 * 100];
  int bc = blockIdx.x;
  int b = bc >> 8, c = bc & 255;
  float csc = warp[bc*4 + 0], ssc = warp[bc*4 + 1];
  float tx = warp[bc*4 + 2], ty = warp[bc*4 + 3];

  const float axw = csc * (96.f / 95.f);
  const float axh = -ssc * (96.f / 95.f);
  const float ax0 = 48.f * (tx - csc + ssc) + 47.5f;
  const float ayw = ssc * (96.f / 95.f);
  const float ayh = csc * (96.f / 95.f);
  const float ay0 = 48.f * (ty - ssc - csc) + 47.5f;

  float iz = 256.f * (float)c / 255.f - 0.5f;
  float z0f = floorf(iz);
  float wz = iz - z0f;
  int z0 = (int)z0f;
  const float* p0 = (z0 >= 0) ? fm + (size_t)(b*256 + z0) * HWN : nullptr;
  const float* p1 = (z0 + 1 < 256) ? fm + (size_t)(b*256 + z0 + 1) * HWN : nullptr;
  float w0 = 1.f - wz, w1 = wz;

  int t = threadIdx.x;
  const float4* q0 = (const float4*)p0;
  const float4* q1 = (const float4*)p1;
  for (int i = t; i < 2304; i += 256) {
    int row = i / 24, col = i - row * 24;
    float4 r = {0.f, 0.f, 0.f, 0.f};
    if (q0) {
      float4 v = q0[i];
      r.x = w0 * v.x; r.y = w0 * v.y; r.z = w0 * v.z; r.w = w0 * v.w;
    }
    if (q1) {
      float4 v = q1[i];
      r.x = fmaf(w1, v.x, r.x); r.y = fmaf(w1, v.y, r.y);
      r.z = fmaf(w1, v.z, r.z); r.w = fmaf(w1, v.w, r.w);
    }
    *(float4*)&s[row * 100 + col * 4] = r;
  }
  __syncthreads();

  int h = t / 96, w = t - (t / 96) * 96;
  float vals[36];
  float sum = 0.f, sumsq = 0.f;
  #pragma unroll
  for (int k = 0; k < 36; k++) {
    float ix = fmaf(axw, (float)w, fmaf(axh, (float)h, ax0));
    float iy = fmaf(ayw, (float)w, fmaf(ayh, (float)h, ay0));
    float x0f = floorf(ix), y0f = floorf(iy);
    float wx = ix - x0f, wy = iy - y0f;
    int x0 = (int)x0f, y0 = (int)y0f;
    int x0c = min(max(x0, 0), 95), x1c = min(max(x0 + 1, 0), 95);
    int y0c = min(max(y0, 0), 95), y1c = min(max(y0 + 1, 0), 95);
    bool vx0 = (unsigned)x0 < 96u, vx1 = (unsigned)(x0 + 1) < 96u;
    bool vy0 = (unsigned)y0 < 96u, vy1 = (unsigned)(y0 + 1) < 96u;
    float a00 = s[y0c * 100 + x0c], a01 = s[y0c * 100 + x1c];
    float a10 = s[y1c * 100 + x0c], a11 = s[y1c * 100 + x1c];
    float wxm = 1.f - wx, wym = 1.f - wy;
    float w00 = (vy0 && vx0) ? wym * wxm : 0.f;
    float w01 = (vy0 && vx1) ? wym * wx  : 0.f;
    float w10 = (vy1 && vx0) ? wy * wxm  : 0.f;
    float w11 = (vy1 && vx1) ? wy * wx   : 0.f;
    float v = w00 * a00;
    v = fmaf(w01, a01, v);
    v = fmaf(w10, a10, v);
    v = fmaf(w11, a11, v);
    vals[k] = v;
    sum += v;
    sumsq = fmaf(v, v, sumsq);
    int wn = w + 64;
    int carry = (wn >= 96) ? 1 : 0;
    w = wn - (carry ? 96 : 0);
    h += 2 + carry;
  }

  for (int off = 32; off > 0; off >>= 1) {
    sum   += __shfl_down(sum, off, 64);
    sumsq += __shfl_down(sumsq, off, 64);
  }
  __shared__ float rs[4], rq[4], sbi[2];
  int lane = t & 63, wvi = t >> 6;
  if (lane == 0) { rs[wvi] = sum; rq[wvi] = sumsq; }
  __syncthreads();
  if (t == 0) {
    float S = rs[0] + rs[1] + rs[2] + rs[3];
    float Q = rq[0] + rq[1] + rq[2] + rq[3];
    float m = S * (1.f / 9216.f);
    float var = Q * (1.f / 9216.f) - m * m;
    float rstd = rsqrtf(var + 1e-5f);
    float sc = (1.f + gb1[bc*2]) * rstd;
    sbi[0] = sc;
    sbi[1] = gb1[bc*2 + 1] - m * sc;
  }
  __syncthreads();
  float sc = sbi[0], bi = sbi[1];
  unsigned short* dst = tout + (size_t)bc * HWN + t;
  #pragma unroll
  for (int k = 0; k < 36; k++) {
    float y = fmaf(vals[k], sc, bi);
    y = (y >= 0.f) ? y : 0.2f * y;
    dst[k * 256] = f2bf(y);
  }
}

// ---------------------------------------------------------------------------
// Kernel 4: finalize per-(b,co) stats from conv1 partials (unchanged R11).
// psum layout: [b][hb48][row2][co256][2]
// ---------------------------------------------------------------------------
__global__ __launch_bounds__(256) void finalize_stats_kernel(
    const float* __restrict__ psum, const float* __restrict__ gb,
    float* __restrict__ nrm)
{
  int bc = blockIdx.x * 256 + threadIdx.x;   // 4 blocks x 256
  int b = bc >> 8, co = bc & 255;
  float S = 0.f, Q = 0.f;
  for (int j = 0; j < 96; j++) {
    const float* p = psum + ((((size_t)b * 48 + (j >> 1)) * 2 + (j & 1)) * 256 + co) * 2;
    S += p[0];
    Q += p[1];
  }
  float m = S * (1.f / 9216.f);
  float var = Q * (1.f / 9216.f) - m * m;
  float rstd = rsqrtf(var + 1e-5f);
  float sc = (1.f + gb[bc*2]) * rstd;
  nrm[bc*2] = sc;
  nrm[bc*2 + 1] = gb[bc*2 + 1] - m * sc;
}

// ---------------------------------------------------------------------------
// Kernel 5 (R14): pure bf16 transpose t(plane-major) -> xt layout + borders.
// ---------------------------------------------------------------------------
__global__ __launch_bounds__(256) void transpose_kernel(
    const unsigned short* __restrict__ tb, unsigned short* __restrict__ xt)
{
  int hi = blockIdx.x;
  int b  = blockIdx.y;
  unsigned short* dst = xt + (size_t)b * XT_PLANE + (size_t)hi * (XT_W * CH);
  int t = threadIdx.x;
  int h = hi - 1;
  u16x8 zero = {0,0,0,0,0,0,0,0};
  if (h < 0 || h >= 96) {
    for (int c = t; c < XT_W * CH / 8; c += 256) ((u16x8*)dst)[c] = zero;
    return;
  }
  __shared__ unsigned short s[96 * 256];  // [w][ci]
  int ci = t;
  const unsigned short* src = tb + ((size_t)(b*256 + ci)) * HWN + h * 96;
  #pragma unroll
  for (int wg = 0; wg < 12; wg++) {
    u16x8 v = *(const u16x8*)(src + wg * 8);
    #pragma unroll
    for (int j = 0; j < 8; j++) s[(wg*8 + j) * 256 + ci] = v[j];
  }
  __syncthreads();
  for (int c = t; c < 98 * 32; c += 256) {
    int w = c >> 5, p = c & 31;
    u16x8 v = zero;
    if (w >= 1 && w <= 96) v = *(const u16x8*)&s[(w - 1) * 256 + p * 8];
    ((u16x8*)dst)[c] = v;
  }
}

// ---------------------------------------------------------------------------
// Kernel 5b: elementwise AdaIN-2 + lrelu on bf16 xt2, in place (unchanged R13).
// ---------------------------------------------------------------------------
__global__ __launch_bounds__(256) void norm2_kernel(
    unsigned short* __restrict__ xt, const float* __restrict__ nrm)
{
  int hi = blockIdx.x, b = blockIdx.y;
  unsigned short* row = xt + (size_t)b * XT_PLANE + (size_t)hi * (XT_W * CH);
  int t = threadIdx.x;
  u16x8 zero = {0,0,0,0,0,0,0,0};
  if (hi == 0 || hi == 97) {
    for (int c = t; c < XT_W * CH / 8; c += 256) ((u16x8*)row)[c] = zero;
    return;
  }
  int p = t & 31;
  float sc[8], bi[8];
  #pragma unroll
  for (int j = 0; j < 8; j++) {
    int co = p * 8 + j;
    sc[j] = nrm[(b*256 + co)*2];
    bi[j] = nrm[(b*256 + co)*2 + 1];
  }
  for (int wi = t >> 5; wi < 98; wi += 8) {
    int c = wi * 32 + p;
    if (wi == 0 || wi == 97) { ((u16x8*)row)[c] = zero; continue; }
    u16x8 v = ((u16x8*)row)[c];
    u16x8 o;
    #pragma unroll
    for (int j = 0; j < 8; j++) {
      float x = bf2f(v[j]);
      float y = fmaf(x, sc[j], bi[j]);
      y = (y >= 0.f) ? y : 0.2f * y;
      o[j] = f2bf(y);
    }
    ((u16x8*)row)[c] = o;
  }
}

// ---------------------------------------------------------------------------
// Kernel 6 (R14): conv = R13 main loop; 1-D grid with XCD-pinned coblk
// decode (n&7 determines coblk -> each XCD-L2 keeps ONE weight slice hot).
// ---------------------------------------------------------------------------
__global__ __launch_bounds__(256, 3) void conv_mfma_kernel(
    const unsigned short* __restrict__ xt,   // input [4][98][98][256] bf16
    const unsigned short* __restrict__ wf,   // frag layout (see prep)
    const float* __restrict__ cb,
    float* __restrict__ out,                 // f32 output (conv2 path)
    unsigned short* __restrict__ xt2,        // bf16 transposed output (conv1)
    float* __restrict__ psum)                // partials or nullptr
{
  __shared__ __align__(16) unsigned short s_in[2][6528];

  // XCD-pinned decode: xcd = n&7 -> coblk = n&3; bijective over 768
  int n = blockIdx.x;
  int coblk = n & 3;
  int bit2 = (n >> 2) & 1;
  int j = n >> 3;              // 0..95
  int hb = j % 48;
  int b = (j / 48) * 2 + bit2;

  int co0 = coblk * 64, h0 = hb * 2;
  int t = threadIdx.x, lane = t & 63, wv = t >> 6;
  int rw = wv >> 1, mh = wv & 1;
  int l31 = lane & 31, lhi = lane >> 5;
  const unsigned short* xtb = xt + (size_t)b * XT_PLANE;

  int pre_g[4];
  #pragma unroll
  for (int i = 0; i < 4; i++) {
    int c = t + i * 256;
    if (c < 784) {
      int r = c / 196;
      int rem = c - r * 196;
      int half = rem / 98;
      int w = rem - half * 98;
      pre_g[i] = ((h0 + r) * 98 + w) * 256 + half * 8;
    }
  }

  f32x16 acc[3];
  #pragma unroll
  for (int nn = 0; nn < 3; nn++)
    #pragma unroll
    for (int i = 0; i < 16; i++) acc[nn][i] = 0.f;

  const unsigned short* wfb = wf + (size_t)(coblk * 16) * 9216 + mh * 512 + lane * 8;

  {
    #pragma unroll
    for (int i = 0; i < 3; i++)
      gload16(xtb + pre_g[i], &s_in[0][(i * 256 + wv * 64) * 8]);
    u16x8 tail0;
    if (t < 16) tail0 = *(const u16x8*)(xtb + pre_g[3]);
    if (t < 16) *(u16x8*)(&s_in[0][(768 + t) * 8]) = tail0;
  }
  bfrag wa[9];
  #pragma unroll
  for (int tap = 0; tap < 9; tap++) wa[tap] = *(const bfrag*)(wfb + tap * 1024);
  __syncthreads();

  int buf = 0;
  u16x8 tail;
  #pragma unroll 1
  for (int ks = 0; ks < 16; ks++) {
    if (ks < 15) {
      int cib = (ks + 1) * 16;
      unsigned short* nb = s_in[buf ^ 1];
      #pragma unroll
      for (int i = 0; i < 3; i++)
        gload16(xtb + pre_g[i] + cib, &nb[(i * 256 + wv * 64) * 8]);
      if (t < 16) tail = *(const u16x8*)(xtb + pre_g[3] + cib);
    }
    const unsigned short* sb = s_in[buf];
    int ksn = (ks < 15) ? (ks + 1) : 15;
    const unsigned short* wkn = wfb + (size_t)ksn * 9216;
    #pragma unroll
    for (int ky = 0; ky < 3; ky++) {
      const unsigned short* srow = sb + (((rw + ky) * 2 + lhi) * 98) * 8;
      bfrag bb[9];
      #pragma unroll
      for (int kx = 0; kx < 3; kx++)
        #pragma unroll
        for (int nn = 0; nn < 3; nn++)
          bb[kx * 3 + nn] = *(const bfrag*)(srow + (nn * 32 + kx + l31) * 8);
      __builtin_amdgcn_s_setprio(1);
      #pragma unroll
      for (int kx = 0; kx < 3; kx++) {
        int tap = ky * 3 + kx;
        acc[0] = __builtin_amdgcn_mfma_f32_32x32x16_bf16(wa[tap], bb[kx*3+0], acc[0], 0, 0, 0);
        acc[1] = __builtin_amdgcn_mfma_f32_32x32x16_bf16(wa[tap], bb[kx*3+1], acc[1], 0, 0, 0);
        acc[2] = __builtin_amdgcn_mfma_f32_32x32x16_bf16(wa[tap], bb[kx*3+2], acc[2], 0, 0, 0);
        wa[tap] = *(const bfrag*)(wkn + tap * 1024);
      }
      __builtin_amdgcn_s_setprio(0);
    }
    if (ks < 15 && t < 16) *(u16x8*)(&s_in[buf ^ 1][(768 + t) * 8]) = tail;
    __syncthreads();
    buf ^= 1;
  }

  int h = h0 + rw;
  if (psum) {
    // conv1: bf16 transposed output via LDS bounce + stats partials
    unsigned short* tbl = (unsigned short*)s_in;   // [2 rows][96 px][68 co-pad]
    float bsum[16], bsq[16];
    #pragma unroll
    for (int r = 0; r < 16; r++) {
      int row = (r & 3) + 8 * (r >> 2) + 4 * lhi;
      int col = mh * 32 + row;
      float bv = cb[co0 + col];
      float s = 0.f, q = 0.f;
      #pragma unroll
      for (int nn = 0; nn < 3; nn++) {
        float y = acc[nn][r] + bv;
        int px = nn * 32 + l31;
        tbl[(rw * 96 + px) * 68 + col] = f2bf(y);
        s += y;
        q = fmaf(y, y, q);
      }
      bsum[r] = s; bsq[r] = q;
    }
    #pragma unroll
    for (int r = 0; r < 16; r++) {
      float s = bsum[r], q = bsq[r];
      #pragma unroll
      for (int off = 16; off > 0; off >>= 1) {
        s += __shfl_xor(s, off, 64);
        q += __shfl_xor(q, off, 64);
      }
      bsum[r] = s; bsq[r] = q;
    }
    if (l31 == 0) {
      float* pp = psum + ((((size_t)b * 48 + hb) * 2 + rw) * 256) * 2;
      #pragma unroll
      for (int r = 0; r < 16; r++) {
        int row = (r & 3) + 8 * (r >> 2) + 4 * lhi;
        int co = co0 + mh * 32 + row;
        pp[co * 2]     = bsum[r];
        pp[co * 2 + 1] = bsq[r];
      }
    }
    __syncthreads();
    unsigned short* dstb = xt2 + (size_t)b * XT_PLANE;
    #pragma unroll
    for (int i = 0; i < 6; i++) {
      int c = t + i * 256;
      int row2 = c / 768;
      int rem = c - row2 * 768;
      int wi = rem >> 3, p8 = rem & 7;
      const unsigned short* lsrc = &tbl[(row2 * 96 + wi) * 68 + p8 * 8];
      uint2 lo = *(const uint2*)lsrc;
      uint2 hi2 = *(const uint2*)(lsrc + 4);
      size_t ga = ((size_t)(h0 + 1 + row2) * 98 + (wi + 1)) * 256 + co0 + p8 * 8;
      uint4 vv; vv.x = lo.x; vv.y = lo.y; vv.z = hi2.x; vv.w = hi2.y;
      *(uint4*)&dstb[ga] = vv;
    }
  } else {
    // conv2: f32 plane-major output
    #pragma unroll
    for (int r = 0; r < 16; r++) {
      int row = (r & 3) + 8 * (r >> 2) + 4 * lhi;
      int co = co0 + mh * 32 + row;
      float bv = cb[co];
      size_t base = ((size_t)(b * 256 + co) * 96 + h) * 96;
      #pragma unroll
      for (int nn = 0; nn < 3; nn++) {
        out[base + nn * 32 + l31] = acc[nn][r] + bv;
      }
    }
  }
}

// ---------------------------------------------------------------------------
extern "C" void kernel_launch(void* const* d_in, const int* in_sizes, int n_in,
                              void* d_out, int out_size, void* d_ws, size_t ws_size,
                              hipStream_t stream)
{
  const float* fm    = (const float*)d_in[0];
  const float* para  = (const float*)d_in[1];
  const float* style = (const float*)d_in[2];
  const float* cw  = (const float*)d_in[3];
  const float* cb  = (const float*)d_in[4];
  const float* sw  = (const float*)d_in[5];
  const float* sb  = (const float*)d_in[6];
  const float* rw  = (const float*)d_in[7];
  const float* rb  = (const float*)d_in[8];
  const float* tw  = (const float*)d_in[9];
  const float* tb  = (const float*)d_in[10];
  const float* a1w = (const float*)d_in[11];
  const float* a1b = (const float*)d_in[12];
  const float* g1w = (const float*)d_in[13];
  const float* g1b = (const float*)d_in[14];
  const float* b1w = (const float*)d_in[15];
  const float* b1b = (const float*)d_in[16];
  const float* c1w = (const float*)d_in[17];
  const float* c1b = (const float*)d_in[18];
  const float* a2w = (const float*)d_in[19];
  const float* a2b = (const float*)d_in[20];
  const float* g2w = (const float*)d_in[21];
  const float* g2b = (const float*)d_in[22];
  const float* b2w = (const float*)d_in[23];
  const float* b2b = (const float*)d_in[24];
  const float* c2w = (const float*)d_in[25];
  const float* c2b = (const float*)d_in[26];

  float* outf = (float*)d_out;
  unsigned short* tbf16 = (unsigned short*)d_out;  // bf16 t (first half of d_out)

  unsigned short* xtbuf  = (unsigned short*)d_ws;                 // xt1
  unsigned short* xt2buf = xtbuf + (size_t)BATCH * XT_PLANE;      // xt2
  unsigned short* wf1    = xt2buf + (size_t)BATCH * XT_PLANE;
  unsigned short* wf2    = wf1 + 9 * 256 * 256;
  float* fws  = (float*)(wf2 + 9 * 256 * 256);
  float* warp = fws;                   // 4096
  float* gb1  = warp + 4 * 1024;       // 2048
  float* gb2  = gb1 + 2 * 1024;        // 2048
  float* nrm2 = gb2 + 2 * 1024;        // 2048
  float* pcbuf = nrm2 + 2 * 1024;      // 1024
  float* a1buf = pcbuf + 1024;         // 512
  float* a2buf = a1buf + 512;          // 512
  float* psum  = a2buf + 512;          // 98304 floats

  params_stage1_kernel<<<dim3(6, 4), 256, 0, stream>>>(para, style, cw, cb,
      a1w, a1b, a2w, a2b, pcbuf, a1buf, a2buf);
  params_stage2_kernel<<<dim3(16, 4), 256, 0, stream>>>(pcbuf, a1buf, a2buf,
      sw, sb, rw, rb, tw, tb, g1w, g1b, b1w, b1b, g2w, g2b, b2w, b2b,
      warp, gb1, gb2);
  prep_weights_kernel<<<512, 256, 0, stream>>>(c1w, c2w, wf1, wf2);
  // adaat: fused warp + stats + AdaIN-1 + lrelu -> bf16 t in d_out
  adaat_kernel<<<1024, 256, 0, stream>>>(fm, warp, gb1, tbf16);
  transpose_kernel<<<dim3(98, 4), 256, 0, stream>>>(tbf16, xtbuf);
  // conv1: writes xt2 (bf16 transposed, pre-norm) + stats partials
  conv_mfma_kernel<<<768, 256, 0, stream>>>(xtbuf, wf1, c1b,
      outf, xt2buf, psum);
  finalize_stats_kernel<<<4, 256, 0, stream>>>(psum, gb2, nrm2);
  norm2_kernel<<<dim3(98, 4), 256, 0, stream>>>(xt2buf, nrm2);
  // conv2: final f32 output
  conv_mfma_kernel<<<768, 256, 0, stream>>>(xt2buf, wf2, c2b,
      outf, nullptr, nullptr);
}